// Round 1
// baseline (1446.390 us; speedup 1.0000x reference)
//
#include <hip/hip_runtime.h>
#include <stdint.h>

#define TT 2048
#define DM 2048
#define NH 16
#define HD 128
#define FFN 8192
#define MR 4096   // B*T
#define EPSF 1.1920928955078125e-07f
#define NEGBIG (-1.0e30f)

typedef __attribute__((ext_vector_type(8))) short short8;
typedef __attribute__((ext_vector_type(4))) float f32x4;
typedef unsigned short u16;
typedef unsigned int u32;

__device__ __forceinline__ float bf2f(u32 u) {
    return __uint_as_float((u & 0xffffu) << 16);
}
__device__ __forceinline__ u16 f2bf(float f) {
    u32 x = __float_as_uint(f);
    return (u16)((x + 0x7fffu + ((x >> 16) & 1u)) >> 16);
}
__device__ __forceinline__ void load8f(const u16* p, float* v) {
    uint4 d = *(const uint4*)p;
    v[0] = bf2f(d.x); v[1] = bf2f(d.x >> 16);
    v[2] = bf2f(d.y); v[3] = bf2f(d.y >> 16);
    v[4] = bf2f(d.z); v[5] = bf2f(d.z >> 16);
    v[6] = bf2f(d.w); v[7] = bf2f(d.w >> 16);
}
__device__ __forceinline__ void load8f32(const float* p, float* v) {
    float4 a = *(const float4*)p, b = *(const float4*)(p + 4);
    v[0]=a.x; v[1]=a.y; v[2]=a.z; v[3]=a.w; v[4]=b.x; v[5]=b.y; v[6]=b.z; v[7]=b.w;
}
__device__ __forceinline__ void store8bf(u16* p, const float* v) {
    uint4 o;
    o.x = (u32)f2bf(v[0]) | ((u32)f2bf(v[1]) << 16);
    o.y = (u32)f2bf(v[2]) | ((u32)f2bf(v[3]) << 16);
    o.z = (u32)f2bf(v[4]) | ((u32)f2bf(v[5]) << 16);
    o.w = (u32)f2bf(v[6]) | ((u32)f2bf(v[7]) << 16);
    *(uint4*)p = o;
}
__device__ __forceinline__ uint4 cvt8_f32_bf16(const float* p) {
    float4 a = *(const float4*)p, b = *(const float4*)(p + 4);
    uint4 o;
    o.x = (u32)f2bf(a.x) | ((u32)f2bf(a.y) << 16);
    o.y = (u32)f2bf(a.z) | ((u32)f2bf(a.w) << 16);
    o.z = (u32)f2bf(b.x) | ((u32)f2bf(b.y) << 16);
    o.w = (u32)f2bf(b.z) | ((u32)f2bf(b.w) << 16);
    return o;
}
__device__ __forceinline__ void gload_lds16(const void* g, void* l) {
    __builtin_amdgcn_global_load_lds((const __attribute__((address_space(1))) u32*)g,
                                     (__attribute__((address_space(3))) u32*)l, 16, 0, 0);
}

// ---------------- weight f32 -> bf16 (8 elems/thread) ----------------
__global__ __launch_bounds__(256)
void cvt_w(const float* __restrict__ S, u16* __restrict__ D) {
    size_t i = ((size_t)blockIdx.x * 256 + threadIdx.x) * 8;
    *(uint4*)(D + i) = cvt8_f32_bf16(S + i);
}

// ---------------- RMSNorm (f32 in, bf16 out): one block per row of 2048 ----------------
__global__ __launch_bounds__(256)
void rmsnorm_k(const float* __restrict__ X, const float* __restrict__ W, u16* __restrict__ O) {
    const int row = blockIdx.x, tid = threadIdx.x;
    float v[8];
    load8f32(X + (size_t)row * DM + tid * 8, v);
    float ssq = 0.f;
#pragma unroll
    for (int i = 0; i < 8; ++i) ssq += v[i] * v[i];
#pragma unroll
    for (int d = 1; d < 64; d <<= 1) ssq += __shfl_xor(ssq, d);
    __shared__ float red[4];
    if ((tid & 63) == 0) red[tid >> 6] = ssq;
    __syncthreads();
    ssq = red[0] + red[1] + red[2] + red[3];
    const float inv = rsqrtf(ssq * (1.f / DM) + EPSF);
    float wv[8], o[8];
    load8f32(W + tid * 8, wv);
#pragma unroll
    for (int i = 0; i < 8; ++i) o[i] = v[i] * inv * wv[i];
    store8bf(O + (size_t)row * DM + tid * 8, o);
}

// ---------------- GEMM C[M,N] = A[M,K](bf16, lda=K) * Bw[N,K](bf16, row-stride ldb)^T ----
// m97 pattern: global_load_lds width-16 staging, XOR-swizzled LDS, 128x128 tile, BK=32.
// EPI: 0 = bf16 out, 1 = relu^2 bf16 out, 2 = + f32 Res -> f32 out
template<int EPI>
__global__ __launch_bounds__(256)
void gemm_bt(const u16* __restrict__ A, const u16* __restrict__ Bw,
             const float* __restrict__ Res, void* __restrict__ Cp,
             int M, int N, int K, int ldb) {
    __shared__ alignas(16) u16 As[128 * 32];
    __shared__ alignas(16) u16 Bs[128 * 32];
    const int tid = threadIdx.x;
    const int lane = tid & 63, w = tid >> 6;
    const int quad = lane >> 4, col = lane & 15;
    const int n0 = blockIdx.x * 128, m0 = blockIdx.y * 128;
    const int wm = (w >> 1) * 64, wn = (w & 1) * 64;

    // staging: 512 chunks of 8 elems per tile, 2 per thread; LDS slot s of row r
    // holds global chunk q = s ^ ((r>>1)&3)
    const int c0 = tid, c1 = tid + 256;
    const int ar0 = c0 >> 2, aq0 = (c0 & 3) ^ ((ar0 >> 1) & 3);
    const int ar1 = c1 >> 2, aq1 = (c1 & 3) ^ ((ar1 >> 1) & 3);
    const u16* agp0 = A  + (size_t)(m0 + ar0) * K + aq0 * 8;
    const u16* agp1 = A  + (size_t)(m0 + ar1) * K + aq1 * 8;
    const u16* bgp0 = Bw + (size_t)(n0 + ar0) * ldb + aq0 * 8;
    const u16* bgp1 = Bw + (size_t)(n0 + ar1) * ldb + aq1 * 8;
    u16* al0 = As + c0 * 8; u16* al1 = As + c1 * 8;
    u16* bl0 = Bs + c0 * 8; u16* bl1 = Bs + c1 * 8;

    int aoff[4], boff[4];
#pragma unroll
    for (int i = 0; i < 4; ++i) {
        int r = wm + i * 16 + col;
        aoff[i] = r * 32 + (quad ^ ((r >> 1) & 3)) * 8;
        r = wn + i * 16 + col;
        boff[i] = r * 32 + (quad ^ ((r >> 1) & 3)) * 8;
    }

    f32x4 acc[4][4];
#pragma unroll
    for (int i = 0; i < 4; ++i)
#pragma unroll
        for (int j = 0; j < 4; ++j) acc[i][j] = (f32x4){0.f, 0.f, 0.f, 0.f};

    for (int kt = 0; kt < K; kt += 32) {
        __syncthreads();
        gload_lds16(agp0 + kt, al0);
        gload_lds16(agp1 + kt, al1);
        gload_lds16(bgp0 + kt, bl0);
        gload_lds16(bgp1 + kt, bl1);
        __syncthreads();
        short8 af[4], bfr[4];
#pragma unroll
        for (int i = 0; i < 4; ++i) af[i] = *(const short8*)(As + aoff[i]);
#pragma unroll
        for (int i = 0; i < 4; ++i) bfr[i] = *(const short8*)(Bs + boff[i]);
#pragma unroll
        for (int mi = 0; mi < 4; ++mi)
#pragma unroll
            for (int ni = 0; ni < 4; ++ni)
                acc[mi][ni] = __builtin_amdgcn_mfma_f32_16x16x32_bf16(af[mi], bfr[ni], acc[mi][ni], 0, 0, 0);
    }

#pragma unroll
    for (int mi = 0; mi < 4; ++mi)
#pragma unroll
        for (int ni = 0; ni < 4; ++ni) {
            const int rbase = m0 + wm + mi * 16 + quad * 4;
            const int cc = n0 + wn + ni * 16 + col;
#pragma unroll
            for (int rr = 0; rr < 4; ++rr) {
                float v = acc[mi][ni][rr];
                size_t idx = (size_t)(rbase + rr) * N + cc;
                if (EPI == 0) ((u16*)Cp)[idx] = f2bf(v);
                else if (EPI == 1) { float t = fmaxf(v, 0.f); ((u16*)Cp)[idx] = f2bf(t * t); }
                else ((float*)Cp)[idx] = v + Res[idx];
            }
        }
}

// ---------------- RoPE + per-head RMSNorm on q,k; split v ----------------
__global__ __launch_bounds__(256)
void rope_split_k(const u16* __restrict__ QKV, const float* __restrict__ RC,
                  const float* __restrict__ QW, const float* __restrict__ KW,
                  u16* __restrict__ Qo, u16* __restrict__ Ko, u16* __restrict__ Vo) {
    const int row = blockIdx.x;                 // b*T + t
    const int t = row & (TT - 1), b = row >> 11;
    const int tid = threadIdx.x, h = tid >> 4, j = tid & 15;
    const size_t qb = (size_t)row * (3 * DM) + h * HD + j * 8;
    float q[8], k[8], cs[8], sn[8];
    load8f(QKV + qb, q);
    load8f(QKV + qb + DM, k);
    uint4 vv = *(const uint4*)(QKV + qb + 2 * DM);
    load8f32(RC + (size_t)t * HD + j * 8, cs);
    load8f32(RC + (size_t)(TT + t) * HD + j * 8, sn);
    float qr[8], kr[8];
#pragma unroll
    for (int p = 0; p < 4; ++p) {
        float c = cs[2 * p], s = sn[2 * p];
        qr[2*p]   = q[2*p]   * c - q[2*p+1] * s;
        qr[2*p+1] = q[2*p+1] * c + q[2*p]   * s;
        kr[2*p]   = k[2*p]   * c - k[2*p+1] * s;
        kr[2*p+1] = k[2*p+1] * c + k[2*p]   * s;
    }
    float sq = 0.f, sk = 0.f;
#pragma unroll
    for (int i = 0; i < 8; ++i) { sq += qr[i] * qr[i]; sk += kr[i] * kr[i]; }
#pragma unroll
    for (int d = 1; d < 16; d <<= 1) { sq += __shfl_xor(sq, d); sk += __shfl_xor(sk, d); }
    const float iq = rsqrtf(sq * (1.f / HD) + EPSF);
    const float ik = rsqrtf(sk * (1.f / HD) + EPSF);
    float qw[8], kw[8], oq[8], ok[8];
    load8f32(QW + j * 8, qw); load8f32(KW + j * 8, kw);
#pragma unroll
    for (int i = 0; i < 8; ++i) { oq[i] = qr[i] * iq * qw[i]; ok[i] = kr[i] * ik * kw[i]; }
    const size_t ob = ((size_t)(b * NH + h) * TT + t) * HD + j * 8;
    store8bf(Qo + ob, oq);
    store8bf(Ko + ob, ok);
    *(uint4*)(Vo + ob) = vv;
}

// ---------------- V transpose: [bh][T][128] -> [bh][128][T] ----------------
__global__ __launch_bounds__(256)
void transpose_v(const u16* __restrict__ V, u16* __restrict__ Vt) {
    __shared__ alignas(16) u16 tile[64][72];
    const int bh = blockIdx.z;
    const int t0 = blockIdx.x * 64, d0 = blockIdx.y * 64;
    const int tid = threadIdx.x;
#pragma unroll
    for (int i = 0; i < 2; ++i) {
        int c = i * 256 + tid;
        int r = c >> 3, cc = (c & 7) * 8;
        *(uint4*)(&tile[r][cc]) = *(const uint4*)(V + ((size_t)bh * TT + t0 + r) * HD + d0 + cc);
    }
    __syncthreads();
#pragma unroll
    for (int i = 0; i < 2; ++i) {
        int c = i * 256 + tid;
        int dc = c >> 3, rr = (c & 7) * 8;
        u16 tmp[8];
#pragma unroll
        for (int kk = 0; kk < 8; ++kk) tmp[kk] = tile[rr + kk][dc];
        uint4 o;
        o.x = (u32)tmp[0] | ((u32)tmp[1] << 16);
        o.y = (u32)tmp[2] | ((u32)tmp[3] << 16);
        o.z = (u32)tmp[4] | ((u32)tmp[5] << 16);
        o.w = (u32)tmp[6] | ((u32)tmp[7] << 16);
        *(uint4*)(Vt + ((size_t)bh * HD + d0 + dc) * TT + t0 + rr) = o;
    }
}

// ---------------- Causal flash attention, 64-query tile per block ----------------
// v2: T14 register prefetch of next K/V tile (hide global latency under compute),
//     T5 setprio around MFMA clusters, strict defer-rescale (exact, alpha==1 skip).
__global__ __launch_bounds__(256)
void attn_k(const u16* __restrict__ Q, const u16* __restrict__ Kg,
            const u16* __restrict__ Vt, u16* __restrict__ O) {
    __shared__ alignas(16) u16 k_lds[64 * 128];
    __shared__ alignas(16) u16 v_lds[128 * 64];
    __shared__ alignas(16) u16 p_lds[4 * 16 * 72];
    const int qt = gridDim.x - 1 - blockIdx.x;   // long blocks first
    const int bh = blockIdx.y;
    const int tid = threadIdx.x, lane = tid & 63, w = tid >> 6;
    const int quad = lane >> 4, col = lane & 15;
    const int qbase = qt * 64;
    const int qrow = qbase + w * 16 + col;

    short8 qf[4];
    const u16* qp = Q + ((size_t)bh * TT + qrow) * HD;
#pragma unroll
    for (int s = 0; s < 4; ++s) qf[s] = *(const short8*)(qp + s * 32 + quad * 8);

    // per-thread staging addresses (swizzled), advanced by kb each tile
    const u16* kp[4]; const u16* vp[4];
#pragma unroll
    for (int i = 0; i < 4; ++i) {
        int lin = i * 256 + tid;
        int r = lin >> 4, sl = lin & 15;
        int gq = sl ^ (r & 15);
        kp[i] = Kg + ((size_t)bh * TT + r) * HD + gq * 8;
    }
#pragma unroll
    for (int i = 0; i < 4; ++i) {
        int lin = i * 256 + tid;
        int r = lin >> 3, sl = lin & 7;
        int gq = sl ^ (r & 7);
        vp[i] = Vt + ((size_t)bh * HD + r) * TT + gq * 8;
    }

    f32x4 oacc[8];
#pragma unroll
    for (int i = 0; i < 8; ++i) oacc[i] = (f32x4){0.f, 0.f, 0.f, 0.f};
    float mrow[4] = {NEGBIG, NEGBIG, NEGBIG, NEGBIG};
    float lrow[4] = {0.f, 0.f, 0.f, 0.f};
    const float scale = 0.08838834764831845f;   // 1/sqrt(128)

    // prologue: tile 0 into staging regs
    uint4 kreg[4], vreg[4], kreg2[4], vreg2[4];
#pragma unroll
    for (int i = 0; i < 4; ++i) kreg[i] = *(const uint4*)(kp[i]);
#pragma unroll
    for (int i = 0; i < 4; ++i) vreg[i] = *(const uint4*)(vp[i]);

    for (int kt = 0; kt <= qt; ++kt) {
        const int kb = kt * 64;
        __syncthreads();
#pragma unroll
        for (int i = 0; i < 4; ++i) *(uint4*)(k_lds + (i * 256 + tid) * 8) = kreg[i];
#pragma unroll
        for (int i = 0; i < 4; ++i) *(uint4*)(v_lds + (i * 256 + tid) * 8) = vreg[i];
        __syncthreads();

        // T14: issue next tile's loads now; consumed at next iteration's ds_write.
        const bool pf = (kt < qt);
        if (pf) {
            const int kb2 = kb + 64;
#pragma unroll
            for (int i = 0; i < 4; ++i) kreg2[i] = *(const uint4*)(kp[i] + (size_t)kb2 * HD);
#pragma unroll
            for (int i = 0; i < 4; ++i) vreg2[i] = *(const uint4*)(vp[i] + kb2);
        }

        f32x4 sfr[4];
#pragma unroll
        for (int ni = 0; ni < 4; ++ni) sfr[ni] = (f32x4){0.f, 0.f, 0.f, 0.f};
        __builtin_amdgcn_s_setprio(1);
#pragma unroll
        for (int ni = 0; ni < 4; ++ni) {
            const int r = ni * 16 + col;
#pragma unroll
            for (int s = 0; s < 4; ++s) {
                int sl = (s * 4 + quad) ^ (r & 15);
                short8 kf = *(const short8*)(k_lds + r * 128 + sl * 8);
                sfr[ni] = __builtin_amdgcn_mfma_f32_16x16x32_bf16(qf[s], kf, sfr[ni], 0, 0, 0);
            }
        }
        __builtin_amdgcn_s_setprio(0);
        const bool diag = (kt == qt);
#pragma unroll
        for (int ni = 0; ni < 4; ++ni) {
            const int key = kb + ni * 16 + col;
#pragma unroll
            for (int rr = 0; rr < 4; ++rr) {
                float v = sfr[ni][rr] * scale;
                int qv = qbase + w * 16 + quad * 4 + rr;
                if (diag && key > qv) v = NEGBIG;
                sfr[ni][rr] = v;
            }
        }
        float mx[4];
#pragma unroll
        for (int rr = 0; rr < 4; ++rr)
            mx[rr] = fmaxf(fmaxf(sfr[0][rr], sfr[1][rr]), fmaxf(sfr[2][rr], sfr[3][rr]));
#pragma unroll
        for (int d = 1; d < 16; d <<= 1)
#pragma unroll
            for (int rr = 0; rr < 4; ++rr) mx[rr] = fmaxf(mx[rr], __shfl_xor(mx[rr], d));
        // strict defer-rescale: if no row's max grew, alpha==1 exactly -> skip.
        if (__any((mx[0] > mrow[0]) || (mx[1] > mrow[1]) ||
                  (mx[2] > mrow[2]) || (mx[3] > mrow[3]))) {
#pragma unroll
            for (int rr = 0; rr < 4; ++rr) {
                float mn = fmaxf(mrow[rr], mx[rr]);
                float a = __expf(mrow[rr] - mn);
                mrow[rr] = mn;
                lrow[rr] *= a;
#pragma unroll
                for (int i = 0; i < 8; ++i) oacc[i][rr] *= a;
            }
        }
        float rs[4] = {0.f, 0.f, 0.f, 0.f};
#pragma unroll
        for (int ni = 0; ni < 4; ++ni)
#pragma unroll
            for (int rr = 0; rr < 4; ++rr) {
                float p = __expf(sfr[ni][rr] - mrow[rr]);
                sfr[ni][rr] = p;
                rs[rr] += p;
            }
#pragma unroll
        for (int d = 1; d < 16; d <<= 1)
#pragma unroll
            for (int rr = 0; rr < 4; ++rr) rs[rr] += __shfl_xor(rs[rr], d);
#pragma unroll
        for (int rr = 0; rr < 4; ++rr) lrow[rr] += rs[rr];
        // P (C-layout) -> LDS -> A-layout
#pragma unroll
        for (int ni = 0; ni < 4; ++ni)
#pragma unroll
            for (int rr = 0; rr < 4; ++rr)
                p_lds[(w * 16 + quad * 4 + rr) * 72 + ni * 16 + col] = f2bf(sfr[ni][rr]);
        __builtin_amdgcn_s_setprio(1);
#pragma unroll
        for (int ks = 0; ks < 2; ++ks) {
            short8 pa = *(const short8*)(p_lds + (w * 16 + col) * 72 + ks * 32 + quad * 8);
#pragma unroll
            for (int di = 0; di < 8; ++di) {
                int r = di * 16 + col;
                int sl = (ks * 4 + quad) ^ (r & 7);
                short8 vb = *(const short8*)(v_lds + r * 64 + sl * 8);
                oacc[di] = __builtin_amdgcn_mfma_f32_16x16x32_bf16(pa, vb, oacc[di], 0, 0, 0);
            }
        }
        __builtin_amdgcn_s_setprio(0);
        if (pf) {
#pragma unroll
            for (int i = 0; i < 4; ++i) { kreg[i] = kreg2[i]; vreg[i] = vreg2[i]; }
        }
    }
    const int b = bh >> 4, h = bh & 15;
#pragma unroll
    for (int di = 0; di < 8; ++di)
#pragma unroll
        for (int rr = 0; rr < 4; ++rr) {
            int trow = qbase + w * 16 + quad * 4 + rr;
            float ov = oacc[di][rr] / lrow[rr];
            O[((size_t)(b * TT + trow)) * DM + h * HD + di * 16 + col] = f2bf(ov);
        }
}

extern "C" void kernel_launch(void* const* d_in, const int* in_sizes, int n_in,
                              void* d_out, int out_size, void* d_ws, size_t ws_size,
                              hipStream_t stream) {
    const float* x    = (const float*)d_in[0];
    const float* rc   = (const float*)d_in[1];
    const float* anw  = (const float*)d_in[2];
    const float* qkvw = (const float*)d_in[3];
    const float* qnw  = (const float*)d_in[4];
    const float* knw  = (const float*)d_in[5];
    const float* opw  = (const float*)d_in[6];
    const float* mnw  = (const float*)d_in[7];
    const float* miw  = (const float*)d_in[8];
    const float* mow  = (const float*)d_in[9];

    char* ws = (char*)d_ws;
    // Workspace plan, 120 MiB peak (MiB offsets). Late-phase owners:
    //   hbuf[0,16) Wmi[16,48) Wmo[48,80) mbuf[80,112) Wo[112,120)
    // Early/mid aliases (dead before late owner is written):
    //   Wq[16,40)  qkv[48,96)  qh[96,112)  kh[112,128)  vh[0,16)  vt[16,32)  aout[32,48)
    // Residual x2 lives in d_out (f32), accumulated by the mlp_out halves.
    u16* hbuf = (u16*)(ws);
    u16* Wq   = (u16*)(ws + (16ll  << 20));
    u16* Wmi  = (u16*)(ws + (16ll  << 20));
    u16* vt   = (u16*)(ws + (16ll  << 20));
    u16* aout = (u16*)(ws + (32ll  << 20));
    u16* Wmo  = (u16*)(ws + (48ll  << 20));
    u16* qkv  = (u16*)(ws + (48ll  << 20));
    u16* mbuf = (u16*)(ws + (80ll  << 20));
    u16* qh   = (u16*)(ws + (96ll  << 20));
    u16* Wo   = (u16*)(ws + (112ll << 20));
    u16* kh   = (u16*)(ws + (112ll << 20));
    u16* vh   = (u16*)(ws);
    float* xo = (float*)d_out;

    rmsnorm_k<<<MR, 256, 0, stream>>>(x, anw, hbuf);
    cvt_w<<<6144, 256, 0, stream>>>(qkvw, Wq);                     // 3DM*DM
    gemm_bt<0><<<dim3(48, 32), 256, 0, stream>>>(hbuf, Wq, nullptr, qkv, MR, 3 * DM, DM, DM);
    rope_split_k<<<MR, 256, 0, stream>>>(qkv, rc, qnw, knw, qh, kh, vh);
    transpose_v<<<dim3(32, 2, 32), 256, 0, stream>>>(vh, vt);
    attn_k<<<dim3(32, 32), 256, 0, stream>>>(qh, kh, vt, aout);
    cvt_w<<<2048, 256, 0, stream>>>(opw, Wo);                      // DM*DM (kh dead)
    cvt_w<<<8192, 256, 0, stream>>>(mow, Wmo);                     // DM*FFN (qkv dead)
    gemm_bt<2><<<dim3(16, 32), 256, 0, stream>>>(aout, Wo, x, xo, MR, DM, DM, DM);
    rmsnorm_k<<<MR, 256, 0, stream>>>(xo, mnw, hbuf);
    cvt_w<<<8192, 256, 0, stream>>>(miw, Wmi);                     // FFN*DM (vt/aout dead)
    // MLP in two FFN halves; mbuf is 4096x4096 bf16, d_out accumulates in f32.
    gemm_bt<1><<<dim3(32, 32), 256, 0, stream>>>(hbuf, Wmi, nullptr, mbuf, MR, FFN / 2, DM, DM);
    gemm_bt<2><<<dim3(16, 32), 256, 0, stream>>>(mbuf, Wmo, xo, xo, MR, DM, FFN / 2, FFN);
    gemm_bt<1><<<dim3(32, 32), 256, 0, stream>>>(hbuf, Wmi + (size_t)(FFN / 2) * DM, nullptr, mbuf, MR, FFN / 2, DM, DM);
    gemm_bt<2><<<dim3(16, 32), 256, 0, stream>>>(mbuf, Wmo + FFN / 2, xo, xo, MR, DM, FFN / 2, FFN);
}

// Round 2
// 1060.824 us; speedup vs baseline: 1.3635x; 1.3635x over previous
//
#include <hip/hip_runtime.h>
#include <stdint.h>

#define TT 2048
#define DM 2048
#define NH 16
#define HD 128
#define FFN 8192
#define MR 4096   // B*T
#define EPSF 1.1920928955078125e-07f
#define NEGBIG (-1.0e30f)

typedef __attribute__((ext_vector_type(8))) short short8;
typedef __attribute__((ext_vector_type(4))) float f32x4;
typedef unsigned short u16;
typedef unsigned int u32;

__device__ __forceinline__ float bf2f(u32 u) {
    return __uint_as_float((u & 0xffffu) << 16);
}
__device__ __forceinline__ u16 f2bf(float f) {
    u32 x = __float_as_uint(f);
    return (u16)((x + 0x7fffu + ((x >> 16) & 1u)) >> 16);
}
__device__ __forceinline__ void load8f(const u16* p, float* v) {
    uint4 d = *(const uint4*)p;
    v[0] = bf2f(d.x); v[1] = bf2f(d.x >> 16);
    v[2] = bf2f(d.y); v[3] = bf2f(d.y >> 16);
    v[4] = bf2f(d.z); v[5] = bf2f(d.z >> 16);
    v[6] = bf2f(d.w); v[7] = bf2f(d.w >> 16);
}
__device__ __forceinline__ void load8f32(const float* p, float* v) {
    float4 a = *(const float4*)p, b = *(const float4*)(p + 4);
    v[0]=a.x; v[1]=a.y; v[2]=a.z; v[3]=a.w; v[4]=b.x; v[5]=b.y; v[6]=b.z; v[7]=b.w;
}
__device__ __forceinline__ void store8bf(u16* p, const float* v) {
    uint4 o;
    o.x = (u32)f2bf(v[0]) | ((u32)f2bf(v[1]) << 16);
    o.y = (u32)f2bf(v[2]) | ((u32)f2bf(v[3]) << 16);
    o.z = (u32)f2bf(v[4]) | ((u32)f2bf(v[5]) << 16);
    o.w = (u32)f2bf(v[6]) | ((u32)f2bf(v[7]) << 16);
    *(uint4*)p = o;
}
__device__ __forceinline__ uint4 cvt8_f32_bf16(const float* p) {
    float4 a = *(const float4*)p, b = *(const float4*)(p + 4);
    uint4 o;
    o.x = (u32)f2bf(a.x) | ((u32)f2bf(a.y) << 16);
    o.y = (u32)f2bf(a.z) | ((u32)f2bf(a.w) << 16);
    o.z = (u32)f2bf(b.x) | ((u32)f2bf(b.y) << 16);
    o.w = (u32)f2bf(b.z) | ((u32)f2bf(b.w) << 16);
    return o;
}
__device__ __forceinline__ void gload_lds16(const void* g, void* l) {
    __builtin_amdgcn_global_load_lds((const __attribute__((address_space(1))) u32*)g,
                                     (__attribute__((address_space(3))) u32*)l, 16, 0, 0);
}

// ---------------- weight f32 -> bf16 (8 elems/thread) ----------------
__global__ __launch_bounds__(256)
void cvt_w(const float* __restrict__ S, u16* __restrict__ D) {
    size_t i = ((size_t)blockIdx.x * 256 + threadIdx.x) * 8;
    *(uint4*)(D + i) = cvt8_f32_bf16(S + i);
}

// ---------------- RMSNorm (f32 in, bf16 out): one block per row of 2048 ----------------
__global__ __launch_bounds__(256)
void rmsnorm_k(const float* __restrict__ X, const float* __restrict__ W, u16* __restrict__ O) {
    const int row = blockIdx.x, tid = threadIdx.x;
    float v[8];
    load8f32(X + (size_t)row * DM + tid * 8, v);
    float ssq = 0.f;
#pragma unroll
    for (int i = 0; i < 8; ++i) ssq += v[i] * v[i];
#pragma unroll
    for (int d = 1; d < 64; d <<= 1) ssq += __shfl_xor(ssq, d);
    __shared__ float red[4];
    if ((tid & 63) == 0) red[tid >> 6] = ssq;
    __syncthreads();
    ssq = red[0] + red[1] + red[2] + red[3];
    const float inv = rsqrtf(ssq * (1.f / DM) + EPSF);
    float wv[8], o[8];
    load8f32(W + tid * 8, wv);
#pragma unroll
    for (int i = 0; i < 8; ++i) o[i] = v[i] * inv * wv[i];
    store8bf(O + (size_t)row * DM + tid * 8, o);
}

// ---------------- GEMM C[M,N] = A[M,K](bf16, lda=K) * Bw[N,K](bf16, row-stride ldb)^T ----
// m97 pattern: global_load_lds width-16 staging, XOR-swizzled LDS, 128x128 tile, BK=32.
// EPI: 0 = bf16 out, 1 = relu^2 bf16 out, 2 = + f32 Res -> f32 out
template<int EPI>
__global__ __launch_bounds__(256)
void gemm_bt(const u16* __restrict__ A, const u16* __restrict__ Bw,
             const float* __restrict__ Res, void* __restrict__ Cp,
             int M, int N, int K, int ldb) {
    __shared__ alignas(16) u16 As[128 * 32];
    __shared__ alignas(16) u16 Bs[128 * 32];
    const int tid = threadIdx.x;
    const int lane = tid & 63, w = tid >> 6;
    const int quad = lane >> 4, col = lane & 15;
    const int n0 = blockIdx.x * 128, m0 = blockIdx.y * 128;
    const int wm = (w >> 1) * 64, wn = (w & 1) * 64;

    // staging: 512 chunks of 8 elems per tile, 2 per thread; LDS slot s of row r
    // holds global chunk q = s ^ ((r>>1)&3)
    const int c0 = tid, c1 = tid + 256;
    const int ar0 = c0 >> 2, aq0 = (c0 & 3) ^ ((ar0 >> 1) & 3);
    const int ar1 = c1 >> 2, aq1 = (c1 & 3) ^ ((ar1 >> 1) & 3);
    const u16* agp0 = A  + (size_t)(m0 + ar0) * K + aq0 * 8;
    const u16* agp1 = A  + (size_t)(m0 + ar1) * K + aq1 * 8;
    const u16* bgp0 = Bw + (size_t)(n0 + ar0) * ldb + aq0 * 8;
    const u16* bgp1 = Bw + (size_t)(n0 + ar1) * ldb + aq1 * 8;
    u16* al0 = As + c0 * 8; u16* al1 = As + c1 * 8;
    u16* bl0 = Bs + c0 * 8; u16* bl1 = Bs + c1 * 8;

    int aoff[4], boff[4];
#pragma unroll
    for (int i = 0; i < 4; ++i) {
        int r = wm + i * 16 + col;
        aoff[i] = r * 32 + (quad ^ ((r >> 1) & 3)) * 8;
        r = wn + i * 16 + col;
        boff[i] = r * 32 + (quad ^ ((r >> 1) & 3)) * 8;
    }

    f32x4 acc[4][4];
#pragma unroll
    for (int i = 0; i < 4; ++i)
#pragma unroll
        for (int j = 0; j < 4; ++j) acc[i][j] = (f32x4){0.f, 0.f, 0.f, 0.f};

    for (int kt = 0; kt < K; kt += 32) {
        __syncthreads();
        gload_lds16(agp0 + kt, al0);
        gload_lds16(agp1 + kt, al1);
        gload_lds16(bgp0 + kt, bl0);
        gload_lds16(bgp1 + kt, bl1);
        __syncthreads();
        short8 af[4], bfr[4];
#pragma unroll
        for (int i = 0; i < 4; ++i) af[i] = *(const short8*)(As + aoff[i]);
#pragma unroll
        for (int i = 0; i < 4; ++i) bfr[i] = *(const short8*)(Bs + boff[i]);
#pragma unroll
        for (int mi = 0; mi < 4; ++mi)
#pragma unroll
            for (int ni = 0; ni < 4; ++ni)
                acc[mi][ni] = __builtin_amdgcn_mfma_f32_16x16x32_bf16(af[mi], bfr[ni], acc[mi][ni], 0, 0, 0);
    }

#pragma unroll
    for (int mi = 0; mi < 4; ++mi)
#pragma unroll
        for (int ni = 0; ni < 4; ++ni) {
            const int rbase = m0 + wm + mi * 16 + quad * 4;
            const int cc = n0 + wn + ni * 16 + col;
#pragma unroll
            for (int rr = 0; rr < 4; ++rr) {
                float v = acc[mi][ni][rr];
                size_t idx = (size_t)(rbase + rr) * N + cc;
                if (EPI == 0) ((u16*)Cp)[idx] = f2bf(v);
                else if (EPI == 1) { float t = fmaxf(v, 0.f); ((u16*)Cp)[idx] = f2bf(t * t); }
                else ((float*)Cp)[idx] = v + Res[idx];
            }
        }
}

// ---------------- RoPE + per-head RMSNorm on q,k; split v ----------------
__global__ __launch_bounds__(256)
void rope_split_k(const u16* __restrict__ QKV, const float* __restrict__ RC,
                  const float* __restrict__ QW, const float* __restrict__ KW,
                  u16* __restrict__ Qo, u16* __restrict__ Ko, u16* __restrict__ Vo) {
    const int row = blockIdx.x;                 // b*T + t
    const int t = row & (TT - 1), b = row >> 11;
    const int tid = threadIdx.x, h = tid >> 4, j = tid & 15;
    const size_t qb = (size_t)row * (3 * DM) + h * HD + j * 8;
    float q[8], k[8], cs[8], sn[8];
    load8f(QKV + qb, q);
    load8f(QKV + qb + DM, k);
    uint4 vv = *(const uint4*)(QKV + qb + 2 * DM);
    load8f32(RC + (size_t)t * HD + j * 8, cs);
    load8f32(RC + (size_t)(TT + t) * HD + j * 8, sn);
    float qr[8], kr[8];
#pragma unroll
    for (int p = 0; p < 4; ++p) {
        float c = cs[2 * p], s = sn[2 * p];
        qr[2*p]   = q[2*p]   * c - q[2*p+1] * s;
        qr[2*p+1] = q[2*p+1] * c + q[2*p]   * s;
        kr[2*p]   = k[2*p]   * c - k[2*p+1] * s;
        kr[2*p+1] = k[2*p+1] * c + k[2*p]   * s;
    }
    float sq = 0.f, sk = 0.f;
#pragma unroll
    for (int i = 0; i < 8; ++i) { sq += qr[i] * qr[i]; sk += kr[i] * kr[i]; }
#pragma unroll
    for (int d = 1; d < 16; d <<= 1) { sq += __shfl_xor(sq, d); sk += __shfl_xor(sk, d); }
    const float iq = rsqrtf(sq * (1.f / HD) + EPSF);
    const float ik = rsqrtf(sk * (1.f / HD) + EPSF);
    float qw[8], kw[8], oq[8], ok[8];
    load8f32(QW + j * 8, qw); load8f32(KW + j * 8, kw);
#pragma unroll
    for (int i = 0; i < 8; ++i) { oq[i] = qr[i] * iq * qw[i]; ok[i] = kr[i] * ik * kw[i]; }
    const size_t ob = ((size_t)(b * NH + h) * TT + t) * HD + j * 8;
    store8bf(Qo + ob, oq);
    store8bf(Ko + ob, ok);
    *(uint4*)(Vo + ob) = vv;
}

// ---------------- V transpose: [bh][T][128] -> [bh][128][T] ----------------
__global__ __launch_bounds__(256)
void transpose_v(const u16* __restrict__ V, u16* __restrict__ Vt) {
    __shared__ alignas(16) u16 tile[64][72];
    const int bh = blockIdx.z;
    const int t0 = blockIdx.x * 64, d0 = blockIdx.y * 64;
    const int tid = threadIdx.x;
#pragma unroll
    for (int i = 0; i < 2; ++i) {
        int c = i * 256 + tid;
        int r = c >> 3, cc = (c & 7) * 8;
        *(uint4*)(&tile[r][cc]) = *(const uint4*)(V + ((size_t)bh * TT + t0 + r) * HD + d0 + cc);
    }
    __syncthreads();
#pragma unroll
    for (int i = 0; i < 2; ++i) {
        int c = i * 256 + tid;
        int dc = c >> 3, rr = (c & 7) * 8;
        u16 tmp[8];
#pragma unroll
        for (int kk = 0; kk < 8; ++kk) tmp[kk] = tile[rr + kk][dc];
        uint4 o;
        o.x = (u32)tmp[0] | ((u32)tmp[1] << 16);
        o.y = (u32)tmp[2] | ((u32)tmp[3] << 16);
        o.z = (u32)tmp[4] | ((u32)tmp[5] << 16);
        o.w = (u32)tmp[6] | ((u32)tmp[7] << 16);
        *(uint4*)(Vt + ((size_t)bh * HD + d0 + dc) * TT + t0 + rr) = o;
    }
}

// ---------------- Causal flash attention, 64-query tile per block ----------------
// v3: double-buffered LDS staging via global_load_lds (async, zero VGPR cost).
//     One barrier per K-tile; prefetch of tile kt+1 issued right after the barrier
//     and drained by the compiler's vmcnt(0) at the NEXT barrier -> full compute
//     phase hides global latency. setprio around MFMA; strict (exact) defer-rescale.
__global__ __launch_bounds__(256)
void attn_k(const u16* __restrict__ Q, const u16* __restrict__ Kg,
            const u16* __restrict__ Vt, u16* __restrict__ O) {
    __shared__ alignas(16) u16 k_lds[2][64 * 128];
    __shared__ alignas(16) u16 v_lds[2][128 * 64];
    __shared__ alignas(16) u16 p_lds[4 * 16 * 72];
    const int qt = gridDim.x - 1 - blockIdx.x;   // long blocks first
    const int bh = blockIdx.y;
    const int tid = threadIdx.x, lane = tid & 63, w = tid >> 6;
    const int quad = lane >> 4, col = lane & 15;
    const int qbase = qt * 64;
    const int qrow = qbase + w * 16 + col;

    short8 qf[4];
    const u16* qp = Q + ((size_t)bh * TT + qrow) * HD;
#pragma unroll
    for (int s = 0; s < 4; ++s) qf[s] = *(const short8*)(qp + s * 32 + quad * 8);

    // per-thread swizzled GLOBAL source addresses (tile-relative); LDS dest is linear,
    // wave-uniform base + lane*16 (global_load_lds requirement).
    const u16* kp[4]; const u16* vp[4];
#pragma unroll
    for (int i = 0; i < 4; ++i) {
        int lin = i * 256 + tid;
        int r = lin >> 4, sl = lin & 15;
        int gq = sl ^ (r & 15);
        kp[i] = Kg + ((size_t)bh * TT + r) * HD + gq * 8;
    }
#pragma unroll
    for (int i = 0; i < 4; ++i) {
        int lin = i * 256 + tid;
        int r = lin >> 3, sl = lin & 7;
        int gq = sl ^ (r & 7);
        vp[i] = Vt + ((size_t)bh * HD + r) * TT + gq * 8;
    }

    f32x4 oacc[8];
#pragma unroll
    for (int i = 0; i < 8; ++i) oacc[i] = (f32x4){0.f, 0.f, 0.f, 0.f};
    float mrow[4] = {NEGBIG, NEGBIG, NEGBIG, NEGBIG};
    float lrow[4] = {0.f, 0.f, 0.f, 0.f};
    const float scale = 0.08838834764831845f;   // 1/sqrt(128)

    // prologue: stage tile 0 into buffer 0
    u16* kcur = k_lds[0]; u16* knxt = k_lds[1];
    u16* vcur = v_lds[0]; u16* vnxt = v_lds[1];
#pragma unroll
    for (int i = 0; i < 4; ++i) gload_lds16(kp[i], kcur + (i * 256 + tid) * 8);
#pragma unroll
    for (int i = 0; i < 4; ++i) gload_lds16(vp[i], vcur + (i * 256 + tid) * 8);

    for (int kt = 0; kt <= qt; ++kt) {
        const int kb = kt * 64;
        __syncthreads();   // compiler drains vmcnt(0): buf[cur] staged, buf[nxt] reads done

        if (kt < qt) {     // prefetch tile kt+1 into the other buffer (async)
            const int kb2 = kb + 64;
#pragma unroll
            for (int i = 0; i < 4; ++i) gload_lds16(kp[i] + (size_t)kb2 * HD, knxt + (i * 256 + tid) * 8);
#pragma unroll
            for (int i = 0; i < 4; ++i) gload_lds16(vp[i] + kb2, vnxt + (i * 256 + tid) * 8);
        }

        f32x4 sfr[4];
#pragma unroll
        for (int ni = 0; ni < 4; ++ni) sfr[ni] = (f32x4){0.f, 0.f, 0.f, 0.f};
        __builtin_amdgcn_s_setprio(1);
#pragma unroll
        for (int ni = 0; ni < 4; ++ni) {
            const int r = ni * 16 + col;
#pragma unroll
            for (int s = 0; s < 4; ++s) {
                int sl = (s * 4 + quad) ^ (r & 15);
                short8 kf = *(const short8*)(kcur + r * 128 + sl * 8);
                sfr[ni] = __builtin_amdgcn_mfma_f32_16x16x32_bf16(qf[s], kf, sfr[ni], 0, 0, 0);
            }
        }
        __builtin_amdgcn_s_setprio(0);
        const bool diag = (kt == qt);
#pragma unroll
        for (int ni = 0; ni < 4; ++ni) {
            const int key = kb + ni * 16 + col;
#pragma unroll
            for (int rr = 0; rr < 4; ++rr) {
                float v = sfr[ni][rr] * scale;
                int qv = qbase + w * 16 + quad * 4 + rr;
                if (diag && key > qv) v = NEGBIG;
                sfr[ni][rr] = v;
            }
        }
        float mx[4];
#pragma unroll
        for (int rr = 0; rr < 4; ++rr)
            mx[rr] = fmaxf(fmaxf(sfr[0][rr], sfr[1][rr]), fmaxf(sfr[2][rr], sfr[3][rr]));
#pragma unroll
        for (int d = 1; d < 16; d <<= 1)
#pragma unroll
            for (int rr = 0; rr < 4; ++rr) mx[rr] = fmaxf(mx[rr], __shfl_xor(mx[rr], d));
        // strict defer-rescale: if no row's max grew, alpha==1 exactly -> skip.
        if (__any((mx[0] > mrow[0]) || (mx[1] > mrow[1]) ||
                  (mx[2] > mrow[2]) || (mx[3] > mrow[3]))) {
#pragma unroll
            for (int rr = 0; rr < 4; ++rr) {
                float mn = fmaxf(mrow[rr], mx[rr]);
                float a = __expf(mrow[rr] - mn);
                mrow[rr] = mn;
                lrow[rr] *= a;
#pragma unroll
                for (int i = 0; i < 8; ++i) oacc[i][rr] *= a;
            }
        }
        float rs[4] = {0.f, 0.f, 0.f, 0.f};
#pragma unroll
        for (int ni = 0; ni < 4; ++ni)
#pragma unroll
            for (int rr = 0; rr < 4; ++rr) {
                float p = __expf(sfr[ni][rr] - mrow[rr]);
                sfr[ni][rr] = p;
                rs[rr] += p;
            }
#pragma unroll
        for (int d = 1; d < 16; d <<= 1)
#pragma unroll
            for (int rr = 0; rr < 4; ++rr) rs[rr] += __shfl_xor(rs[rr], d);
#pragma unroll
        for (int rr = 0; rr < 4; ++rr) lrow[rr] += rs[rr];
        // P (C-layout) -> LDS -> A-layout (per-wave rows; no cross-wave dep, no barrier)
#pragma unroll
        for (int ni = 0; ni < 4; ++ni)
#pragma unroll
            for (int rr = 0; rr < 4; ++rr)
                p_lds[(w * 16 + quad * 4 + rr) * 72 + ni * 16 + col] = f2bf(sfr[ni][rr]);
        __builtin_amdgcn_s_setprio(1);
#pragma unroll
        for (int ks = 0; ks < 2; ++ks) {
            short8 pa = *(const short8*)(p_lds + (w * 16 + col) * 72 + ks * 32 + quad * 8);
#pragma unroll
            for (int di = 0; di < 8; ++di) {
                int r = di * 16 + col;
                int sl = (ks * 4 + quad) ^ (r & 7);
                short8 vb = *(const short8*)(vcur + r * 64 + sl * 8);
                oacc[di] = __builtin_amdgcn_mfma_f32_16x16x32_bf16(pa, vb, oacc[di], 0, 0, 0);
            }
        }
        __builtin_amdgcn_s_setprio(0);
        { u16* t = kcur; kcur = knxt; knxt = t; }
        { u16* t = vcur; vcur = vnxt; vnxt = t; }
    }
    const int b = bh >> 4, h = bh & 15;
#pragma unroll
    for (int di = 0; di < 8; ++di)
#pragma unroll
        for (int rr = 0; rr < 4; ++rr) {
            int trow = qbase + w * 16 + quad * 4 + rr;
            float ov = oacc[di][rr] / lrow[rr];
            O[((size_t)(b * TT + trow)) * DM + h * HD + di * 16 + col] = f2bf(ov);
        }
}

extern "C" void kernel_launch(void* const* d_in, const int* in_sizes, int n_in,
                              void* d_out, int out_size, void* d_ws, size_t ws_size,
                              hipStream_t stream) {
    const float* x    = (const float*)d_in[0];
    const float* rc   = (const float*)d_in[1];
    const float* anw  = (const float*)d_in[2];
    const float* qkvw = (const float*)d_in[3];
    const float* qnw  = (const float*)d_in[4];
    const float* knw  = (const float*)d_in[5];
    const float* opw  = (const float*)d_in[6];
    const float* mnw  = (const float*)d_in[7];
    const float* miw  = (const float*)d_in[8];
    const float* mow  = (const float*)d_in[9];

    char* ws = (char*)d_ws;
    // Workspace plan, 120 MiB peak (MiB offsets). Late-phase owners:
    //   hbuf[0,16) Wmi[16,48) Wmo[48,80) mbuf[80,112) Wo[112,120)
    // Early/mid aliases (dead before late owner is written):
    //   Wq[16,40)  qkv[48,96)  qh[96,112)  kh[112,128)  vh[0,16)  vt[16,32)  aout[32,48)
    // Residual x2 lives in d_out (f32), accumulated by the mlp_out halves.
    u16* hbuf = (u16*)(ws);
    u16* Wq   = (u16*)(ws + (16ll  << 20));
    u16* Wmi  = (u16*)(ws + (16ll  << 20));
    u16* vt   = (u16*)(ws + (16ll  << 20));
    u16* aout = (u16*)(ws + (32ll  << 20));
    u16* Wmo  = (u16*)(ws + (48ll  << 20));
    u16* qkv  = (u16*)(ws + (48ll  << 20));
    u16* mbuf = (u16*)(ws + (80ll  << 20));
    u16* qh   = (u16*)(ws + (96ll  << 20));
    u16* Wo   = (u16*)(ws + (112ll << 20));
    u16* kh   = (u16*)(ws + (112ll << 20));
    u16* vh   = (u16*)(ws);
    float* xo = (float*)d_out;

    rmsnorm_k<<<MR, 256, 0, stream>>>(x, anw, hbuf);
    cvt_w<<<6144, 256, 0, stream>>>(qkvw, Wq);                     // 3DM*DM
    gemm_bt<0><<<dim3(48, 32), 256, 0, stream>>>(hbuf, Wq, nullptr, qkv, MR, 3 * DM, DM, DM);
    rope_split_k<<<MR, 256, 0, stream>>>(qkv, rc, qnw, knw, qh, kh, vh);
    transpose_v<<<dim3(32, 2, 32), 256, 0, stream>>>(vh, vt);
    attn_k<<<dim3(32, 32), 256, 0, stream>>>(qh, kh, vt, aout);
    cvt_w<<<2048, 256, 0, stream>>>(opw, Wo);                      // DM*DM (kh dead)
    cvt_w<<<8192, 256, 0, stream>>>(mow, Wmo);                     // DM*FFN (qkv dead)
    gemm_bt<2><<<dim3(16, 32), 256, 0, stream>>>(aout, Wo, x, xo, MR, DM, DM, DM);
    rmsnorm_k<<<MR, 256, 0, stream>>>(xo, mnw, hbuf);
    cvt_w<<<8192, 256, 0, stream>>>(miw, Wmi);                     // FFN*DM (vt/aout dead)
    // MLP in two FFN halves; mbuf is 4096x4096 bf16, d_out accumulates in f32.
    gemm_bt<1><<<dim3(32, 32), 256, 0, stream>>>(hbuf, Wmi, nullptr, mbuf, MR, FFN / 2, DM, DM);
    gemm_bt<2><<<dim3(16, 32), 256, 0, stream>>>(mbuf, Wmo, xo, xo, MR, DM, FFN / 2, FFN);
    gemm_bt<1><<<dim3(32, 32), 256, 0, stream>>>(hbuf, Wmi + (size_t)(FFN / 2) * DM, nullptr, mbuf, MR, FFN / 2, DM, DM);
    gemm_bt<2><<<dim3(16, 32), 256, 0, stream>>>(mbuf, Wmo + FFN / 2, xo, xo, MR, DM, FFN / 2, FFN);
}

// Round 3
// 1047.358 us; speedup vs baseline: 1.3810x; 1.0129x over previous
//
#include <hip/hip_runtime.h>
#include <stdint.h>

#define TT 2048
#define DM 2048
#define NH 16
#define HD 128
#define FFN 8192
#define MR 4096   // B*T
#define EPSF 1.1920928955078125e-07f
#define NEGBIG (-1.0e30f)

typedef __attribute__((ext_vector_type(8))) short short8;
typedef __attribute__((ext_vector_type(4))) float f32x4;
typedef unsigned short u16;
typedef unsigned int u32;

__device__ __forceinline__ float bf2f(u32 u) {
    return __uint_as_float((u & 0xffffu) << 16);
}
__device__ __forceinline__ u16 f2bf(float f) {
    u32 x = __float_as_uint(f);
    return (u16)((x + 0x7fffu + ((x >> 16) & 1u)) >> 16);
}
__device__ __forceinline__ void load8f(const u16* p, float* v) {
    uint4 d = *(const uint4*)p;
    v[0] = bf2f(d.x); v[1] = bf2f(d.x >> 16);
    v[2] = bf2f(d.y); v[3] = bf2f(d.y >> 16);
    v[4] = bf2f(d.z); v[5] = bf2f(d.z >> 16);
    v[6] = bf2f(d.w); v[7] = bf2f(d.w >> 16);
}
__device__ __forceinline__ void load8f32(const float* p, float* v) {
    float4 a = *(const float4*)p, b = *(const float4*)(p + 4);
    v[0]=a.x; v[1]=a.y; v[2]=a.z; v[3]=a.w; v[4]=b.x; v[5]=b.y; v[6]=b.z; v[7]=b.w;
}
__device__ __forceinline__ void store8bf(u16* p, const float* v) {
    uint4 o;
    o.x = (u32)f2bf(v[0]) | ((u32)f2bf(v[1]) << 16);
    o.y = (u32)f2bf(v[2]) | ((u32)f2bf(v[3]) << 16);
    o.z = (u32)f2bf(v[4]) | ((u32)f2bf(v[5]) << 16);
    o.w = (u32)f2bf(v[6]) | ((u32)f2bf(v[7]) << 16);
    *(uint4*)p = o;
}
__device__ __forceinline__ uint4 cvt8_f32_bf16(const float* p) {
    float4 a = *(const float4*)p, b = *(const float4*)(p + 4);
    uint4 o;
    o.x = (u32)f2bf(a.x) | ((u32)f2bf(a.y) << 16);
    o.y = (u32)f2bf(a.z) | ((u32)f2bf(a.w) << 16);
    o.z = (u32)f2bf(b.x) | ((u32)f2bf(b.y) << 16);
    o.w = (u32)f2bf(b.z) | ((u32)f2bf(b.w) << 16);
    return o;
}
__device__ __forceinline__ void gload_lds16(const void* g, void* l) {
    __builtin_amdgcn_global_load_lds((const __attribute__((address_space(1))) u32*)g,
                                     (__attribute__((address_space(3))) u32*)l, 16, 0, 0);
}

// ---------------- weight f32 -> bf16 (8 elems/thread) ----------------
__global__ __launch_bounds__(256)
void cvt_w(const float* __restrict__ S, u16* __restrict__ D) {
    size_t i = ((size_t)blockIdx.x * 256 + threadIdx.x) * 8;
    *(uint4*)(D + i) = cvt8_f32_bf16(S + i);
}

// ---------------- RMSNorm (f32 in, bf16 out): one block per row of 2048 ----------------
__global__ __launch_bounds__(256)
void rmsnorm_k(const float* __restrict__ X, const float* __restrict__ W, u16* __restrict__ O) {
    const int row = blockIdx.x, tid = threadIdx.x;
    float v[8];
    load8f32(X + (size_t)row * DM + tid * 8, v);
    float ssq = 0.f;
#pragma unroll
    for (int i = 0; i < 8; ++i) ssq += v[i] * v[i];
#pragma unroll
    for (int d = 1; d < 64; d <<= 1) ssq += __shfl_xor(ssq, d);
    __shared__ float red[4];
    if ((tid & 63) == 0) red[tid >> 6] = ssq;
    __syncthreads();
    ssq = red[0] + red[1] + red[2] + red[3];
    const float inv = rsqrtf(ssq * (1.f / DM) + EPSF);
    float wv[8], o[8];
    load8f32(W + tid * 8, wv);
#pragma unroll
    for (int i = 0; i < 8; ++i) o[i] = v[i] * inv * wv[i];
    store8bf(O + (size_t)row * DM + tid * 8, o);
}

// ---------------- GEMM 128x128 (m97 structure), for small-N GEMMs ----------------
// EPI: 0 = bf16 out, 1 = relu^2 bf16 out, 2 = + f32 Res -> f32 out
template<int EPI>
__global__ __launch_bounds__(256)
void gemm_bt(const u16* __restrict__ A, const u16* __restrict__ Bw,
             const float* __restrict__ Res, void* __restrict__ Cp,
             int M, int N, int K, int ldb) {
    __shared__ alignas(16) u16 As[128 * 32];
    __shared__ alignas(16) u16 Bs[128 * 32];
    const int tid = threadIdx.x;
    const int lane = tid & 63, w = tid >> 6;
    const int quad = lane >> 4, col = lane & 15;
    const int n0 = blockIdx.x * 128, m0 = blockIdx.y * 128;
    const int wm = (w >> 1) * 64, wn = (w & 1) * 64;

    const int c0 = tid, c1 = tid + 256;
    const int ar0 = c0 >> 2, aq0 = (c0 & 3) ^ ((ar0 >> 1) & 3);
    const int ar1 = c1 >> 2, aq1 = (c1 & 3) ^ ((ar1 >> 1) & 3);
    const u16* agp0 = A  + (size_t)(m0 + ar0) * K + aq0 * 8;
    const u16* agp1 = A  + (size_t)(m0 + ar1) * K + aq1 * 8;
    const u16* bgp0 = Bw + (size_t)(n0 + ar0) * ldb + aq0 * 8;
    const u16* bgp1 = Bw + (size_t)(n0 + ar1) * ldb + aq1 * 8;
    u16* al0 = As + c0 * 8; u16* al1 = As + c1 * 8;
    u16* bl0 = Bs + c0 * 8; u16* bl1 = Bs + c1 * 8;

    int aoff[4], boff[4];
#pragma unroll
    for (int i = 0; i < 4; ++i) {
        int r = wm + i * 16 + col;
        aoff[i] = r * 32 + (quad ^ ((r >> 1) & 3)) * 8;
        r = wn + i * 16 + col;
        boff[i] = r * 32 + (quad ^ ((r >> 1) & 3)) * 8;
    }

    f32x4 acc[4][4];
#pragma unroll
    for (int i = 0; i < 4; ++i)
#pragma unroll
        for (int j = 0; j < 4; ++j) acc[i][j] = (f32x4){0.f, 0.f, 0.f, 0.f};

    for (int kt = 0; kt < K; kt += 32) {
        __syncthreads();
        gload_lds16(agp0 + kt, al0);
        gload_lds16(agp1 + kt, al1);
        gload_lds16(bgp0 + kt, bl0);
        gload_lds16(bgp1 + kt, bl1);
        __syncthreads();
        short8 af[4], bfr[4];
#pragma unroll
        for (int i = 0; i < 4; ++i) af[i] = *(const short8*)(As + aoff[i]);
#pragma unroll
        for (int i = 0; i < 4; ++i) bfr[i] = *(const short8*)(Bs + boff[i]);
#pragma unroll
        for (int mi = 0; mi < 4; ++mi)
#pragma unroll
            for (int ni = 0; ni < 4; ++ni)
                acc[mi][ni] = __builtin_amdgcn_mfma_f32_16x16x32_bf16(af[mi], bfr[ni], acc[mi][ni], 0, 0, 0);
    }

#pragma unroll
    for (int mi = 0; mi < 4; ++mi)
#pragma unroll
        for (int ni = 0; ni < 4; ++ni) {
            const int rbase = m0 + wm + mi * 16 + quad * 4;
            const int cc = n0 + wn + ni * 16 + col;
#pragma unroll
            for (int rr = 0; rr < 4; ++rr) {
                float v = acc[mi][ni][rr];
                size_t idx = (size_t)(rbase + rr) * N + cc;
                if (EPI == 0) ((u16*)Cp)[idx] = f2bf(v);
                else if (EPI == 1) { float t = fmaxf(v, 0.f); ((u16*)Cp)[idx] = f2bf(t * t); }
                else ((float*)Cp)[idx] = v + Res[idx];
            }
        }
}

// ---------------- GEMM 256x256, 8 waves, 4-deep LDS ring, counted vmcnt ----------------
// T3+T4: one barrier per K-step (BK=32); stage step t+3 while computing step t;
// vmcnt(8) steady-state (never drain); fragment/staging math identical to gemm_bt.
// LDS: 4 buffers x (A 16KB + B 16KB) = 128 KiB -> 1 block/CU, 8 waves.
template<int EPI>
__global__ __launch_bounds__(512, 2)
void gemm_big(const u16* __restrict__ A, const u16* __restrict__ Bw,
              void* __restrict__ Cp, int M, int N, int K, int ldb) {
    __shared__ alignas(16) u16 As[4][256 * 32];
    __shared__ alignas(16) u16 Bs[4][256 * 32];
    const int tid = threadIdx.x;
    const int lane = tid & 63, w = tid >> 6;
    const int wr = w >> 2, wc = w & 3;              // 2M x 4N wave grid
    const int quad = lane >> 4, colL = lane & 15;

    // XCD-aware swizzle (grid sizes here are multiples of 8)
    const int nbx = N >> 8;
    const int nwg = gridDim.x;
    const int cpx = nwg >> 3;
    const int bid = blockIdx.x;
    const int swz = (bid & 7) * cpx + (bid >> 3);
    const int by = swz / nbx, bx = swz - by * nbx;
    const int m0 = by << 8, n0 = bx << 8;

    // staging: 1024 16B-chunks per matrix per K-step; thread covers chunks tid, tid+512.
    // LDS slot s of row r holds global chunk q = s ^ ((r>>1)&3)  (same as gemm_bt).
    const int r0 = tid >> 2,       q0 = (tid & 3) ^ ((r0 >> 1) & 3);
    const int p1 = tid + 512;
    const int r1 = p1 >> 2,        q1 = (p1 & 3) ^ ((r1 >> 1) & 3);
    const u16* agp0 = A  + (size_t)(m0 + r0) * K   + q0 * 8;
    const u16* agp1 = A  + (size_t)(m0 + r1) * K   + q1 * 8;
    const u16* bgp0 = Bw + (size_t)(n0 + r0) * ldb + q0 * 8;
    const u16* bgp1 = Bw + (size_t)(n0 + r1) * ldb + q1 * 8;
    const int l0 = tid * 8, l1 = p1 * 8;

    int aoff[8], boff[4];
#pragma unroll
    for (int mi = 0; mi < 8; ++mi) {
        int r = wr * 128 + mi * 16 + colL;
        aoff[mi] = r * 32 + (quad ^ ((r >> 1) & 3)) * 8;
    }
#pragma unroll
    for (int ni = 0; ni < 4; ++ni) {
        int r = wc * 64 + ni * 16 + colL;
        boff[ni] = r * 32 + (quad ^ ((r >> 1) & 3)) * 8;
    }

    f32x4 acc[8][4];
#pragma unroll
    for (int i = 0; i < 8; ++i)
#pragma unroll
        for (int j = 0; j < 4; ++j) acc[i][j] = (f32x4){0.f, 0.f, 0.f, 0.f};

    const int KT = K >> 5;

#define GB_STAGE(s) { const int _b = (s) & 3; const size_t _ko = (size_t)(s) * 32; \
    gload_lds16(agp0 + _ko, &As[_b][l0]); \
    gload_lds16(agp1 + _ko, &As[_b][l1]); \
    gload_lds16(bgp0 + _ko, &Bs[_b][l0]); \
    gload_lds16(bgp1 + _ko, &Bs[_b][l1]); }

    // prologue: stage steps 0,1,2 (12 loads in flight)
    GB_STAGE(0);
    GB_STAGE(1);
    GB_STAGE(2);

    for (int t = 0; t < KT; ++t) {
        const int rem = KT - 1 - t;
        // in-order vmcnt: <=4*rem_prefetched outstanding => step t's 4 loads retired
        if (rem >= 2)      asm volatile("s_waitcnt vmcnt(8)" ::: "memory");
        else if (rem == 1) asm volatile("s_waitcnt vmcnt(4)" ::: "memory");
        else               asm volatile("s_waitcnt vmcnt(0)" ::: "memory");
        __builtin_amdgcn_s_barrier();
        // stage step t+3 into buf[(t+3)&3] == buf[(t-1)&3]: all reads of it retired
        // before every wave's arrival at the barrier above.
        if (t + 3 < KT) GB_STAGE(t + 3);
        const u16* ab = As[t & 3];
        const u16* bb = Bs[t & 3];
        short8 af[8], bfr[4];
#pragma unroll
        for (int mi = 0; mi < 8; ++mi) af[mi] = *(const short8*)(ab + aoff[mi]);
#pragma unroll
        for (int ni = 0; ni < 4; ++ni) bfr[ni] = *(const short8*)(bb + boff[ni]);
        __builtin_amdgcn_s_setprio(1);
#pragma unroll
        for (int mi = 0; mi < 8; ++mi)
#pragma unroll
            for (int ni = 0; ni < 4; ++ni)
                acc[mi][ni] = __builtin_amdgcn_mfma_f32_16x16x32_bf16(af[mi], bfr[ni], acc[mi][ni], 0, 0, 0);
        __builtin_amdgcn_s_setprio(0);
        __builtin_amdgcn_sched_barrier(0);   // pin MFMAs: none may sink past the next barrier
    }
#undef GB_STAGE

#pragma unroll
    for (int mi = 0; mi < 8; ++mi)
#pragma unroll
        for (int ni = 0; ni < 4; ++ni) {
            const int rbase = m0 + wr * 128 + mi * 16 + quad * 4;
            const int cc = n0 + wc * 64 + ni * 16 + colL;
#pragma unroll
            for (int rr = 0; rr < 4; ++rr) {
                float v = acc[mi][ni][rr];
                size_t idx = (size_t)(rbase + rr) * N + cc;
                if (EPI == 0) ((u16*)Cp)[idx] = f2bf(v);
                else { float tq = fmaxf(v, 0.f); ((u16*)Cp)[idx] = f2bf(tq * tq); }
            }
        }
}

// ---------------- RoPE + per-head RMSNorm on q,k; split v ----------------
__global__ __launch_bounds__(256)
void rope_split_k(const u16* __restrict__ QKV, const float* __restrict__ RC,
                  const float* __restrict__ QW, const float* __restrict__ KW,
                  u16* __restrict__ Qo, u16* __restrict__ Ko, u16* __restrict__ Vo) {
    const int row = blockIdx.x;                 // b*T + t
    const int t = row & (TT - 1), b = row >> 11;
    const int tid = threadIdx.x, h = tid >> 4, j = tid & 15;
    const size_t qb = (size_t)row * (3 * DM) + h * HD + j * 8;
    float q[8], k[8], cs[8], sn[8];
    load8f(QKV + qb, q);
    load8f(QKV + qb + DM, k);
    uint4 vv = *(const uint4*)(QKV + qb + 2 * DM);
    load8f32(RC + (size_t)t * HD + j * 8, cs);
    load8f32(RC + (size_t)(TT + t) * HD + j * 8, sn);
    float qr[8], kr[8];
#pragma unroll
    for (int p = 0; p < 4; ++p) {
        float c = cs[2 * p], s = sn[2 * p];
        qr[2*p]   = q[2*p]   * c - q[2*p+1] * s;
        qr[2*p+1] = q[2*p+1] * c + q[2*p]   * s;
        kr[2*p]   = k[2*p]   * c - k[2*p+1] * s;
        kr[2*p+1] = k[2*p+1] * c + k[2*p]   * s;
    }
    float sq = 0.f, sk = 0.f;
#pragma unroll
    for (int i = 0; i < 8; ++i) { sq += qr[i] * qr[i]; sk += kr[i] * kr[i]; }
#pragma unroll
    for (int d = 1; d < 16; d <<= 1) { sq += __shfl_xor(sq, d); sk += __shfl_xor(sk, d); }
    const float iq = rsqrtf(sq * (1.f / HD) + EPSF);
    const float ik = rsqrtf(sk * (1.f / HD) + EPSF);
    float qw[8], kw[8], oq[8], ok[8];
    load8f32(QW + j * 8, qw); load8f32(KW + j * 8, kw);
#pragma unroll
    for (int i = 0; i < 8; ++i) { oq[i] = qr[i] * iq * qw[i]; ok[i] = kr[i] * ik * kw[i]; }
    const size_t ob = ((size_t)(b * NH + h) * TT + t) * HD + j * 8;
    store8bf(Qo + ob, oq);
    store8bf(Ko + ob, ok);
    *(uint4*)(Vo + ob) = vv;
}

// ---------------- V transpose: [bh][T][128] -> [bh][128][T] ----------------
__global__ __launch_bounds__(256)
void transpose_v(const u16* __restrict__ V, u16* __restrict__ Vt) {
    __shared__ alignas(16) u16 tile[64][72];
    const int bh = blockIdx.z;
    const int t0 = blockIdx.x * 64, d0 = blockIdx.y * 64;
    const int tid = threadIdx.x;
#pragma unroll
    for (int i = 0; i < 2; ++i) {
        int c = i * 256 + tid;
        int r = c >> 3, cc = (c & 7) * 8;
        *(uint4*)(&tile[r][cc]) = *(const uint4*)(V + ((size_t)bh * TT + t0 + r) * HD + d0 + cc);
    }
    __syncthreads();
#pragma unroll
    for (int i = 0; i < 2; ++i) {
        int c = i * 256 + tid;
        int dc = c >> 3, rr = (c & 7) * 8;
        u16 tmp[8];
#pragma unroll
        for (int kk = 0; kk < 8; ++kk) tmp[kk] = tile[rr + kk][dc];
        uint4 o;
        o.x = (u32)tmp[0] | ((u32)tmp[1] << 16);
        o.y = (u32)tmp[2] | ((u32)tmp[3] << 16);
        o.z = (u32)tmp[4] | ((u32)tmp[5] << 16);
        o.w = (u32)tmp[6] | ((u32)tmp[7] << 16);
        *(uint4*)(Vt + ((size_t)bh * HD + d0 + dc) * TT + t0 + rr) = o;
    }
}

// ---------------- Causal flash attention, 64-query tile per block ----------------
// v3: double-buffered LDS staging via global_load_lds (async, zero VGPR cost).
__global__ __launch_bounds__(256)
void attn_k(const u16* __restrict__ Q, const u16* __restrict__ Kg,
            const u16* __restrict__ Vt, u16* __restrict__ O) {
    __shared__ alignas(16) u16 k_lds[2][64 * 128];
    __shared__ alignas(16) u16 v_lds[2][128 * 64];
    __shared__ alignas(16) u16 p_lds[4 * 16 * 72];
    const int qt = gridDim.x - 1 - blockIdx.x;   // long blocks first
    const int bh = blockIdx.y;
    const int tid = threadIdx.x, lane = tid & 63, w = tid >> 6;
    const int quad = lane >> 4, col = lane & 15;
    const int qbase = qt * 64;
    const int qrow = qbase + w * 16 + col;

    short8 qf[4];
    const u16* qp = Q + ((size_t)bh * TT + qrow) * HD;
#pragma unroll
    for (int s = 0; s < 4; ++s) qf[s] = *(const short8*)(qp + s * 32 + quad * 8);

    const u16* kp[4]; const u16* vp[4];
#pragma unroll
    for (int i = 0; i < 4; ++i) {
        int lin = i * 256 + tid;
        int r = lin >> 4, sl = lin & 15;
        int gq = sl ^ (r & 15);
        kp[i] = Kg + ((size_t)bh * TT + r) * HD + gq * 8;
    }
#pragma unroll
    for (int i = 0; i < 4; ++i) {
        int lin = i * 256 + tid;
        int r = lin >> 3, sl = lin & 7;
        int gq = sl ^ (r & 7);
        vp[i] = Vt + ((size_t)bh * HD + r) * TT + gq * 8;
    }

    f32x4 oacc[8];
#pragma unroll
    for (int i = 0; i < 8; ++i) oacc[i] = (f32x4){0.f, 0.f, 0.f, 0.f};
    float mrow[4] = {NEGBIG, NEGBIG, NEGBIG, NEGBIG};
    float lrow[4] = {0.f, 0.f, 0.f, 0.f};
    const float scale = 0.08838834764831845f;   // 1/sqrt(128)

    u16* kcur = k_lds[0]; u16* knxt = k_lds[1];
    u16* vcur = v_lds[0]; u16* vnxt = v_lds[1];
#pragma unroll
    for (int i = 0; i < 4; ++i) gload_lds16(kp[i], kcur + (i * 256 + tid) * 8);
#pragma unroll
    for (int i = 0; i < 4; ++i) gload_lds16(vp[i], vcur + (i * 256 + tid) * 8);

    for (int kt = 0; kt <= qt; ++kt) {
        const int kb = kt * 64;
        __syncthreads();   // drains vmcnt(0): buf[cur] staged, buf[nxt] reads done

        if (kt < qt) {     // prefetch tile kt+1 into the other buffer (async)
            const int kb2 = kb + 64;
#pragma unroll
            for (int i = 0; i < 4; ++i) gload_lds16(kp[i] + (size_t)kb2 * HD, knxt + (i * 256 + tid) * 8);
#pragma unroll
            for (int i = 0; i < 4; ++i) gload_lds16(vp[i] + kb2, vnxt + (i * 256 + tid) * 8);
        }

        f32x4 sfr[4];
#pragma unroll
        for (int ni = 0; ni < 4; ++ni) sfr[ni] = (f32x4){0.f, 0.f, 0.f, 0.f};
        __builtin_amdgcn_s_setprio(1);
#pragma unroll
        for (int ni = 0; ni < 4; ++ni) {
            const int r = ni * 16 + col;
#pragma unroll
            for (int s = 0; s < 4; ++s) {
                int sl = (s * 4 + quad) ^ (r & 15);
                short8 kf = *(const short8*)(kcur + r * 128 + sl * 8);
                sfr[ni] = __builtin_amdgcn_mfma_f32_16x16x32_bf16(qf[s], kf, sfr[ni], 0, 0, 0);
            }
        }
        __builtin_amdgcn_s_setprio(0);
        const bool diag = (kt == qt);
#pragma unroll
        for (int ni = 0; ni < 4; ++ni) {
            const int key = kb + ni * 16 + col;
#pragma unroll
            for (int rr = 0; rr < 4; ++rr) {
                float v = sfr[ni][rr] * scale;
                int qv = qbase + w * 16 + quad * 4 + rr;
                if (diag && key > qv) v = NEGBIG;
                sfr[ni][rr] = v;
            }
        }
        float mx[4];
#pragma unroll
        for (int rr = 0; rr < 4; ++rr)
            mx[rr] = fmaxf(fmaxf(sfr[0][rr], sfr[1][rr]), fmaxf(sfr[2][rr], sfr[3][rr]));
#pragma unroll
        for (int d = 1; d < 16; d <<= 1)
#pragma unroll
            for (int rr = 0; rr < 4; ++rr) mx[rr] = fmaxf(mx[rr], __shfl_xor(mx[rr], d));
        if (__any((mx[0] > mrow[0]) || (mx[1] > mrow[1]) ||
                  (mx[2] > mrow[2]) || (mx[3] > mrow[3]))) {
#pragma unroll
            for (int rr = 0; rr < 4; ++rr) {
                float mn = fmaxf(mrow[rr], mx[rr]);
                float a = __expf(mrow[rr] - mn);
                mrow[rr] = mn;
                lrow[rr] *= a;
#pragma unroll
                for (int i = 0; i < 8; ++i) oacc[i][rr] *= a;
            }
        }
        float rs[4] = {0.f, 0.f, 0.f, 0.f};
#pragma unroll
        for (int ni = 0; ni < 4; ++ni)
#pragma unroll
            for (int rr = 0; rr < 4; ++rr) {
                float p = __expf(sfr[ni][rr] - mrow[rr]);
                sfr[ni][rr] = p;
                rs[rr] += p;
            }
#pragma unroll
        for (int d = 1; d < 16; d <<= 1)
#pragma unroll
            for (int rr = 0; rr < 4; ++rr) rs[rr] += __shfl_xor(rs[rr], d);
#pragma unroll
        for (int rr = 0; rr < 4; ++rr) lrow[rr] += rs[rr];
#pragma unroll
        for (int ni = 0; ni < 4; ++ni)
#pragma unroll
            for (int rr = 0; rr < 4; ++rr)
                p_lds[(w * 16 + quad * 4 + rr) * 72 + ni * 16 + col] = f2bf(sfr[ni][rr]);
        __builtin_amdgcn_s_setprio(1);
#pragma unroll
        for (int ks = 0; ks < 2; ++ks) {
            short8 pa = *(const short8*)(p_lds + (w * 16 + col) * 72 + ks * 32 + quad * 8);
#pragma unroll
            for (int di = 0; di < 8; ++di) {
                int r = di * 16 + col;
                int sl = (ks * 4 + quad) ^ (r & 7);
                short8 vb = *(const short8*)(vcur + r * 64 + sl * 8);
                oacc[di] = __builtin_amdgcn_mfma_f32_16x16x32_bf16(pa, vb, oacc[di], 0, 0, 0);
            }
        }
        __builtin_amdgcn_s_setprio(0);
        { u16* t = kcur; kcur = knxt; knxt = t; }
        { u16* t = vcur; vcur = vnxt; vnxt = t; }
    }
    const int b = bh >> 4, h = bh & 15;
#pragma unroll
    for (int di = 0; di < 8; ++di)
#pragma unroll
        for (int rr = 0; rr < 4; ++rr) {
            int trow = qbase + w * 16 + quad * 4 + rr;
            float ov = oacc[di][rr] / lrow[rr];
            O[((size_t)(b * TT + trow)) * DM + h * HD + di * 16 + col] = f2bf(ov);
        }
}

extern "C" void kernel_launch(void* const* d_in, const int* in_sizes, int n_in,
                              void* d_out, int out_size, void* d_ws, size_t ws_size,
                              hipStream_t stream) {
    const float* x    = (const float*)d_in[0];
    const float* rc   = (const float*)d_in[1];
    const float* anw  = (const float*)d_in[2];
    const float* qkvw = (const float*)d_in[3];
    const float* qnw  = (const float*)d_in[4];
    const float* knw  = (const float*)d_in[5];
    const float* opw  = (const float*)d_in[6];
    const float* mnw  = (const float*)d_in[7];
    const float* miw  = (const float*)d_in[8];
    const float* mow  = (const float*)d_in[9];

    char* ws = (char*)d_ws;
    // Workspace plan, 120 MiB peak (MiB offsets). Late-phase owners:
    //   hbuf[0,16) Wmi[16,48) Wmo[48,80) mbuf[80,112) Wo[112,120)
    // Early/mid aliases (dead before late owner is written):
    //   Wq[16,40)  qkv[48,96)  qh[96,112)  kh[112,128)  vh[0,16)  vt[16,32)  aout[32,48)
    // Residual x2 lives in d_out (f32), accumulated by the mlp_out halves.
    u16* hbuf = (u16*)(ws);
    u16* Wq   = (u16*)(ws + (16ll  << 20));
    u16* Wmi  = (u16*)(ws + (16ll  << 20));
    u16* vt   = (u16*)(ws + (16ll  << 20));
    u16* aout = (u16*)(ws + (32ll  << 20));
    u16* Wmo  = (u16*)(ws + (48ll  << 20));
    u16* qkv  = (u16*)(ws + (48ll  << 20));
    u16* mbuf = (u16*)(ws + (80ll  << 20));
    u16* qh   = (u16*)(ws + (96ll  << 20));
    u16* Wo   = (u16*)(ws + (112ll << 20));
    u16* kh   = (u16*)(ws + (112ll << 20));
    u16* vh   = (u16*)(ws);
    float* xo = (float*)d_out;

    rmsnorm_k<<<MR, 256, 0, stream>>>(x, anw, hbuf);
    cvt_w<<<6144, 256, 0, stream>>>(qkvw, Wq);                     // 3DM*DM
    gemm_big<0><<<384, 512, 0, stream>>>(hbuf, Wq, qkv, MR, 3 * DM, DM, DM);
    rope_split_k<<<MR, 256, 0, stream>>>(qkv, rc, qnw, knw, qh, kh, vh);
    transpose_v<<<dim3(32, 2, 32), 256, 0, stream>>>(vh, vt);
    attn_k<<<dim3(32, 32), 256, 0, stream>>>(qh, kh, vt, aout);
    cvt_w<<<2048, 256, 0, stream>>>(opw, Wo);                      // DM*DM (kh dead)
    cvt_w<<<8192, 256, 0, stream>>>(mow, Wmo);                     // DM*FFN (qkv dead)
    gemm_bt<2><<<dim3(16, 32), 256, 0, stream>>>(aout, Wo, x, xo, MR, DM, DM, DM);
    rmsnorm_k<<<MR, 256, 0, stream>>>(xo, mnw, hbuf);
    cvt_w<<<8192, 256, 0, stream>>>(miw, Wmi);                     // FFN*DM (vt/aout dead)
    // MLP in two FFN halves; mbuf is 4096x4096 bf16, d_out accumulates in f32.
    gemm_big<1><<<256, 512, 0, stream>>>(hbuf, Wmi, mbuf, MR, FFN / 2, DM, DM);
    gemm_bt<2><<<dim3(16, 32), 256, 0, stream>>>(mbuf, Wmo, xo, xo, MR, DM, FFN / 2, FFN);
    gemm_big<1><<<256, 512, 0, stream>>>(hbuf, Wmi + (size_t)(FFN / 2) * DM, mbuf, MR, FFN / 2, DM, DM);
    gemm_bt<2><<<dim3(16, 32), 256, 0, stream>>>(mbuf, Wmo + FFN / 2, xo, xo, MR, DM, FFN / 2, FFN);
}

// Round 4
// 995.718 us; speedup vs baseline: 1.4526x; 1.0519x over previous
//
#include <hip/hip_runtime.h>
#include <stdint.h>

#define TT 2048
#define DM 2048
#define NH 16
#define HD 128
#define FFN 8192
#define MR 4096   // B*T
#define EPSF 1.1920928955078125e-07f
#define NEGBIG (-1.0e30f)

typedef __attribute__((ext_vector_type(8))) short short8;
typedef __attribute__((ext_vector_type(4))) float f32x4;
typedef unsigned short u16;
typedef unsigned int u32;

__device__ __forceinline__ float bf2f(u32 u) {
    return __uint_as_float((u & 0xffffu) << 16);
}
__device__ __forceinline__ u16 f2bf(float f) {
    u32 x = __float_as_uint(f);
    return (u16)((x + 0x7fffu + ((x >> 16) & 1u)) >> 16);
}
__device__ __forceinline__ void load8f(const u16* p, float* v) {
    uint4 d = *(const uint4*)p;
    v[0] = bf2f(d.x); v[1] = bf2f(d.x >> 16);
    v[2] = bf2f(d.y); v[3] = bf2f(d.y >> 16);
    v[4] = bf2f(d.z); v[5] = bf2f(d.z >> 16);
    v[6] = bf2f(d.w); v[7] = bf2f(d.w >> 16);
}
__device__ __forceinline__ void load8f32(const float* p, float* v) {
    float4 a = *(const float4*)p, b = *(const float4*)(p + 4);
    v[0]=a.x; v[1]=a.y; v[2]=a.z; v[3]=a.w; v[4]=b.x; v[5]=b.y; v[6]=b.z; v[7]=b.w;
}
__device__ __forceinline__ void store8bf(u16* p, const float* v) {
    uint4 o;
    o.x = (u32)f2bf(v[0]) | ((u32)f2bf(v[1]) << 16);
    o.y = (u32)f2bf(v[2]) | ((u32)f2bf(v[3]) << 16);
    o.z = (u32)f2bf(v[4]) | ((u32)f2bf(v[5]) << 16);
    o.w = (u32)f2bf(v[6]) | ((u32)f2bf(v[7]) << 16);
    *(uint4*)p = o;
}
__device__ __forceinline__ uint4 cvt8_f32_bf16(const float* p) {
    float4 a = *(const float4*)p, b = *(const float4*)(p + 4);
    uint4 o;
    o.x = (u32)f2bf(a.x) | ((u32)f2bf(a.y) << 16);
    o.y = (u32)f2bf(a.z) | ((u32)f2bf(a.w) << 16);
    o.z = (u32)f2bf(b.x) | ((u32)f2bf(b.y) << 16);
    o.w = (u32)f2bf(b.z) | ((u32)f2bf(b.w) << 16);
    return o;
}
__device__ __forceinline__ void gload_lds16(const void* g, void* l) {
    __builtin_amdgcn_global_load_lds((const __attribute__((address_space(1))) u32*)g,
                                     (__attribute__((address_space(3))) u32*)l, 16, 0, 0);
}

// ---------------- weight f32 -> bf16 (8 elems/thread) ----------------
__global__ __launch_bounds__(256)
void cvt_w(const float* __restrict__ S, u16* __restrict__ D) {
    size_t i = ((size_t)blockIdx.x * 256 + threadIdx.x) * 8;
    *(uint4*)(D + i) = cvt8_f32_bf16(S + i);
}

// ---------------- RMSNorm (f32 in, bf16 out): one block per row of 2048 ----------------
__global__ __launch_bounds__(256)
void rmsnorm_k(const float* __restrict__ X, const float* __restrict__ W, u16* __restrict__ O) {
    const int row = blockIdx.x, tid = threadIdx.x;
    float v[8];
    load8f32(X + (size_t)row * DM + tid * 8, v);
    float ssq = 0.f;
#pragma unroll
    for (int i = 0; i < 8; ++i) ssq += v[i] * v[i];
#pragma unroll
    for (int d = 1; d < 64; d <<= 1) ssq += __shfl_xor(ssq, d);
    __shared__ float red[4];
    if ((tid & 63) == 0) red[tid >> 6] = ssq;
    __syncthreads();
    ssq = red[0] + red[1] + red[2] + red[3];
    const float inv = rsqrtf(ssq * (1.f / DM) + EPSF);
    float wv[8], o[8];
    load8f32(W + tid * 8, wv);
#pragma unroll
    for (int i = 0; i < 8; ++i) o[i] = v[i] * inv * wv[i];
    store8bf(O + (size_t)row * DM + tid * 8, o);
}

// ---------------- GEMM 128x128, 4-deep LDS ring, counted vmcnt, 2 blocks/CU ----------
// Ring schedule at the m97 tile size: isolates schedule-vs-tile (vs gemm_big 256²).
// EPI: 0 = bf16 out, 1 = relu^2 bf16 out, 2 = + f32 Res -> f32 out
template<int EPI>
__global__ __launch_bounds__(256, 2)
void gemm_ring(const u16* __restrict__ A, const u16* __restrict__ Bw,
               const float* __restrict__ Res, void* __restrict__ Cp,
               int M, int N, int K, int ldb) {
    __shared__ alignas(16) u16 As[4][128 * 32];
    __shared__ alignas(16) u16 Bs[4][128 * 32];
    const int tid = threadIdx.x;
    const int lane = tid & 63, w = tid >> 6;
    const int quad = lane >> 4, col = lane & 15;
    const int n0 = blockIdx.x * 128, m0 = blockIdx.y * 128;
    const int wm = (w >> 1) * 64, wn = (w & 1) * 64;

    const int c0 = tid, c1 = tid + 256;
    const int ar0 = c0 >> 2, aq0 = (c0 & 3) ^ ((ar0 >> 1) & 3);
    const int ar1 = c1 >> 2, aq1 = (c1 & 3) ^ ((ar1 >> 1) & 3);
    const u16* agp0 = A  + (size_t)(m0 + ar0) * K + aq0 * 8;
    const u16* agp1 = A  + (size_t)(m0 + ar1) * K + aq1 * 8;
    const u16* bgp0 = Bw + (size_t)(n0 + ar0) * ldb + aq0 * 8;
    const u16* bgp1 = Bw + (size_t)(n0 + ar1) * ldb + aq1 * 8;
    const int l0 = c0 * 8, l1 = c1 * 8;

    int aoff[4], boff[4];
#pragma unroll
    for (int i = 0; i < 4; ++i) {
        int r = wm + i * 16 + col;
        aoff[i] = r * 32 + (quad ^ ((r >> 1) & 3)) * 8;
        r = wn + i * 16 + col;
        boff[i] = r * 32 + (quad ^ ((r >> 1) & 3)) * 8;
    }

    f32x4 acc[4][4];
#pragma unroll
    for (int i = 0; i < 4; ++i)
#pragma unroll
        for (int j = 0; j < 4; ++j) acc[i][j] = (f32x4){0.f, 0.f, 0.f, 0.f};

    const int KT = K >> 5;

#define GR_STAGE(s) { const int _b = (s) & 3; const size_t _ko = (size_t)(s) * 32; \
    gload_lds16(agp0 + _ko, &As[_b][l0]); \
    gload_lds16(agp1 + _ko, &As[_b][l1]); \
    gload_lds16(bgp0 + _ko, &Bs[_b][l0]); \
    gload_lds16(bgp1 + _ko, &Bs[_b][l1]); }

    GR_STAGE(0);
    GR_STAGE(1);
    GR_STAGE(2);

    for (int t = 0; t < KT; ++t) {
        const int rem = KT - 1 - t;
        if (rem >= 2)      asm volatile("s_waitcnt vmcnt(8)" ::: "memory");
        else if (rem == 1) asm volatile("s_waitcnt vmcnt(4)" ::: "memory");
        else               asm volatile("s_waitcnt vmcnt(0)" ::: "memory");
        __builtin_amdgcn_s_barrier();
        if (t + 3 < KT) GR_STAGE(t + 3);
        const u16* ab = As[t & 3];
        const u16* bb = Bs[t & 3];
        short8 af[4], bfr[4];
#pragma unroll
        for (int i = 0; i < 4; ++i) af[i] = *(const short8*)(ab + aoff[i]);
#pragma unroll
        for (int i = 0; i < 4; ++i) bfr[i] = *(const short8*)(bb + boff[i]);
        __builtin_amdgcn_s_setprio(1);
#pragma unroll
        for (int mi = 0; mi < 4; ++mi)
#pragma unroll
            for (int ni = 0; ni < 4; ++ni)
                acc[mi][ni] = __builtin_amdgcn_mfma_f32_16x16x32_bf16(af[mi], bfr[ni], acc[mi][ni], 0, 0, 0);
        __builtin_amdgcn_s_setprio(0);
        __builtin_amdgcn_sched_barrier(0);
    }
#undef GR_STAGE

#pragma unroll
    for (int mi = 0; mi < 4; ++mi)
#pragma unroll
        for (int ni = 0; ni < 4; ++ni) {
            const int rbase = m0 + wm + mi * 16 + quad * 4;
            const int cc = n0 + wn + ni * 16 + col;
#pragma unroll
            for (int rr = 0; rr < 4; ++rr) {
                float v = acc[mi][ni][rr];
                size_t idx = (size_t)(rbase + rr) * N + cc;
                if (EPI == 0) ((u16*)Cp)[idx] = f2bf(v);
                else if (EPI == 1) { float t2 = fmaxf(v, 0.f); ((u16*)Cp)[idx] = f2bf(t2 * t2); }
                else ((float*)Cp)[idx] = v + Res[idx];
            }
        }
}

// ---------------- GEMM 256x256, 8 waves, 4-deep LDS ring, counted vmcnt ----------------
template<int EPI>
__global__ __launch_bounds__(512, 2)
void gemm_big(const u16* __restrict__ A, const u16* __restrict__ Bw,
              void* __restrict__ Cp, int M, int N, int K, int ldb) {
    __shared__ alignas(16) u16 As[4][256 * 32];
    __shared__ alignas(16) u16 Bs[4][256 * 32];
    const int tid = threadIdx.x;
    const int lane = tid & 63, w = tid >> 6;
    const int wr = w >> 2, wc = w & 3;              // 2M x 4N wave grid
    const int quad = lane >> 4, colL = lane & 15;

    const int nbx = N >> 8;
    const int nwg = gridDim.x;
    const int cpx = nwg >> 3;
    const int bid = blockIdx.x;
    const int swz = (bid & 7) * cpx + (bid >> 3);
    const int by = swz / nbx, bx = swz - by * nbx;
    const int m0 = by << 8, n0 = bx << 8;

    const int r0 = tid >> 2,       q0 = (tid & 3) ^ ((r0 >> 1) & 3);
    const int p1 = tid + 512;
    const int r1 = p1 >> 2,        q1 = (p1 & 3) ^ ((r1 >> 1) & 3);
    const u16* agp0 = A  + (size_t)(m0 + r0) * K   + q0 * 8;
    const u16* agp1 = A  + (size_t)(m0 + r1) * K   + q1 * 8;
    const u16* bgp0 = Bw + (size_t)(n0 + r0) * ldb + q0 * 8;
    const u16* bgp1 = Bw + (size_t)(n0 + r1) * ldb + q1 * 8;
    const int l0 = tid * 8, l1 = p1 * 8;

    int aoff[8], boff[4];
#pragma unroll
    for (int mi = 0; mi < 8; ++mi) {
        int r = wr * 128 + mi * 16 + colL;
        aoff[mi] = r * 32 + (quad ^ ((r >> 1) & 3)) * 8;
    }
#pragma unroll
    for (int ni = 0; ni < 4; ++ni) {
        int r = wc * 64 + ni * 16 + colL;
        boff[ni] = r * 32 + (quad ^ ((r >> 1) & 3)) * 8;
    }

    f32x4 acc[8][4];
#pragma unroll
    for (int i = 0; i < 8; ++i)
#pragma unroll
        for (int j = 0; j < 4; ++j) acc[i][j] = (f32x4){0.f, 0.f, 0.f, 0.f};

    const int KT = K >> 5;

#define GB_STAGE(s) { const int _b = (s) & 3; const size_t _ko = (size_t)(s) * 32; \
    gload_lds16(agp0 + _ko, &As[_b][l0]); \
    gload_lds16(agp1 + _ko, &As[_b][l1]); \
    gload_lds16(bgp0 + _ko, &Bs[_b][l0]); \
    gload_lds16(bgp1 + _ko, &Bs[_b][l1]); }

    GB_STAGE(0);
    GB_STAGE(1);
    GB_STAGE(2);

    for (int t = 0; t < KT; ++t) {
        const int rem = KT - 1 - t;
        if (rem >= 2)      asm volatile("s_waitcnt vmcnt(8)" ::: "memory");
        else if (rem == 1) asm volatile("s_waitcnt vmcnt(4)" ::: "memory");
        else               asm volatile("s_waitcnt vmcnt(0)" ::: "memory");
        __builtin_amdgcn_s_barrier();
        if (t + 3 < KT) GB_STAGE(t + 3);
        const u16* ab = As[t & 3];
        const u16* bb = Bs[t & 3];
        short8 af[8], bfr[4];
#pragma unroll
        for (int mi = 0; mi < 8; ++mi) af[mi] = *(const short8*)(ab + aoff[mi]);
#pragma unroll
        for (int ni = 0; ni < 4; ++ni) bfr[ni] = *(const short8*)(bb + boff[ni]);
        __builtin_amdgcn_s_setprio(1);
#pragma unroll
        for (int mi = 0; mi < 8; ++mi)
#pragma unroll
            for (int ni = 0; ni < 4; ++ni)
                acc[mi][ni] = __builtin_amdgcn_mfma_f32_16x16x32_bf16(af[mi], bfr[ni], acc[mi][ni], 0, 0, 0);
        __builtin_amdgcn_s_setprio(0);
        __builtin_amdgcn_sched_barrier(0);
    }
#undef GB_STAGE

#pragma unroll
    for (int mi = 0; mi < 8; ++mi)
#pragma unroll
        for (int ni = 0; ni < 4; ++ni) {
            const int rbase = m0 + wr * 128 + mi * 16 + quad * 4;
            const int cc = n0 + wc * 64 + ni * 16 + colL;
#pragma unroll
            for (int rr = 0; rr < 4; ++rr) {
                float v = acc[mi][ni][rr];
                size_t idx = (size_t)(rbase + rr) * N + cc;
                if (EPI == 0) ((u16*)Cp)[idx] = f2bf(v);
                else { float tq = fmaxf(v, 0.f); ((u16*)Cp)[idx] = f2bf(tq * tq); }
            }
        }
}

// ---------------- RoPE + per-head RMSNorm on q,k; split v ----------------
__global__ __launch_bounds__(256)
void rope_split_k(const u16* __restrict__ QKV, const float* __restrict__ RC,
                  const float* __restrict__ QW, const float* __restrict__ KW,
                  u16* __restrict__ Qo, u16* __restrict__ Ko, u16* __restrict__ Vo) {
    const int row = blockIdx.x;                 // b*T + t
    const int t = row & (TT - 1), b = row >> 11;
    const int tid = threadIdx.x, h = tid >> 4, j = tid & 15;
    const size_t qb = (size_t)row * (3 * DM) + h * HD + j * 8;
    float q[8], k[8], cs[8], sn[8];
    load8f(QKV + qb, q);
    load8f(QKV + qb + DM, k);
    uint4 vv = *(const uint4*)(QKV + qb + 2 * DM);
    load8f32(RC + (size_t)t * HD + j * 8, cs);
    load8f32(RC + (size_t)(TT + t) * HD + j * 8, sn);
    float qr[8], kr[8];
#pragma unroll
    for (int p = 0; p < 4; ++p) {
        float c = cs[2 * p], s = sn[2 * p];
        qr[2*p]   = q[2*p]   * c - q[2*p+1] * s;
        qr[2*p+1] = q[2*p+1] * c + q[2*p]   * s;
        kr[2*p]   = k[2*p]   * c - k[2*p+1] * s;
        kr[2*p+1] = k[2*p+1] * c + k[2*p]   * s;
    }
    float sq = 0.f, sk = 0.f;
#pragma unroll
    for (int i = 0; i < 8; ++i) { sq += qr[i] * qr[i]; sk += kr[i] * kr[i]; }
#pragma unroll
    for (int d = 1; d < 16; d <<= 1) { sq += __shfl_xor(sq, d); sk += __shfl_xor(sk, d); }
    const float iq = rsqrtf(sq * (1.f / HD) + EPSF);
    const float ik = rsqrtf(sk * (1.f / HD) + EPSF);
    float qw[8], kw[8], oq[8], ok[8];
    load8f32(QW + j * 8, qw); load8f32(KW + j * 8, kw);
#pragma unroll
    for (int i = 0; i < 8; ++i) { oq[i] = qr[i] * iq * qw[i]; ok[i] = kr[i] * ik * kw[i]; }
    const size_t ob = ((size_t)(b * NH + h) * TT + t) * HD + j * 8;
    store8bf(Qo + ob, oq);
    store8bf(Ko + ob, ok);
    *(uint4*)(Vo + ob) = vv;
}

// ---------------- V transpose: [bh][T][128] -> [bh][128][T] ----------------
__global__ __launch_bounds__(256)
void transpose_v(const u16* __restrict__ V, u16* __restrict__ Vt) {
    __shared__ alignas(16) u16 tile[64][72];
    const int bh = blockIdx.z;
    const int t0 = blockIdx.x * 64, d0 = blockIdx.y * 64;
    const int tid = threadIdx.x;
#pragma unroll
    for (int i = 0; i < 2; ++i) {
        int c = i * 256 + tid;
        int r = c >> 3, cc = (c & 7) * 8;
        *(uint4*)(&tile[r][cc]) = *(const uint4*)(V + ((size_t)bh * TT + t0 + r) * HD + d0 + cc);
    }
    __syncthreads();
#pragma unroll
    for (int i = 0; i < 2; ++i) {
        int c = i * 256 + tid;
        int dc = c >> 3, rr = (c & 7) * 8;
        u16 tmp[8];
#pragma unroll
        for (int kk = 0; kk < 8; ++kk) tmp[kk] = tile[rr + kk][dc];
        uint4 o;
        o.x = (u32)tmp[0] | ((u32)tmp[1] << 16);
        o.y = (u32)tmp[2] | ((u32)tmp[3] << 16);
        o.z = (u32)tmp[4] | ((u32)tmp[5] << 16);
        o.w = (u32)tmp[6] | ((u32)tmp[7] << 16);
        *(uint4*)(Vt + ((size_t)bh * HD + d0 + dc) * TT + t0 + rr) = o;
    }
}

// ---------------- Causal flash attention, 128-query tile, 4 waves x 32 q/wave ----------
// v4: each wave owns TWO 16-row q-subtiles -> every K/V LDS fragment read feeds 2 MFMAs
// (halves LDS-read + staging + barrier cost per query). PV runs in two 32-key half
// passes through a small wave-private p_lds so LDS stays at 75.8 KB (2 blocks/CU).
__global__ __launch_bounds__(256, 2)
void attn_k(const u16* __restrict__ Q, const u16* __restrict__ Kg,
            const u16* __restrict__ Vt, u16* __restrict__ O) {
    __shared__ alignas(16) u16 k_lds[2][64 * 128];
    __shared__ alignas(16) u16 v_lds[2][128 * 64];
    __shared__ alignas(16) u16 p_lds[128 * 40];
    const int qt = gridDim.x - 1 - blockIdx.x;   // long blocks first
    const int bh = blockIdx.y;
    const int tid = threadIdx.x, lane = tid & 63, w = tid >> 6;
    const int quad = lane >> 4, col = lane & 15;
    const int qbase = qt * 128;
    const int wq = qbase + w * 32;

    short8 qf[2][4];
#pragma unroll
    for (int sub = 0; sub < 2; ++sub) {
        const u16* qp = Q + ((size_t)bh * TT + wq + sub * 16 + col) * HD;
#pragma unroll
        for (int s = 0; s < 4; ++s) qf[sub][s] = *(const short8*)(qp + s * 32 + quad * 8);
    }

    // per-thread swizzled GLOBAL source addresses; LDS dest is linear (gload_lds req).
    const u16* kp[4]; const u16* vp[4];
#pragma unroll
    for (int i = 0; i < 4; ++i) {
        int lin = i * 256 + tid;
        int r = lin >> 4, sl = lin & 15;
        int gq = sl ^ (r & 15);
        kp[i] = Kg + ((size_t)bh * TT + r) * HD + gq * 8;
    }
#pragma unroll
    for (int i = 0; i < 4; ++i) {
        int lin = i * 256 + tid;
        int r = lin >> 3, sl = lin & 7;
        int gq = sl ^ (r & 7);
        vp[i] = Vt + ((size_t)bh * HD + r) * TT + gq * 8;
    }

    f32x4 oacc[2][8];
#pragma unroll
    for (int s = 0; s < 2; ++s)
#pragma unroll
        for (int i = 0; i < 8; ++i) oacc[s][i] = (f32x4){0.f, 0.f, 0.f, 0.f};
    float mrow[2][4], lrow[2][4];
#pragma unroll
    for (int s = 0; s < 2; ++s)
#pragma unroll
        for (int r = 0; r < 4; ++r) { mrow[s][r] = NEGBIG; lrow[s][r] = 0.f; }
    const float scale = 0.08838834764831845f;   // 1/sqrt(128)

    u16* kcur = k_lds[0]; u16* knxt = k_lds[1];
    u16* vcur = v_lds[0]; u16* vnxt = v_lds[1];
#pragma unroll
    for (int i = 0; i < 4; ++i) gload_lds16(kp[i], kcur + (i * 256 + tid) * 8);
#pragma unroll
    for (int i = 0; i < 4; ++i) gload_lds16(vp[i], vcur + (i * 256 + tid) * 8);

    const int ktmax = 2 * qt + 1;
    for (int kt = 0; kt <= ktmax; ++kt) {
        const int kb = kt * 64;
        __syncthreads();   // drains vmcnt(0): buf[cur] staged, buf[nxt] reads done

        if (kt < ktmax) {  // prefetch next K/V tile into the other buffer (async)
            const int kb2 = kb + 64;
#pragma unroll
            for (int i = 0; i < 4; ++i) gload_lds16(kp[i] + (size_t)kb2 * HD, knxt + (i * 256 + tid) * 8);
#pragma unroll
            for (int i = 0; i < 4; ++i) gload_lds16(vp[i] + kb2, vnxt + (i * 256 + tid) * 8);
        }

        f32x4 sfr[2][4];
#pragma unroll
        for (int s = 0; s < 2; ++s)
#pragma unroll
            for (int ni = 0; ni < 4; ++ni) sfr[s][ni] = (f32x4){0.f, 0.f, 0.f, 0.f};
        __builtin_amdgcn_s_setprio(1);
#pragma unroll
        for (int ni = 0; ni < 4; ++ni) {
            const int r = ni * 16 + col;
#pragma unroll
            for (int s = 0; s < 4; ++s) {
                int sl = (s * 4 + quad) ^ (r & 15);
                short8 kf = *(const short8*)(kcur + r * 128 + sl * 8);
                sfr[0][ni] = __builtin_amdgcn_mfma_f32_16x16x32_bf16(qf[0][s], kf, sfr[0][ni], 0, 0, 0);
                sfr[1][ni] = __builtin_amdgcn_mfma_f32_16x16x32_bf16(qf[1][s], kf, sfr[1][ni], 0, 0, 0);
            }
        }
        __builtin_amdgcn_s_setprio(0);
        // unconditional causal mask (cheap; all-false below the diagonal band)
#pragma unroll
        for (int sub = 0; sub < 2; ++sub)
#pragma unroll
            for (int ni = 0; ni < 4; ++ni) {
                const int key = kb + ni * 16 + col;
#pragma unroll
                for (int rr = 0; rr < 4; ++rr) {
                    float v = sfr[sub][ni][rr] * scale;
                    int qv = wq + sub * 16 + quad * 4 + rr;
                    if (key > qv) v = NEGBIG;
                    sfr[sub][ni][rr] = v;
                }
            }
        float mx[2][4];
#pragma unroll
        for (int sub = 0; sub < 2; ++sub)
#pragma unroll
            for (int rr = 0; rr < 4; ++rr)
                mx[sub][rr] = fmaxf(fmaxf(sfr[sub][0][rr], sfr[sub][1][rr]),
                                    fmaxf(sfr[sub][2][rr], sfr[sub][3][rr]));
#pragma unroll
        for (int d = 1; d < 16; d <<= 1)
#pragma unroll
            for (int sub = 0; sub < 2; ++sub)
#pragma unroll
                for (int rr = 0; rr < 4; ++rr) mx[sub][rr] = fmaxf(mx[sub][rr], __shfl_xor(mx[sub][rr], d));
        // strict defer-rescale: alpha==1 exactly when no row max grew -> skip.
        bool grew = false;
#pragma unroll
        for (int sub = 0; sub < 2; ++sub)
#pragma unroll
            for (int rr = 0; rr < 4; ++rr) grew = grew || (mx[sub][rr] > mrow[sub][rr]);
        if (__any(grew)) {
#pragma unroll
            for (int sub = 0; sub < 2; ++sub)
#pragma unroll
                for (int rr = 0; rr < 4; ++rr) {
                    float mn = fmaxf(mrow[sub][rr], mx[sub][rr]);
                    float a = __expf(mrow[sub][rr] - mn);
                    mrow[sub][rr] = mn;
                    lrow[sub][rr] *= a;
#pragma unroll
                    for (int i = 0; i < 8; ++i) oacc[sub][i][rr] *= a;
                }
        }
        float rs[2][4];
#pragma unroll
        for (int s = 0; s < 2; ++s)
#pragma unroll
            for (int r = 0; r < 4; ++r) rs[s][r] = 0.f;
#pragma unroll
        for (int sub = 0; sub < 2; ++sub)
#pragma unroll
            for (int ni = 0; ni < 4; ++ni)
#pragma unroll
                for (int rr = 0; rr < 4; ++rr) {
                    float p = __expf(sfr[sub][ni][rr] - mrow[sub][rr]);
                    sfr[sub][ni][rr] = p;
                    rs[sub][rr] += p;
                }
#pragma unroll
        for (int d = 1; d < 16; d <<= 1)
#pragma unroll
            for (int sub = 0; sub < 2; ++sub)
#pragma unroll
                for (int rr = 0; rr < 4; ++rr) rs[sub][rr] += __shfl_xor(rs[sub][rr], d);
#pragma unroll
        for (int sub = 0; sub < 2; ++sub)
#pragma unroll
            for (int rr = 0; rr < 4; ++rr) lrow[sub][rr] += rs[sub][rr];
        // PV in two 32-key halves through wave-private p_lds rows (no barrier needed)
#pragma unroll
        for (int ks = 0; ks < 2; ++ks) {
#pragma unroll
            for (int sub = 0; sub < 2; ++sub)
#pragma unroll
                for (int nio = 0; nio < 2; ++nio) {
                    const int ni = ks * 2 + nio;
#pragma unroll
                    for (int rr = 0; rr < 4; ++rr)
                        p_lds[(w * 32 + sub * 16 + quad * 4 + rr) * 40 + nio * 16 + col] = f2bf(sfr[sub][ni][rr]);
                }
            short8 pa0 = *(const short8*)(p_lds + (w * 32 + col) * 40 + quad * 8);
            short8 pa1 = *(const short8*)(p_lds + (w * 32 + 16 + col) * 40 + quad * 8);
            __builtin_amdgcn_s_setprio(1);
#pragma unroll
            for (int di = 0; di < 8; ++di) {
                int r = di * 16 + col;
                int sl = (ks * 4 + quad) ^ (r & 7);
                short8 vb = *(const short8*)(vcur + r * 64 + sl * 8);
                oacc[0][di] = __builtin_amdgcn_mfma_f32_16x16x32_bf16(pa0, vb, oacc[0][di], 0, 0, 0);
                oacc[1][di] = __builtin_amdgcn_mfma_f32_16x16x32_bf16(pa1, vb, oacc[1][di], 0, 0, 0);
            }
            __builtin_amdgcn_s_setprio(0);
        }
        { u16* t = kcur; kcur = knxt; knxt = t; }
        { u16* t = vcur; vcur = vnxt; vnxt = t; }
    }
    const int b = bh >> 4, hh = bh & 15;
#pragma unroll
    for (int sub = 0; sub < 2; ++sub)
#pragma unroll
        for (int di = 0; di < 8; ++di)
#pragma unroll
            for (int rr = 0; rr < 4; ++rr) {
                int trow = wq + sub * 16 + quad * 4 + rr;
                float ov = oacc[sub][di][rr] / lrow[sub][rr];
                O[((size_t)(b * TT + trow)) * DM + hh * HD + di * 16 + col] = f2bf(ov);
            }
}

extern "C" void kernel_launch(void* const* d_in, const int* in_sizes, int n_in,
                              void* d_out, int out_size, void* d_ws, size_t ws_size,
                              hipStream_t stream) {
    const float* x    = (const float*)d_in[0];
    const float* rc   = (const float*)d_in[1];
    const float* anw  = (const float*)d_in[2];
    const float* qkvw = (const float*)d_in[3];
    const float* qnw  = (const float*)d_in[4];
    const float* knw  = (const float*)d_in[5];
    const float* opw  = (const float*)d_in[6];
    const float* mnw  = (const float*)d_in[7];
    const float* miw  = (const float*)d_in[8];
    const float* mow  = (const float*)d_in[9];

    char* ws = (char*)d_ws;
    // Workspace plan, 120 MiB peak (MiB offsets). Late-phase owners:
    //   hbuf[0,16) Wmi[16,48) Wmo[48,80) mbuf[80,112) Wo[112,120)
    // Early/mid aliases (dead before late owner is written):
    //   Wq[16,40)  qkv[48,96)  qh[96,112)  kh[112,128)  vh[0,16)  vt[16,32)  aout[32,48)
    // Residual x2 lives in d_out (f32), accumulated by the mlp_out halves.
    u16* hbuf = (u16*)(ws);
    u16* Wq   = (u16*)(ws + (16ll  << 20));
    u16* Wmi  = (u16*)(ws + (16ll  << 20));
    u16* vt   = (u16*)(ws + (16ll  << 20));
    u16* aout = (u16*)(ws + (32ll  << 20));
    u16* Wmo  = (u16*)(ws + (48ll  << 20));
    u16* qkv  = (u16*)(ws + (48ll  << 20));
    u16* mbuf = (u16*)(ws + (80ll  << 20));
    u16* qh   = (u16*)(ws + (96ll  << 20));
    u16* Wo   = (u16*)(ws + (112ll << 20));
    u16* kh   = (u16*)(ws + (112ll << 20));
    u16* vh   = (u16*)(ws);
    float* xo = (float*)d_out;

    rmsnorm_k<<<MR, 256, 0, stream>>>(x, anw, hbuf);
    cvt_w<<<6144, 256, 0, stream>>>(qkvw, Wq);                     // 3DM*DM
    gemm_big<0><<<384, 512, 0, stream>>>(hbuf, Wq, qkv, MR, 3 * DM, DM, DM);
    rope_split_k<<<MR, 256, 0, stream>>>(qkv, rc, qnw, knw, qh, kh, vh);
    transpose_v<<<dim3(32, 2, 32), 256, 0, stream>>>(vh, vt);
    attn_k<<<dim3(16, 32), 256, 0, stream>>>(qh, kh, vt, aout);
    cvt_w<<<2048, 256, 0, stream>>>(opw, Wo);                      // DM*DM (kh dead)
    cvt_w<<<8192, 256, 0, stream>>>(mow, Wmo);                     // DM*FFN (qkv dead)
    gemm_ring<2><<<dim3(16, 32), 256, 0, stream>>>(aout, Wo, x, xo, MR, DM, DM, DM);
    rmsnorm_k<<<MR, 256, 0, stream>>>(xo, mnw, hbuf);
    cvt_w<<<8192, 256, 0, stream>>>(miw, Wmi);                     // FFN*DM (vt/aout dead)
    // MLP in two FFN halves; mbuf is 4096x4096 bf16, d_out accumulates in f32.
    gemm_big<1><<<256, 512, 0, stream>>>(hbuf, Wmi, mbuf, MR, FFN / 2, DM, DM);
    gemm_ring<2><<<dim3(16, 32), 256, 0, stream>>>(mbuf, Wmo, xo, xo, MR, DM, FFN / 2, FFN);
    gemm_big<1><<<256, 512, 0, stream>>>(hbuf, Wmi + (size_t)(FFN / 2) * DM, mbuf, MR, FFN / 2, DM, DM);
    gemm_ring<2><<<dim3(16, 32), 256, 0, stream>>>(mbuf, Wmo + FFN / 2, xo, xo, MR, DM, FFN / 2, FFN);
}

// Round 5
// 928.715 us; speedup vs baseline: 1.5574x; 1.0721x over previous
//
#include <hip/hip_runtime.h>
#include <stdint.h>

#define TT 2048
#define DM 2048
#define NH 16
#define HD 128
#define FFN 8192
#define MR 4096   // B*T
#define EPSF 1.1920928955078125e-07f
#define NEGBIG (-1.0e30f)

typedef __attribute__((ext_vector_type(8))) short short8;
typedef __attribute__((ext_vector_type(4))) float f32x4;
typedef unsigned short u16;
typedef unsigned int u32;

__device__ __forceinline__ float bf2f(u32 u) {
    return __uint_as_float((u & 0xffffu) << 16);
}
__device__ __forceinline__ u16 f2bf(float f) {
    u32 x = __float_as_uint(f);
    return (u16)((x + 0x7fffu + ((x >> 16) & 1u)) >> 16);
}
__device__ __forceinline__ void load8f(const u16* p, float* v) {
    uint4 d = *(const uint4*)p;
    v[0] = bf2f(d.x); v[1] = bf2f(d.x >> 16);
    v[2] = bf2f(d.y); v[3] = bf2f(d.y >> 16);
    v[4] = bf2f(d.z); v[5] = bf2f(d.z >> 16);
    v[6] = bf2f(d.w); v[7] = bf2f(d.w >> 16);
}
__device__ __forceinline__ void load8f32(const float* p, float* v) {
    float4 a = *(const float4*)p, b = *(const float4*)(p + 4);
    v[0]=a.x; v[1]=a.y; v[2]=a.z; v[3]=a.w; v[4]=b.x; v[5]=b.y; v[6]=b.z; v[7]=b.w;
}
__device__ __forceinline__ void store8bf(u16* p, const float* v) {
    uint4 o;
    o.x = (u32)f2bf(v[0]) | ((u32)f2bf(v[1]) << 16);
    o.y = (u32)f2bf(v[2]) | ((u32)f2bf(v[3]) << 16);
    o.z = (u32)f2bf(v[4]) | ((u32)f2bf(v[5]) << 16);
    o.w = (u32)f2bf(v[6]) | ((u32)f2bf(v[7]) << 16);
    *(uint4*)p = o;
}
__device__ __forceinline__ uint4 cvt8_f32_bf16(const float* p) {
    float4 a = *(const float4*)p, b = *(const float4*)(p + 4);
    uint4 o;
    o.x = (u32)f2bf(a.x) | ((u32)f2bf(a.y) << 16);
    o.y = (u32)f2bf(a.z) | ((u32)f2bf(a.w) << 16);
    o.z = (u32)f2bf(b.x) | ((u32)f2bf(b.y) << 16);
    o.w = (u32)f2bf(b.z) | ((u32)f2bf(b.w) << 16);
    return o;
}
__device__ __forceinline__ void gload_lds16(const void* g, void* l) {
    __builtin_amdgcn_global_load_lds((const __attribute__((address_space(1))) u32*)g,
                                     (__attribute__((address_space(3))) u32*)l, 16, 0, 0);
}

// ---------------- weight f32 -> bf16 (8 elems/thread) ----------------
__global__ __launch_bounds__(256)
void cvt_w(const float* __restrict__ S, u16* __restrict__ D) {
    size_t i = ((size_t)blockIdx.x * 256 + threadIdx.x) * 8;
    *(uint4*)(D + i) = cvt8_f32_bf16(S + i);
}

// ---------------- RMSNorm (f32 in, bf16 out): one block per row of 2048 ----------------
__global__ __launch_bounds__(256)
void rmsnorm_k(const float* __restrict__ X, const float* __restrict__ W, u16* __restrict__ O) {
    const int row = blockIdx.x, tid = threadIdx.x;
    float v[8];
    load8f32(X + (size_t)row * DM + tid * 8, v);
    float ssq = 0.f;
#pragma unroll
    for (int i = 0; i < 8; ++i) ssq += v[i] * v[i];
#pragma unroll
    for (int d = 1; d < 64; d <<= 1) ssq += __shfl_xor(ssq, d);
    __shared__ float red[4];
    if ((tid & 63) == 0) red[tid >> 6] = ssq;
    __syncthreads();
    ssq = red[0] + red[1] + red[2] + red[3];
    const float inv = rsqrtf(ssq * (1.f / DM) + EPSF);
    float wv[8], o[8];
    load8f32(W + tid * 8, wv);
#pragma unroll
    for (int i = 0; i < 8; ++i) o[i] = v[i] * inv * wv[i];
    store8bf(O + (size_t)row * DM + tid * 8, o);
}

// ---------------- GEMM 128x128, 4-deep LDS ring, counted vmcnt, 2 blocks/CU ----------
// v5: fragment reads for step t+1 issued inside step t's MFMA cluster (in-place
// overwrite after last use) -> LDS pipe overlaps matrix pipe. vmcnt(4) publishes
// stages t AND t+1 at the barrier so the pre-read is race-free.
// EPI: 0 = bf16 out, 1 = relu^2 bf16 out, 2 = + f32 Res -> f32 out
template<int EPI>
__global__ __launch_bounds__(256, 2)
void gemm_ring(const u16* __restrict__ A, const u16* __restrict__ Bw,
               const float* __restrict__ Res, void* __restrict__ Cp,
               int M, int N, int K, int ldb) {
    __shared__ alignas(16) u16 As[4][128 * 32];
    __shared__ alignas(16) u16 Bs[4][128 * 32];
    const int tid = threadIdx.x;
    const int lane = tid & 63, w = tid >> 6;
    const int quad = lane >> 4, col = lane & 15;
    const int n0 = blockIdx.x * 128, m0 = blockIdx.y * 128;
    const int wm = (w >> 1) * 64, wn = (w & 1) * 64;

    const int c0 = tid, c1 = tid + 256;
    const int ar0 = c0 >> 2, aq0 = (c0 & 3) ^ ((ar0 >> 1) & 3);
    const int ar1 = c1 >> 2, aq1 = (c1 & 3) ^ ((ar1 >> 1) & 3);
    const u16* agp0 = A  + (size_t)(m0 + ar0) * K + aq0 * 8;
    const u16* agp1 = A  + (size_t)(m0 + ar1) * K + aq1 * 8;
    const u16* bgp0 = Bw + (size_t)(n0 + ar0) * ldb + aq0 * 8;
    const u16* bgp1 = Bw + (size_t)(n0 + ar1) * ldb + aq1 * 8;
    const int l0 = c0 * 8, l1 = c1 * 8;

    int aoff[4], boff[4];
#pragma unroll
    for (int i = 0; i < 4; ++i) {
        int r = wm + i * 16 + col;
        aoff[i] = r * 32 + (quad ^ ((r >> 1) & 3)) * 8;
        r = wn + i * 16 + col;
        boff[i] = r * 32 + (quad ^ ((r >> 1) & 3)) * 8;
    }

    f32x4 acc[4][4];
#pragma unroll
    for (int i = 0; i < 4; ++i)
#pragma unroll
        for (int j = 0; j < 4; ++j) acc[i][j] = (f32x4){0.f, 0.f, 0.f, 0.f};

    const int KT = K >> 5;

#define GR_STAGE(s) { const int _b = (s) & 3; const size_t _ko = (size_t)(s) * 32; \
    gload_lds16(agp0 + _ko, &As[_b][l0]); \
    gload_lds16(agp1 + _ko, &As[_b][l1]); \
    gload_lds16(bgp0 + _ko, &Bs[_b][l0]); \
    gload_lds16(bgp1 + _ko, &Bs[_b][l1]); }

    GR_STAGE(0);
    GR_STAGE(1);
    GR_STAGE(2);

    // prologue: publish stage 0, read its fragments
    asm volatile("s_waitcnt vmcnt(8)" ::: "memory");
    __builtin_amdgcn_s_barrier();
    short8 af[4], bfr[4];
#pragma unroll
    for (int i = 0; i < 4; ++i) af[i]  = *(const short8*)(As[0] + aoff[i]);
#pragma unroll
    for (int i = 0; i < 4; ++i) bfr[i] = *(const short8*)(Bs[0] + boff[i]);

    for (int t = 0; t < KT; ++t) {
        // publish stages t and t+1 (pre-read of t+1 is then race-free)
        if (t <= KT - 3) asm volatile("s_waitcnt vmcnt(4)" ::: "memory");
        else             asm volatile("s_waitcnt vmcnt(0)" ::: "memory");
        __builtin_amdgcn_s_barrier();
        if (t + 3 < KT) GR_STAGE(t + 3);
        const u16* abn = As[(t + 1) & 3];
        const u16* bbn = Bs[(t + 1) & 3];
        __builtin_amdgcn_s_setprio(1);
#pragma unroll
        for (int mi = 0; mi < 4; ++mi) {
#pragma unroll
            for (int ni = 0; ni < 4; ++ni)
                acc[mi][ni] = __builtin_amdgcn_mfma_f32_16x16x32_bf16(af[mi], bfr[ni], acc[mi][ni], 0, 0, 0);
            af[mi] = *(const short8*)(abn + aoff[mi]);   // frag(t+1), in MFMA shadow
        }
        __builtin_amdgcn_s_setprio(0);
#pragma unroll
        for (int ni = 0; ni < 4; ++ni) bfr[ni] = *(const short8*)(bbn + boff[ni]);
        __builtin_amdgcn_sched_barrier(0);
    }
#undef GR_STAGE

#pragma unroll
    for (int mi = 0; mi < 4; ++mi)
#pragma unroll
        for (int ni = 0; ni < 4; ++ni) {
            const int rbase = m0 + wm + mi * 16 + quad * 4;
            const int cc = n0 + wn + ni * 16 + col;
#pragma unroll
            for (int rr = 0; rr < 4; ++rr) {
                float v = acc[mi][ni][rr];
                size_t idx = (size_t)(rbase + rr) * N + cc;
                if (EPI == 0) ((u16*)Cp)[idx] = f2bf(v);
                else if (EPI == 1) { float t2 = fmaxf(v, 0.f); ((u16*)Cp)[idx] = f2bf(t2 * t2); }
                else ((float*)Cp)[idx] = v + Res[idx];
            }
        }
}

// ---------------- GEMM 256x256, 8 waves, 4-deep LDS ring, counted vmcnt ----------------
// v5: same in-cluster fragment pre-read pipelining as gemm_ring.
template<int EPI>
__global__ __launch_bounds__(512, 2)
void gemm_big(const u16* __restrict__ A, const u16* __restrict__ Bw,
              void* __restrict__ Cp, int M, int N, int K, int ldb) {
    __shared__ alignas(16) u16 As[4][256 * 32];
    __shared__ alignas(16) u16 Bs[4][256 * 32];
    const int tid = threadIdx.x;
    const int lane = tid & 63, w = tid >> 6;
    const int wr = w >> 2, wc = w & 3;              // 2M x 4N wave grid
    const int quad = lane >> 4, colL = lane & 15;

    const int nbx = N >> 8;
    const int nwg = gridDim.x;
    const int cpx = nwg >> 3;
    const int bid = blockIdx.x;
    const int swz = (bid & 7) * cpx + (bid >> 3);
    const int by = swz / nbx, bx = swz - by * nbx;
    const int m0 = by << 8, n0 = bx << 8;

    const int r0 = tid >> 2,       q0 = (tid & 3) ^ ((r0 >> 1) & 3);
    const int p1 = tid + 512;
    const int r1 = p1 >> 2,        q1 = (p1 & 3) ^ ((r1 >> 1) & 3);
    const u16* agp0 = A  + (size_t)(m0 + r0) * K   + q0 * 8;
    const u16* agp1 = A  + (size_t)(m0 + r1) * K   + q1 * 8;
    const u16* bgp0 = Bw + (size_t)(n0 + r0) * ldb + q0 * 8;
    const u16* bgp1 = Bw + (size_t)(n0 + r1) * ldb + q1 * 8;
    const int l0 = tid * 8, l1 = p1 * 8;

    int aoff[8], boff[4];
#pragma unroll
    for (int mi = 0; mi < 8; ++mi) {
        int r = wr * 128 + mi * 16 + colL;
        aoff[mi] = r * 32 + (quad ^ ((r >> 1) & 3)) * 8;
    }
#pragma unroll
    for (int ni = 0; ni < 4; ++ni) {
        int r = wc * 64 + ni * 16 + colL;
        boff[ni] = r * 32 + (quad ^ ((r >> 1) & 3)) * 8;
    }

    f32x4 acc[8][4];
#pragma unroll
    for (int i = 0; i < 8; ++i)
#pragma unroll
        for (int j = 0; j < 4; ++j) acc[i][j] = (f32x4){0.f, 0.f, 0.f, 0.f};

    const int KT = K >> 5;

#define GB_STAGE(s) { const int _b = (s) & 3; const size_t _ko = (size_t)(s) * 32; \
    gload_lds16(agp0 + _ko, &As[_b][l0]); \
    gload_lds16(agp1 + _ko, &As[_b][l1]); \
    gload_lds16(bgp0 + _ko, &Bs[_b][l0]); \
    gload_lds16(bgp1 + _ko, &Bs[_b][l1]); }

    GB_STAGE(0);
    GB_STAGE(1);
    GB_STAGE(2);

    asm volatile("s_waitcnt vmcnt(8)" ::: "memory");
    __builtin_amdgcn_s_barrier();
    short8 af[8], bfr[4];
#pragma unroll
    for (int i = 0; i < 8; ++i) af[i]  = *(const short8*)(As[0] + aoff[i]);
#pragma unroll
    for (int i = 0; i < 4; ++i) bfr[i] = *(const short8*)(Bs[0] + boff[i]);

    for (int t = 0; t < KT; ++t) {
        if (t <= KT - 3) asm volatile("s_waitcnt vmcnt(4)" ::: "memory");
        else             asm volatile("s_waitcnt vmcnt(0)" ::: "memory");
        __builtin_amdgcn_s_barrier();
        if (t + 3 < KT) GB_STAGE(t + 3);
        const u16* abn = As[(t + 1) & 3];
        const u16* bbn = Bs[(t + 1) & 3];
        __builtin_amdgcn_s_setprio(1);
#pragma unroll
        for (int mi = 0; mi < 8; ++mi) {
#pragma unroll
            for (int ni = 0; ni < 4; ++ni)
                acc[mi][ni] = __builtin_amdgcn_mfma_f32_16x16x32_bf16(af[mi], bfr[ni], acc[mi][ni], 0, 0, 0);
            af[mi] = *(const short8*)(abn + aoff[mi]);   // frag(t+1), in MFMA shadow
        }
        __builtin_amdgcn_s_setprio(0);
#pragma unroll
        for (int ni = 0; ni < 4; ++ni) bfr[ni] = *(const short8*)(bbn + boff[ni]);
        __builtin_amdgcn_sched_barrier(0);
    }
#undef GB_STAGE

#pragma unroll
    for (int mi = 0; mi < 8; ++mi)
#pragma unroll
        for (int ni = 0; ni < 4; ++ni) {
            const int rbase = m0 + wr * 128 + mi * 16 + quad * 4;
            const int cc = n0 + wc * 64 + ni * 16 + colL;
#pragma unroll
            for (int rr = 0; rr < 4; ++rr) {
                float v = acc[mi][ni][rr];
                size_t idx = (size_t)(rbase + rr) * N + cc;
                if (EPI == 0) ((u16*)Cp)[idx] = f2bf(v);
                else { float tq = fmaxf(v, 0.f); ((u16*)Cp)[idx] = f2bf(tq * tq); }
            }
        }
}

// ---------------- RoPE + per-head RMSNorm on q,k; split v ----------------
__global__ __launch_bounds__(256)
void rope_split_k(const u16* __restrict__ QKV, const float* __restrict__ RC,
                  const float* __restrict__ QW, const float* __restrict__ KW,
                  u16* __restrict__ Qo, u16* __restrict__ Ko, u16* __restrict__ Vo) {
    const int row = blockIdx.x;                 // b*T + t
    const int t = row & (TT - 1), b = row >> 11;
    const int tid = threadIdx.x, h = tid >> 4, j = tid & 15;
    const size_t qb = (size_t)row * (3 * DM) + h * HD + j * 8;
    float q[8], k[8], cs[8], sn[8];
    load8f(QKV + qb, q);
    load8f(QKV + qb + DM, k);
    uint4 vv = *(const uint4*)(QKV + qb + 2 * DM);
    load8f32(RC + (size_t)t * HD + j * 8, cs);
    load8f32(RC + (size_t)(TT + t) * HD + j * 8, sn);
    float qr[8], kr[8];
#pragma unroll
    for (int p = 0; p < 4; ++p) {
        float c = cs[2 * p], s = sn[2 * p];
        qr[2*p]   = q[2*p]   * c - q[2*p+1] * s;
        qr[2*p+1] = q[2*p+1] * c + q[2*p]   * s;
        kr[2*p]   = k[2*p]   * c - k[2*p+1] * s;
        kr[2*p+1] = k[2*p+1] * c + k[2*p]   * s;
    }
    float sq = 0.f, sk = 0.f;
#pragma unroll
    for (int i = 0; i < 8; ++i) { sq += qr[i] * qr[i]; sk += kr[i] * kr[i]; }
#pragma unroll
    for (int d = 1; d < 16; d <<= 1) { sq += __shfl_xor(sq, d); sk += __shfl_xor(sk, d); }
    const float iq = rsqrtf(sq * (1.f / HD) + EPSF);
    const float ik = rsqrtf(sk * (1.f / HD) + EPSF);
    float qw[8], kw[8], oq[8], ok[8];
    load8f32(QW + j * 8, qw); load8f32(KW + j * 8, kw);
#pragma unroll
    for (int i = 0; i < 8; ++i) { oq[i] = qr[i] * iq * qw[i]; ok[i] = kr[i] * ik * kw[i]; }
    const size_t ob = ((size_t)(b * NH + h) * TT + t) * HD + j * 8;
    store8bf(Qo + ob, oq);
    store8bf(Ko + ob, ok);
    *(uint4*)(Vo + ob) = vv;
}

// ---------------- V transpose: [bh][T][128] -> [bh][128][T] ----------------
__global__ __launch_bounds__(256)
void transpose_v(const u16* __restrict__ V, u16* __restrict__ Vt) {
    __shared__ alignas(16) u16 tile[64][72];
    const int bh = blockIdx.z;
    const int t0 = blockIdx.x * 64, d0 = blockIdx.y * 64;
    const int tid = threadIdx.x;
#pragma unroll
    for (int i = 0; i < 2; ++i) {
        int c = i * 256 + tid;
        int r = c >> 3, cc = (c & 7) * 8;
        *(uint4*)(&tile[r][cc]) = *(const uint4*)(V + ((size_t)bh * TT + t0 + r) * HD + d0 + cc);
    }
    __syncthreads();
#pragma unroll
    for (int i = 0; i < 2; ++i) {
        int c = i * 256 + tid;
        int dc = c >> 3, rr = (c & 7) * 8;
        u16 tmp[8];
#pragma unroll
        for (int kk = 0; kk < 8; ++kk) tmp[kk] = tile[rr + kk][dc];
        uint4 o;
        o.x = (u32)tmp[0] | ((u32)tmp[1] << 16);
        o.y = (u32)tmp[2] | ((u32)tmp[3] << 16);
        o.z = (u32)tmp[4] | ((u32)tmp[5] << 16);
        o.w = (u32)tmp[6] | ((u32)tmp[7] << 16);
        *(uint4*)(Vt + ((size_t)bh * HD + d0 + dc) * TT + t0 + rr) = o;
    }
}

// ---------------- Causal flash attention, 128-query tile, 4 waves x 32 q/wave ----------
__global__ __launch_bounds__(256, 2)
void attn_k(const u16* __restrict__ Q, const u16* __restrict__ Kg,
            const u16* __restrict__ Vt, u16* __restrict__ O) {
    __shared__ alignas(16) u16 k_lds[2][64 * 128];
    __shared__ alignas(16) u16 v_lds[2][128 * 64];
    __shared__ alignas(16) u16 p_lds[128 * 40];
    const int qt = gridDim.x - 1 - blockIdx.x;   // long blocks first
    const int bh = blockIdx.y;
    const int tid = threadIdx.x, lane = tid & 63, w = tid >> 6;
    const int quad = lane >> 4, col = lane & 15;
    const int qbase = qt * 128;
    const int wq = qbase + w * 32;

    short8 qf[2][4];
#pragma unroll
    for (int sub = 0; sub < 2; ++sub) {
        const u16* qp = Q + ((size_t)bh * TT + wq + sub * 16 + col) * HD;
#pragma unroll
        for (int s = 0; s < 4; ++s) qf[sub][s] = *(const short8*)(qp + s * 32 + quad * 8);
    }

    const u16* kp[4]; const u16* vp[4];
#pragma unroll
    for (int i = 0; i < 4; ++i) {
        int lin = i * 256 + tid;
        int r = lin >> 4, sl = lin & 15;
        int gq = sl ^ (r & 15);
        kp[i] = Kg + ((size_t)bh * TT + r) * HD + gq * 8;
    }
#pragma unroll
    for (int i = 0; i < 4; ++i) {
        int lin = i * 256 + tid;
        int r = lin >> 3, sl = lin & 7;
        int gq = sl ^ (r & 7);
        vp[i] = Vt + ((size_t)bh * HD + r) * TT + gq * 8;
    }

    f32x4 oacc[2][8];
#pragma unroll
    for (int s = 0; s < 2; ++s)
#pragma unroll
        for (int i = 0; i < 8; ++i) oacc[s][i] = (f32x4){0.f, 0.f, 0.f, 0.f};
    float mrow[2][4], lrow[2][4];
#pragma unroll
    for (int s = 0; s < 2; ++s)
#pragma unroll
        for (int r = 0; r < 4; ++r) { mrow[s][r] = NEGBIG; lrow[s][r] = 0.f; }
    const float scale = 0.08838834764831845f;   // 1/sqrt(128)

    u16* kcur = k_lds[0]; u16* knxt = k_lds[1];
    u16* vcur = v_lds[0]; u16* vnxt = v_lds[1];
#pragma unroll
    for (int i = 0; i < 4; ++i) gload_lds16(kp[i], kcur + (i * 256 + tid) * 8);
#pragma unroll
    for (int i = 0; i < 4; ++i) gload_lds16(vp[i], vcur + (i * 256 + tid) * 8);

    const int ktmax = 2 * qt + 1;
    for (int kt = 0; kt <= ktmax; ++kt) {
        const int kb = kt * 64;
        __syncthreads();   // drains vmcnt(0): buf[cur] staged, buf[nxt] reads done

        if (kt < ktmax) {  // prefetch next K/V tile into the other buffer (async)
            const int kb2 = kb + 64;
#pragma unroll
            for (int i = 0; i < 4; ++i) gload_lds16(kp[i] + (size_t)kb2 * HD, knxt + (i * 256 + tid) * 8);
#pragma unroll
            for (int i = 0; i < 4; ++i) gload_lds16(vp[i] + kb2, vnxt + (i * 256 + tid) * 8);
        }

        f32x4 sfr[2][4];
#pragma unroll
        for (int s = 0; s < 2; ++s)
#pragma unroll
            for (int ni = 0; ni < 4; ++ni) sfr[s][ni] = (f32x4){0.f, 0.f, 0.f, 0.f};
        __builtin_amdgcn_s_setprio(1);
#pragma unroll
        for (int ni = 0; ni < 4; ++ni) {
            const int r = ni * 16 + col;
#pragma unroll
            for (int s = 0; s < 4; ++s) {
                int sl = (s * 4 + quad) ^ (r & 15);
                short8 kf = *(const short8*)(kcur + r * 128 + sl * 8);
                sfr[0][ni] = __builtin_amdgcn_mfma_f32_16x16x32_bf16(qf[0][s], kf, sfr[0][ni], 0, 0, 0);
                sfr[1][ni] = __builtin_amdgcn_mfma_f32_16x16x32_bf16(qf[1][s], kf, sfr[1][ni], 0, 0, 0);
            }
        }
        __builtin_amdgcn_s_setprio(0);
#pragma unroll
        for (int sub = 0; sub < 2; ++sub)
#pragma unroll
            for (int ni = 0; ni < 4; ++ni) {
                const int key = kb + ni * 16 + col;
#pragma unroll
                for (int rr = 0; rr < 4; ++rr) {
                    float v = sfr[sub][ni][rr] * scale;
                    int qv = wq + sub * 16 + quad * 4 + rr;
                    if (key > qv) v = NEGBIG;
                    sfr[sub][ni][rr] = v;
                }
            }
        float mx[2][4];
#pragma unroll
        for (int sub = 0; sub < 2; ++sub)
#pragma unroll
            for (int rr = 0; rr < 4; ++rr)
                mx[sub][rr] = fmaxf(fmaxf(sfr[sub][0][rr], sfr[sub][1][rr]),
                                    fmaxf(sfr[sub][2][rr], sfr[sub][3][rr]));
#pragma unroll
        for (int d = 1; d < 16; d <<= 1)
#pragma unroll
            for (int sub = 0; sub < 2; ++sub)
#pragma unroll
                for (int rr = 0; rr < 4; ++rr) mx[sub][rr] = fmaxf(mx[sub][rr], __shfl_xor(mx[sub][rr], d));
        bool grew = false;
#pragma unroll
        for (int sub = 0; sub < 2; ++sub)
#pragma unroll
            for (int rr = 0; rr < 4; ++rr) grew = grew || (mx[sub][rr] > mrow[sub][rr]);
        if (__any(grew)) {
#pragma unroll
            for (int sub = 0; sub < 2; ++sub)
#pragma unroll
                for (int rr = 0; rr < 4; ++rr) {
                    float mn = fmaxf(mrow[sub][rr], mx[sub][rr]);
                    float a = __expf(mrow[sub][rr] - mn);
                    mrow[sub][rr] = mn;
                    lrow[sub][rr] *= a;
#pragma unroll
                    for (int i = 0; i < 8; ++i) oacc[sub][i][rr] *= a;
                }
        }
        float rs[2][4];
#pragma unroll
        for (int s = 0; s < 2; ++s)
#pragma unroll
            for (int r = 0; r < 4; ++r) rs[s][r] = 0.f;
#pragma unroll
        for (int sub = 0; sub < 2; ++sub)
#pragma unroll
            for (int ni = 0; ni < 4; ++ni)
#pragma unroll
                for (int rr = 0; rr < 4; ++rr) {
                    float p = __expf(sfr[sub][ni][rr] - mrow[sub][rr]);
                    sfr[sub][ni][rr] = p;
                    rs[sub][rr] += p;
                }
#pragma unroll
        for (int d = 1; d < 16; d <<= 1)
#pragma unroll
            for (int sub = 0; sub < 2; ++sub)
#pragma unroll
                for (int rr = 0; rr < 4; ++rr) rs[sub][rr] += __shfl_xor(rs[sub][rr], d);
#pragma unroll
        for (int sub = 0; sub < 2; ++sub)
#pragma unroll
            for (int rr = 0; rr < 4; ++rr) lrow[sub][rr] += rs[sub][rr];
#pragma unroll
        for (int ks = 0; ks < 2; ++ks) {
#pragma unroll
            for (int sub = 0; sub < 2; ++sub)
#pragma unroll
                for (int nio = 0; nio < 2; ++nio) {
                    const int ni = ks * 2 + nio;
#pragma unroll
                    for (int rr = 0; rr < 4; ++rr)
                        p_lds[(w * 32 + sub * 16 + quad * 4 + rr) * 40 + nio * 16 + col] = f2bf(sfr[sub][ni][rr]);
                }
            short8 pa0 = *(const short8*)(p_lds + (w * 32 + col) * 40 + quad * 8);
            short8 pa1 = *(const short8*)(p_lds + (w * 32 + 16 + col) * 40 + quad * 8);
            __builtin_amdgcn_s_setprio(1);
#pragma unroll
            for (int di = 0; di < 8; ++di) {
                int r = di * 16 + col;
                int sl = (ks * 4 + quad) ^ (r & 7);
                short8 vb = *(const short8*)(vcur + r * 64 + sl * 8);
                oacc[0][di] = __builtin_amdgcn_mfma_f32_16x16x32_bf16(pa0, vb, oacc[0][di], 0, 0, 0);
                oacc[1][di] = __builtin_amdgcn_mfma_f32_16x16x32_bf16(pa1, vb, oacc[1][di], 0, 0, 0);
            }
            __builtin_amdgcn_s_setprio(0);
        }
        { u16* t = kcur; kcur = knxt; knxt = t; }
        { u16* t = vcur; vcur = vnxt; vnxt = t; }
    }
    const int b = bh >> 4, hh = bh & 15;
#pragma unroll
    for (int sub = 0; sub < 2; ++sub)
#pragma unroll
        for (int di = 0; di < 8; ++di)
#pragma unroll
            for (int rr = 0; rr < 4; ++rr) {
                int trow = wq + sub * 16 + quad * 4 + rr;
                float ov = oacc[sub][di][rr] / lrow[sub][rr];
                O[((size_t)(b * TT + trow)) * DM + hh * HD + di * 16 + col] = f2bf(ov);
            }
}

extern "C" void kernel_launch(void* const* d_in, const int* in_sizes, int n_in,
                              void* d_out, int out_size, void* d_ws, size_t ws_size,
                              hipStream_t stream) {
    const float* x    = (const float*)d_in[0];
    const float* rc   = (const float*)d_in[1];
    const float* anw  = (const float*)d_in[2];
    const float* qkvw = (const float*)d_in[3];
    const float* qnw  = (const float*)d_in[4];
    const float* knw  = (const float*)d_in[5];
    const float* opw  = (const float*)d_in[6];
    const float* mnw  = (const float*)d_in[7];
    const float* miw  = (const float*)d_in[8];
    const float* mow  = (const float*)d_in[9];

    char* ws = (char*)d_ws;
    // Workspace plan, 120 MiB peak (MiB offsets). Late-phase owners:
    //   hbuf[0,16) Wmi[16,48) Wmo[48,80) mbuf[80,112) Wo[112,120)
    // Early/mid aliases (dead before late owner is written):
    //   Wq[16,40)  qkv[48,96)  qh[96,112)  kh[112,128)  vh[0,16)  vt[16,32)  aout[32,48)
    // Residual x2 lives in d_out (f32), accumulated by the mlp_out halves.
    u16* hbuf = (u16*)(ws);
    u16* Wq   = (u16*)(ws + (16ll  << 20));
    u16* Wmi  = (u16*)(ws + (16ll  << 20));
    u16* vt   = (u16*)(ws + (16ll  << 20));
    u16* aout = (u16*)(ws + (32ll  << 20));
    u16* Wmo  = (u16*)(ws + (48ll  << 20));
    u16* qkv  = (u16*)(ws + (48ll  << 20));
    u16* mbuf = (u16*)(ws + (80ll  << 20));
    u16* qh   = (u16*)(ws + (96ll  << 20));
    u16* Wo   = (u16*)(ws + (112ll << 20));
    u16* kh   = (u16*)(ws + (112ll << 20));
    u16* vh   = (u16*)(ws);
    float* xo = (float*)d_out;

    rmsnorm_k<<<MR, 256, 0, stream>>>(x, anw, hbuf);
    cvt_w<<<6144, 256, 0, stream>>>(qkvw, Wq);                     // 3DM*DM
    gemm_big<0><<<384, 512, 0, stream>>>(hbuf, Wq, qkv, MR, 3 * DM, DM, DM);
    rope_split_k<<<MR, 256, 0, stream>>>(qkv, rc, qnw, knw, qh, kh, vh);
    transpose_v<<<dim3(32, 2, 32), 256, 0, stream>>>(vh, vt);
    attn_k<<<dim3(16, 32), 256, 0, stream>>>(qh, kh, vt, aout);
    cvt_w<<<2048, 256, 0, stream>>>(opw, Wo);                      // DM*DM (kh dead)
    cvt_w<<<8192, 256, 0, stream>>>(mow, Wmo);                     // DM*FFN (qkv dead)
    gemm_ring<2><<<dim3(16, 32), 256, 0, stream>>>(aout, Wo, x, xo, MR, DM, DM, DM);
    rmsnorm_k<<<MR, 256, 0, stream>>>(xo, mnw, hbuf);
    cvt_w<<<8192, 256, 0, stream>>>(miw, Wmi);                     // FFN*DM (vt/aout dead)
    // MLP in two FFN halves; mbuf is 4096x4096 bf16, d_out accumulates in f32.
    gemm_big<1><<<256, 512, 0, stream>>>(hbuf, Wmi, mbuf, MR, FFN / 2, DM, DM);
    gemm_ring<2><<<dim3(16, 32), 256, 0, stream>>>(mbuf, Wmo, xo, xo, MR, DM, FFN / 2, FFN);
    gemm_big<1><<<256, 512, 0, stream>>>(hbuf, Wmi + (size_t)(FFN / 2) * DM, mbuf, MR, FFN / 2, DM, DM);
    gemm_ring<2><<<dim3(16, 32), 256, 0, stream>>>(mbuf, Wmo + FFN / 2, xo, xo, MR, DM, FFN / 2, FFN);
}

// Round 6
// 883.548 us; speedup vs baseline: 1.6370x; 1.0511x over previous
//
#include <hip/hip_runtime.h>
#include <stdint.h>

#define TT 2048
#define DM 2048
#define NH 16
#define HD 128
#define FFN 8192
#define MR 4096   // B*T
#define EPSF 1.1920928955078125e-07f
#define NEGBIG (-1.0e30f)

typedef __attribute__((ext_vector_type(8))) short short8;
typedef __attribute__((ext_vector_type(4))) float f32x4;
typedef unsigned short u16;
typedef unsigned int u32;

__device__ __forceinline__ float bf2f(u32 u) {
    return __uint_as_float((u & 0xffffu) << 16);
}
__device__ __forceinline__ u16 f2bf(float f) {
    u32 x = __float_as_uint(f);
    return (u16)((x + 0x7fffu + ((x >> 16) & 1u)) >> 16);
}
__device__ __forceinline__ void load8f(const u16* p, float* v) {
    uint4 d = *(const uint4*)p;
    v[0] = bf2f(d.x); v[1] = bf2f(d.x >> 16);
    v[2] = bf2f(d.y); v[3] = bf2f(d.y >> 16);
    v[4] = bf2f(d.z); v[5] = bf2f(d.z >> 16);
    v[6] = bf2f(d.w); v[7] = bf2f(d.w >> 16);
}
__device__ __forceinline__ void load8f32(const float* p, float* v) {
    float4 a = *(const float4*)p, b = *(const float4*)(p + 4);
    v[0]=a.x; v[1]=a.y; v[2]=a.z; v[3]=a.w; v[4]=b.x; v[5]=b.y; v[6]=b.z; v[7]=b.w;
}
__device__ __forceinline__ void store8bf(u16* p, const float* v) {
    uint4 o;
    o.x = (u32)f2bf(v[0]) | ((u32)f2bf(v[1]) << 16);
    o.y = (u32)f2bf(v[2]) | ((u32)f2bf(v[3]) << 16);
    o.z = (u32)f2bf(v[4]) | ((u32)f2bf(v[5]) << 16);
    o.w = (u32)f2bf(v[6]) | ((u32)f2bf(v[7]) << 16);
    *(uint4*)p = o;
}
__device__ __forceinline__ uint4 cvt8_f32_bf16(const float* p) {
    float4 a = *(const float4*)p, b = *(const float4*)(p + 4);
    uint4 o;
    o.x = (u32)f2bf(a.x) | ((u32)f2bf(a.y) << 16);
    o.y = (u32)f2bf(a.z) | ((u32)f2bf(a.w) << 16);
    o.z = (u32)f2bf(b.x) | ((u32)f2bf(b.y) << 16);
    o.w = (u32)f2bf(b.z) | ((u32)f2bf(b.w) << 16);
    return o;
}
__device__ __forceinline__ void gload_lds16(const void* g, void* l) {
    __builtin_amdgcn_global_load_lds((const __attribute__((address_space(1))) u32*)g,
                                     (__attribute__((address_space(3))) u32*)l, 16, 0, 0);
}

// ---------------- weight f32 -> bf16 (8 elems/thread) ----------------
__global__ __launch_bounds__(256)
void cvt_w(const float* __restrict__ S, u16* __restrict__ D) {
    size_t i = ((size_t)blockIdx.x * 256 + threadIdx.x) * 8;
    *(uint4*)(D + i) = cvt8_f32_bf16(S + i);
}

// ---------------- RMSNorm (f32 in, bf16 out): one block per row of 2048 ----------------
__global__ __launch_bounds__(256)
void rmsnorm_k(const float* __restrict__ X, const float* __restrict__ W, u16* __restrict__ O) {
    const int row = blockIdx.x, tid = threadIdx.x;
    float v[8];
    load8f32(X + (size_t)row * DM + tid * 8, v);
    float ssq = 0.f;
#pragma unroll
    for (int i = 0; i < 8; ++i) ssq += v[i] * v[i];
#pragma unroll
    for (int d = 1; d < 64; d <<= 1) ssq += __shfl_xor(ssq, d);
    __shared__ float red[4];
    if ((tid & 63) == 0) red[tid >> 6] = ssq;
    __syncthreads();
    ssq = red[0] + red[1] + red[2] + red[3];
    const float inv = rsqrtf(ssq * (1.f / DM) + EPSF);
    float wv[8], o[8];
    load8f32(W + tid * 8, wv);
#pragma unroll
    for (int i = 0; i < 8; ++i) o[i] = v[i] * inv * wv[i];
    store8bf(O + (size_t)row * DM + tid * 8, o);
}

// ---------------- GEMM 128x128, 4-deep LDS ring, counted vmcnt, 2 blocks/CU ----------
// v5: fragment reads for step t+1 issued inside step t's MFMA cluster (in-place
// overwrite after last use) -> LDS pipe overlaps matrix pipe. vmcnt(4) publishes
// stages t AND t+1 at the barrier so the pre-read is race-free.
// EPI: 0 = bf16 out, 1 = relu^2 bf16 out, 2 = + f32 Res -> f32 out
template<int EPI>
__global__ __launch_bounds__(256, 2)
void gemm_ring(const u16* __restrict__ A, const u16* __restrict__ Bw,
               const float* __restrict__ Res, void* __restrict__ Cp,
               int M, int N, int K, int ldb) {
    __shared__ alignas(16) u16 As[4][128 * 32];
    __shared__ alignas(16) u16 Bs[4][128 * 32];
    const int tid = threadIdx.x;
    const int lane = tid & 63, w = tid >> 6;
    const int quad = lane >> 4, col = lane & 15;
    const int n0 = blockIdx.x * 128, m0 = blockIdx.y * 128;
    const int wm = (w >> 1) * 64, wn = (w & 1) * 64;

    const int c0 = tid, c1 = tid + 256;
    const int ar0 = c0 >> 2, aq0 = (c0 & 3) ^ ((ar0 >> 1) & 3);
    const int ar1 = c1 >> 2, aq1 = (c1 & 3) ^ ((ar1 >> 1) & 3);
    const u16* agp0 = A  + (size_t)(m0 + ar0) * K + aq0 * 8;
    const u16* agp1 = A  + (size_t)(m0 + ar1) * K + aq1 * 8;
    const u16* bgp0 = Bw + (size_t)(n0 + ar0) * ldb + aq0 * 8;
    const u16* bgp1 = Bw + (size_t)(n0 + ar1) * ldb + aq1 * 8;
    const int l0 = c0 * 8, l1 = c1 * 8;

    int aoff[4], boff[4];
#pragma unroll
    for (int i = 0; i < 4; ++i) {
        int r = wm + i * 16 + col;
        aoff[i] = r * 32 + (quad ^ ((r >> 1) & 3)) * 8;
        r = wn + i * 16 + col;
        boff[i] = r * 32 + (quad ^ ((r >> 1) & 3)) * 8;
    }

    f32x4 acc[4][4];
#pragma unroll
    for (int i = 0; i < 4; ++i)
#pragma unroll
        for (int j = 0; j < 4; ++j) acc[i][j] = (f32x4){0.f, 0.f, 0.f, 0.f};

    const int KT = K >> 5;

#define GR_STAGE(s) { const int _b = (s) & 3; const size_t _ko = (size_t)(s) * 32; \
    gload_lds16(agp0 + _ko, &As[_b][l0]); \
    gload_lds16(agp1 + _ko, &As[_b][l1]); \
    gload_lds16(bgp0 + _ko, &Bs[_b][l0]); \
    gload_lds16(bgp1 + _ko, &Bs[_b][l1]); }

    GR_STAGE(0);
    GR_STAGE(1);
    GR_STAGE(2);

    // prologue: publish stage 0, read its fragments
    asm volatile("s_waitcnt vmcnt(8)" ::: "memory");
    __builtin_amdgcn_s_barrier();
    short8 af[4], bfr[4];
#pragma unroll
    for (int i = 0; i < 4; ++i) af[i]  = *(const short8*)(As[0] + aoff[i]);
#pragma unroll
    for (int i = 0; i < 4; ++i) bfr[i] = *(const short8*)(Bs[0] + boff[i]);

    for (int t = 0; t < KT; ++t) {
        // publish stages t and t+1 (pre-read of t+1 is then race-free)
        if (t <= KT - 3) asm volatile("s_waitcnt vmcnt(4)" ::: "memory");
        else             asm volatile("s_waitcnt vmcnt(0)" ::: "memory");
        __builtin_amdgcn_s_barrier();
        if (t + 3 < KT) GR_STAGE(t + 3);
        const u16* abn = As[(t + 1) & 3];
        const u16* bbn = Bs[(t + 1) & 3];
        __builtin_amdgcn_s_setprio(1);
#pragma unroll
        for (int mi = 0; mi < 4; ++mi) {
#pragma unroll
            for (int ni = 0; ni < 4; ++ni)
                acc[mi][ni] = __builtin_amdgcn_mfma_f32_16x16x32_bf16(af[mi], bfr[ni], acc[mi][ni], 0, 0, 0);
            af[mi] = *(const short8*)(abn + aoff[mi]);   // frag(t+1), in MFMA shadow
        }
        __builtin_amdgcn_s_setprio(0);
#pragma unroll
        for (int ni = 0; ni < 4; ++ni) bfr[ni] = *(const short8*)(bbn + boff[ni]);
        __builtin_amdgcn_sched_barrier(0);
    }
#undef GR_STAGE

#pragma unroll
    for (int mi = 0; mi < 4; ++mi)
#pragma unroll
        for (int ni = 0; ni < 4; ++ni) {
            const int rbase = m0 + wm + mi * 16 + quad * 4;
            const int cc = n0 + wn + ni * 16 + col;
#pragma unroll
            for (int rr = 0; rr < 4; ++rr) {
                float v = acc[mi][ni][rr];
                size_t idx = (size_t)(rbase + rr) * N + cc;
                if (EPI == 0) ((u16*)Cp)[idx] = f2bf(v);
                else if (EPI == 1) { float t2 = fmaxf(v, 0.f); ((u16*)Cp)[idx] = f2bf(t2 * t2); }
                else ((float*)Cp)[idx] = v + Res[idx];
            }
        }
}

// ---------------- GEMM 256x256, 8 waves, 4-deep LDS ring, counted vmcnt ----------------
// v5: same in-cluster fragment pre-read pipelining as gemm_ring.
template<int EPI>
__global__ __launch_bounds__(512, 2)
void gemm_big(const u16* __restrict__ A, const u16* __restrict__ Bw,
              void* __restrict__ Cp, int M, int N, int K, int ldb) {
    __shared__ alignas(16) u16 As[4][256 * 32];
    __shared__ alignas(16) u16 Bs[4][256 * 32];
    const int tid = threadIdx.x;
    const int lane = tid & 63, w = tid >> 6;
    const int wr = w >> 2, wc = w & 3;              // 2M x 4N wave grid
    const int quad = lane >> 4, colL = lane & 15;

    const int nbx = N >> 8;
    const int nwg = gridDim.x;
    const int cpx = nwg >> 3;
    const int bid = blockIdx.x;
    const int swz = (bid & 7) * cpx + (bid >> 3);
    const int by = swz / nbx, bx = swz - by * nbx;
    const int m0 = by << 8, n0 = bx << 8;

    const int r0 = tid >> 2,       q0 = (tid & 3) ^ ((r0 >> 1) & 3);
    const int p1 = tid + 512;
    const int r1 = p1 >> 2,        q1 = (p1 & 3) ^ ((r1 >> 1) & 3);
    const u16* agp0 = A  + (size_t)(m0 + r0) * K   + q0 * 8;
    const u16* agp1 = A  + (size_t)(m0 + r1) * K   + q1 * 8;
    const u16* bgp0 = Bw + (size_t)(n0 + r0) * ldb + q0 * 8;
    const u16* bgp1 = Bw + (size_t)(n0 + r1) * ldb + q1 * 8;
    const int l0 = tid * 8, l1 = p1 * 8;

    int aoff[8], boff[4];
#pragma unroll
    for (int mi = 0; mi < 8; ++mi) {
        int r = wr * 128 + mi * 16 + colL;
        aoff[mi] = r * 32 + (quad ^ ((r >> 1) & 3)) * 8;
    }
#pragma unroll
    for (int ni = 0; ni < 4; ++ni) {
        int r = wc * 64 + ni * 16 + colL;
        boff[ni] = r * 32 + (quad ^ ((r >> 1) & 3)) * 8;
    }

    f32x4 acc[8][4];
#pragma unroll
    for (int i = 0; i < 8; ++i)
#pragma unroll
        for (int j = 0; j < 4; ++j) acc[i][j] = (f32x4){0.f, 0.f, 0.f, 0.f};

    const int KT = K >> 5;

#define GB_STAGE(s) { const int _b = (s) & 3; const size_t _ko = (size_t)(s) * 32; \
    gload_lds16(agp0 + _ko, &As[_b][l0]); \
    gload_lds16(agp1 + _ko, &As[_b][l1]); \
    gload_lds16(bgp0 + _ko, &Bs[_b][l0]); \
    gload_lds16(bgp1 + _ko, &Bs[_b][l1]); }

    GB_STAGE(0);
    GB_STAGE(1);
    GB_STAGE(2);

    asm volatile("s_waitcnt vmcnt(8)" ::: "memory");
    __builtin_amdgcn_s_barrier();
    short8 af[8], bfr[4];
#pragma unroll
    for (int i = 0; i < 8; ++i) af[i]  = *(const short8*)(As[0] + aoff[i]);
#pragma unroll
    for (int i = 0; i < 4; ++i) bfr[i] = *(const short8*)(Bs[0] + boff[i]);

    for (int t = 0; t < KT; ++t) {
        if (t <= KT - 3) asm volatile("s_waitcnt vmcnt(4)" ::: "memory");
        else             asm volatile("s_waitcnt vmcnt(0)" ::: "memory");
        __builtin_amdgcn_s_barrier();
        if (t + 3 < KT) GB_STAGE(t + 3);
        const u16* abn = As[(t + 1) & 3];
        const u16* bbn = Bs[(t + 1) & 3];
        __builtin_amdgcn_s_setprio(1);
#pragma unroll
        for (int mi = 0; mi < 8; ++mi) {
#pragma unroll
            for (int ni = 0; ni < 4; ++ni)
                acc[mi][ni] = __builtin_amdgcn_mfma_f32_16x16x32_bf16(af[mi], bfr[ni], acc[mi][ni], 0, 0, 0);
            af[mi] = *(const short8*)(abn + aoff[mi]);   // frag(t+1), in MFMA shadow
        }
        __builtin_amdgcn_s_setprio(0);
#pragma unroll
        for (int ni = 0; ni < 4; ++ni) bfr[ni] = *(const short8*)(bbn + boff[ni]);
        __builtin_amdgcn_sched_barrier(0);
    }
#undef GB_STAGE

#pragma unroll
    for (int mi = 0; mi < 8; ++mi)
#pragma unroll
        for (int ni = 0; ni < 4; ++ni) {
            const int rbase = m0 + wr * 128 + mi * 16 + quad * 4;
            const int cc = n0 + wc * 64 + ni * 16 + colL;
#pragma unroll
            for (int rr = 0; rr < 4; ++rr) {
                float v = acc[mi][ni][rr];
                size_t idx = (size_t)(rbase + rr) * N + cc;
                if (EPI == 0) ((u16*)Cp)[idx] = f2bf(v);
                else { float tq = fmaxf(v, 0.f); ((u16*)Cp)[idx] = f2bf(tq * tq); }
            }
        }
}

// ---------------- RoPE + per-head RMSNorm on q,k; split v ----------------
__global__ __launch_bounds__(256)
void rope_split_k(const u16* __restrict__ QKV, const float* __restrict__ RC,
                  const float* __restrict__ QW, const float* __restrict__ KW,
                  u16* __restrict__ Qo, u16* __restrict__ Ko, u16* __restrict__ Vo) {
    const int row = blockIdx.x;                 // b*T + t
    const int t = row & (TT - 1), b = row >> 11;
    const int tid = threadIdx.x, h = tid >> 4, j = tid & 15;
    const size_t qb = (size_t)row * (3 * DM) + h * HD + j * 8;
    float q[8], k[8], cs[8], sn[8];
    load8f(QKV + qb, q);
    load8f(QKV + qb + DM, k);
    uint4 vv = *(const uint4*)(QKV + qb + 2 * DM);
    load8f32(RC + (size_t)t * HD + j * 8, cs);
    load8f32(RC + (size_t)(TT + t) * HD + j * 8, sn);
    float qr[8], kr[8];
#pragma unroll
    for (int p = 0; p < 4; ++p) {
        float c = cs[2 * p], s = sn[2 * p];
        qr[2*p]   = q[2*p]   * c - q[2*p+1] * s;
        qr[2*p+1] = q[2*p+1] * c + q[2*p]   * s;
        kr[2*p]   = k[2*p]   * c - k[2*p+1] * s;
        kr[2*p+1] = k[2*p+1] * c + k[2*p]   * s;
    }
    float sq = 0.f, sk = 0.f;
#pragma unroll
    for (int i = 0; i < 8; ++i) { sq += qr[i] * qr[i]; sk += kr[i] * kr[i]; }
#pragma unroll
    for (int d = 1; d < 16; d <<= 1) { sq += __shfl_xor(sq, d); sk += __shfl_xor(sk, d); }
    const float iq = rsqrtf(sq * (1.f / HD) + EPSF);
    const float ik = rsqrtf(sk * (1.f / HD) + EPSF);
    float qw[8], kw[8], oq[8], ok[8];
    load8f32(QW + j * 8, qw); load8f32(KW + j * 8, kw);
#pragma unroll
    for (int i = 0; i < 8; ++i) { oq[i] = qr[i] * iq * qw[i]; ok[i] = kr[i] * ik * kw[i]; }
    const size_t ob = ((size_t)(b * NH + h) * TT + t) * HD + j * 8;
    store8bf(Qo + ob, oq);
    store8bf(Ko + ob, ok);
    *(uint4*)(Vo + ob) = vv;
}

// ---------------- V transpose: [bh][T][128] -> [bh][128][T] ----------------
__global__ __launch_bounds__(256)
void transpose_v(const u16* __restrict__ V, u16* __restrict__ Vt) {
    __shared__ alignas(16) u16 tile[64][72];
    const int bh = blockIdx.z;
    const int t0 = blockIdx.x * 64, d0 = blockIdx.y * 64;
    const int tid = threadIdx.x;
#pragma unroll
    for (int i = 0; i < 2; ++i) {
        int c = i * 256 + tid;
        int r = c >> 3, cc = (c & 7) * 8;
        *(uint4*)(&tile[r][cc]) = *(const uint4*)(V + ((size_t)bh * TT + t0 + r) * HD + d0 + cc);
    }
    __syncthreads();
#pragma unroll
    for (int i = 0; i < 2; ++i) {
        int c = i * 256 + tid;
        int dc = c >> 3, rr = (c & 7) * 8;
        u16 tmp[8];
#pragma unroll
        for (int kk = 0; kk < 8; ++kk) tmp[kk] = tile[rr + kk][dc];
        uint4 o;
        o.x = (u32)tmp[0] | ((u32)tmp[1] << 16);
        o.y = (u32)tmp[2] | ((u32)tmp[3] << 16);
        o.z = (u32)tmp[4] | ((u32)tmp[5] << 16);
        o.w = (u32)tmp[6] | ((u32)tmp[7] << 16);
        *(uint4*)(Vt + ((size_t)bh * HD + d0 + dc) * TT + t0 + rr) = o;
    }
}

// ---------------- Causal flash attention, 128-query tile, 4 waves x 32 q/wave ----------
// v6: (1) makespan-balanced grid: dispatch i gets qt 15..8 (long), dispatch i+256 gets
//     qt 0..7 (short) -> each CU's two blocks sum to ~36 K-tiles (was up to 64).
//     (2) row-sum via MFMA against a ones-B fragment inside PV (matrix pipe) --
//     removes 32 shuffle-swizzles + 32 VALU adds per tile from the loaded LDS pipe.
__global__ __launch_bounds__(256, 2)
void attn_k(const u16* __restrict__ Q, const u16* __restrict__ Kg,
            const u16* __restrict__ Vt, u16* __restrict__ O) {
    __shared__ alignas(16) u16 k_lds[2][64 * 128];
    __shared__ alignas(16) u16 v_lds[2][128 * 64];
    __shared__ alignas(16) u16 p_lds[128 * 40];
    const int bh = blockIdx.x;                     // 0..31
    const int yy = blockIdx.y;                     // 0..15
    const int qt = (yy < 8) ? (15 - yy) : (yy - 8); // long blocks dispatched first
    const int tid = threadIdx.x, lane = tid & 63, w = tid >> 6;
    const int quad = lane >> 4, col = lane & 15;
    const int qbase = qt * 128;
    const int wq = qbase + w * 32;

    short8 qf[2][4];
#pragma unroll
    for (int sub = 0; sub < 2; ++sub) {
        const u16* qp = Q + ((size_t)bh * TT + wq + sub * 16 + col) * HD;
#pragma unroll
        for (int s = 0; s < 4; ++s) qf[sub][s] = *(const short8*)(qp + s * 32 + quad * 8);
    }
    short8 ones8;
#pragma unroll
    for (int j = 0; j < 8; ++j) ones8[j] = (short)0x3F80;   // bf16 1.0

    const u16* kp[4]; const u16* vp[4];
#pragma unroll
    for (int i = 0; i < 4; ++i) {
        int lin = i * 256 + tid;
        int r = lin >> 4, sl = lin & 15;
        int gq = sl ^ (r & 15);
        kp[i] = Kg + ((size_t)bh * TT + r) * HD + gq * 8;
    }
#pragma unroll
    for (int i = 0; i < 4; ++i) {
        int lin = i * 256 + tid;
        int r = lin >> 3, sl = lin & 7;
        int gq = sl ^ (r & 7);
        vp[i] = Vt + ((size_t)bh * HD + r) * TT + gq * 8;
    }

    f32x4 oacc[2][8];
#pragma unroll
    for (int s = 0; s < 2; ++s)
#pragma unroll
        for (int i = 0; i < 8; ++i) oacc[s][i] = (f32x4){0.f, 0.f, 0.f, 0.f};
    float mrow[2][4], lrow[2][4];
#pragma unroll
    for (int s = 0; s < 2; ++s)
#pragma unroll
        for (int r = 0; r < 4; ++r) { mrow[s][r] = NEGBIG; lrow[s][r] = 0.f; }
    const float scale = 0.08838834764831845f;   // 1/sqrt(128)

    u16* kcur = k_lds[0]; u16* knxt = k_lds[1];
    u16* vcur = v_lds[0]; u16* vnxt = v_lds[1];
#pragma unroll
    for (int i = 0; i < 4; ++i) gload_lds16(kp[i], kcur + (i * 256 + tid) * 8);
#pragma unroll
    for (int i = 0; i < 4; ++i) gload_lds16(vp[i], vcur + (i * 256 + tid) * 8);

    const int ktmax = 2 * qt + 1;
    for (int kt = 0; kt <= ktmax; ++kt) {
        const int kb = kt * 64;
        __syncthreads();   // drains vmcnt(0): buf[cur] staged, buf[nxt] reads done

        if (kt < ktmax) {  // prefetch next K/V tile into the other buffer (async)
            const int kb2 = kb + 64;
#pragma unroll
            for (int i = 0; i < 4; ++i) gload_lds16(kp[i] + (size_t)kb2 * HD, knxt + (i * 256 + tid) * 8);
#pragma unroll
            for (int i = 0; i < 4; ++i) gload_lds16(vp[i] + kb2, vnxt + (i * 256 + tid) * 8);
        }

        f32x4 sfr[2][4];
#pragma unroll
        for (int s = 0; s < 2; ++s)
#pragma unroll
            for (int ni = 0; ni < 4; ++ni) sfr[s][ni] = (f32x4){0.f, 0.f, 0.f, 0.f};
        __builtin_amdgcn_s_setprio(1);
#pragma unroll
        for (int ni = 0; ni < 4; ++ni) {
            const int r = ni * 16 + col;
#pragma unroll
            for (int s = 0; s < 4; ++s) {
                int sl = (s * 4 + quad) ^ (r & 15);
                short8 kf = *(const short8*)(kcur + r * 128 + sl * 8);
                sfr[0][ni] = __builtin_amdgcn_mfma_f32_16x16x32_bf16(qf[0][s], kf, sfr[0][ni], 0, 0, 0);
                sfr[1][ni] = __builtin_amdgcn_mfma_f32_16x16x32_bf16(qf[1][s], kf, sfr[1][ni], 0, 0, 0);
            }
        }
        __builtin_amdgcn_s_setprio(0);
#pragma unroll
        for (int sub = 0; sub < 2; ++sub)
#pragma unroll
            for (int ni = 0; ni < 4; ++ni) {
                const int key = kb + ni * 16 + col;
#pragma unroll
                for (int rr = 0; rr < 4; ++rr) {
                    float v = sfr[sub][ni][rr] * scale;
                    int qv = wq + sub * 16 + quad * 4 + rr;
                    if (key > qv) v = NEGBIG;
                    sfr[sub][ni][rr] = v;
                }
            }
        float mx[2][4];
#pragma unroll
        for (int sub = 0; sub < 2; ++sub)
#pragma unroll
            for (int rr = 0; rr < 4; ++rr)
                mx[sub][rr] = fmaxf(fmaxf(sfr[sub][0][rr], sfr[sub][1][rr]),
                                    fmaxf(sfr[sub][2][rr], sfr[sub][3][rr]));
#pragma unroll
        for (int d = 1; d < 16; d <<= 1)
#pragma unroll
            for (int sub = 0; sub < 2; ++sub)
#pragma unroll
                for (int rr = 0; rr < 4; ++rr) mx[sub][rr] = fmaxf(mx[sub][rr], __shfl_xor(mx[sub][rr], d));
        bool grew = false;
#pragma unroll
        for (int sub = 0; sub < 2; ++sub)
#pragma unroll
            for (int rr = 0; rr < 4; ++rr) grew = grew || (mx[sub][rr] > mrow[sub][rr]);
        if (__any(grew)) {
#pragma unroll
            for (int sub = 0; sub < 2; ++sub)
#pragma unroll
                for (int rr = 0; rr < 4; ++rr) {
                    float mn = fmaxf(mrow[sub][rr], mx[sub][rr]);
                    float a = __expf(mrow[sub][rr] - mn);
                    mrow[sub][rr] = mn;
                    lrow[sub][rr] *= a;
#pragma unroll
                    for (int i = 0; i < 8; ++i) oacc[sub][i][rr] *= a;
                }
        }
#pragma unroll
        for (int sub = 0; sub < 2; ++sub)
#pragma unroll
            for (int ni = 0; ni < 4; ++ni)
#pragma unroll
                for (int rr = 0; rr < 4; ++rr)
                    sfr[sub][ni][rr] = __expf(sfr[sub][ni][rr] - mrow[sub][rr]);
        // row-sum computed by MFMA (P x ones) inside PV below -- no shuffle reduce.
        f32x4 sacc[2];
        sacc[0] = (f32x4){0.f, 0.f, 0.f, 0.f};
        sacc[1] = (f32x4){0.f, 0.f, 0.f, 0.f};
#pragma unroll
        for (int ks = 0; ks < 2; ++ks) {
#pragma unroll
            for (int sub = 0; sub < 2; ++sub)
#pragma unroll
                for (int nio = 0; nio < 2; ++nio) {
                    const int ni = ks * 2 + nio;
#pragma unroll
                    for (int rr = 0; rr < 4; ++rr)
                        p_lds[(w * 32 + sub * 16 + quad * 4 + rr) * 40 + nio * 16 + col] = f2bf(sfr[sub][ni][rr]);
                }
            short8 pa0 = *(const short8*)(p_lds + (w * 32 + col) * 40 + quad * 8);
            short8 pa1 = *(const short8*)(p_lds + (w * 32 + 16 + col) * 40 + quad * 8);
            __builtin_amdgcn_s_setprio(1);
#pragma unroll
            for (int di = 0; di < 8; ++di) {
                int r = di * 16 + col;
                int sl = (ks * 4 + quad) ^ (r & 7);
                short8 vb = *(const short8*)(vcur + r * 64 + sl * 8);
                oacc[0][di] = __builtin_amdgcn_mfma_f32_16x16x32_bf16(pa0, vb, oacc[0][di], 0, 0, 0);
                oacc[1][di] = __builtin_amdgcn_mfma_f32_16x16x32_bf16(pa1, vb, oacc[1][di], 0, 0, 0);
            }
            sacc[0] = __builtin_amdgcn_mfma_f32_16x16x32_bf16(pa0, ones8, sacc[0], 0, 0, 0);
            sacc[1] = __builtin_amdgcn_mfma_f32_16x16x32_bf16(pa1, ones8, sacc[1], 0, 0, 0);
            __builtin_amdgcn_s_setprio(0);
        }
#pragma unroll
        for (int sub = 0; sub < 2; ++sub)
#pragma unroll
            for (int rr = 0; rr < 4; ++rr) lrow[sub][rr] += sacc[sub][rr];
        { u16* t = kcur; kcur = knxt; knxt = t; }
        { u16* t = vcur; vcur = vnxt; vnxt = t; }
    }
    const int b = bh >> 4, hh = bh & 15;
#pragma unroll
    for (int sub = 0; sub < 2; ++sub)
#pragma unroll
        for (int di = 0; di < 8; ++di)
#pragma unroll
            for (int rr = 0; rr < 4; ++rr) {
                int trow = wq + sub * 16 + quad * 4 + rr;
                float ov = oacc[sub][di][rr] / lrow[sub][rr];
                O[((size_t)(b * TT + trow)) * DM + hh * HD + di * 16 + col] = f2bf(ov);
            }
}

extern "C" void kernel_launch(void* const* d_in, const int* in_sizes, int n_in,
                              void* d_out, int out_size, void* d_ws, size_t ws_size,
                              hipStream_t stream) {
    const float* x    = (const float*)d_in[0];
    const float* rc   = (const float*)d_in[1];
    const float* anw  = (const float*)d_in[2];
    const float* qkvw = (const float*)d_in[3];
    const float* qnw  = (const float*)d_in[4];
    const float* knw  = (const float*)d_in[5];
    const float* opw  = (const float*)d_in[6];
    const float* mnw  = (const float*)d_in[7];
    const float* miw  = (const float*)d_in[8];
    const float* mow  = (const float*)d_in[9];

    char* ws = (char*)d_ws;
    // Workspace plan, 120 MiB peak (MiB offsets). Late-phase owners:
    //   hbuf[0,16) Wmi[16,48) Wmo[48,80) mbuf[80,112) Wo[112,120)
    // Early/mid aliases (dead before late owner is written):
    //   Wq[16,40)  qkv[48,96)  qh[96,112)  kh[112,128)  vh[0,16)  vt[16,32)  aout[32,48)
    // Residual x2 lives in d_out (f32), accumulated by the mlp_out halves.
    u16* hbuf = (u16*)(ws);
    u16* Wq   = (u16*)(ws + (16ll  << 20));
    u16* Wmi  = (u16*)(ws + (16ll  << 20));
    u16* vt   = (u16*)(ws + (16ll  << 20));
    u16* aout = (u16*)(ws + (32ll  << 20));
    u16* Wmo  = (u16*)(ws + (48ll  << 20));
    u16* qkv  = (u16*)(ws + (48ll  << 20));
    u16* mbuf = (u16*)(ws + (80ll  << 20));
    u16* qh   = (u16*)(ws + (96ll  << 20));
    u16* Wo   = (u16*)(ws + (112ll << 20));
    u16* kh   = (u16*)(ws + (112ll << 20));
    u16* vh   = (u16*)(ws);
    float* xo = (float*)d_out;

    rmsnorm_k<<<MR, 256, 0, stream>>>(x, anw, hbuf);
    cvt_w<<<6144, 256, 0, stream>>>(qkvw, Wq);                     // 3DM*DM
    gemm_big<0><<<384, 512, 0, stream>>>(hbuf, Wq, qkv, MR, 3 * DM, DM, DM);
    rope_split_k<<<MR, 256, 0, stream>>>(qkv, rc, qnw, knw, qh, kh, vh);
    transpose_v<<<dim3(32, 2, 32), 256, 0, stream>>>(vh, vt);
    attn_k<<<dim3(32, 16), 256, 0, stream>>>(qh, kh, vt, aout);
    cvt_w<<<2048, 256, 0, stream>>>(opw, Wo);                      // DM*DM (kh dead)
    cvt_w<<<8192, 256, 0, stream>>>(mow, Wmo);                     // DM*FFN (qkv dead)
    gemm_ring<2><<<dim3(16, 32), 256, 0, stream>>>(aout, Wo, x, xo, MR, DM, DM, DM);
    rmsnorm_k<<<MR, 256, 0, stream>>>(xo, mnw, hbuf);
    cvt_w<<<8192, 256, 0, stream>>>(miw, Wmi);                     // FFN*DM (vt/aout dead)
    // MLP in two FFN halves; mbuf is 4096x4096 bf16, d_out accumulates in f32.
    gemm_big<1><<<256, 512, 0, stream>>>(hbuf, Wmi, mbuf, MR, FFN / 2, DM, DM);
    gemm_ring<2><<<dim3(16, 32), 256, 0, stream>>>(mbuf, Wmo, xo, xo, MR, DM, FFN / 2, FFN);
    gemm_big<1><<<256, 512, 0, stream>>>(hbuf, Wmi + (size_t)(FFN / 2) * DM, mbuf, MR, FFN / 2, DM, DM);
    gemm_ring<2><<<dim3(16, 32), 256, 0, stream>>>(mbuf, Wmo + FFN / 2, xo, xo, MR, DM, FFN / 2, FFN);
}

// Round 7
// 865.097 us; speedup vs baseline: 1.6719x; 1.0213x over previous
//
#include <hip/hip_runtime.h>
#include <stdint.h>

#define TT 2048
#define DM 2048
#define NH 16
#define HD 128
#define FFN 8192
#define MR 4096   // B*T
#define EPSF 1.1920928955078125e-07f
#define NEGBIG (-1.0e30f)

typedef __attribute__((ext_vector_type(8))) short short8;
typedef __attribute__((ext_vector_type(4))) float f32x4;
typedef unsigned short u16;
typedef unsigned int u32;

__device__ __forceinline__ float bf2f(u32 u) {
    return __uint_as_float((u & 0xffffu) << 16);
}
__device__ __forceinline__ u16 f2bf(float f) {
    u32 x = __float_as_uint(f);
    return (u16)((x + 0x7fffu + ((x >> 16) & 1u)) >> 16);
}
__device__ __forceinline__ void load8f(const u16* p, float* v) {
    uint4 d = *(const uint4*)p;
    v[0] = bf2f(d.x); v[1] = bf2f(d.x >> 16);
    v[2] = bf2f(d.y); v[3] = bf2f(d.y >> 16);
    v[4] = bf2f(d.z); v[5] = bf2f(d.z >> 16);
    v[6] = bf2f(d.w); v[7] = bf2f(d.w >> 16);
}
__device__ __forceinline__ void load8f32(const float* p, float* v) {
    float4 a = *(const float4*)p, b = *(const float4*)(p + 4);
    v[0]=a.x; v[1]=a.y; v[2]=a.z; v[3]=a.w; v[4]=b.x; v[5]=b.y; v[6]=b.z; v[7]=b.w;
}
__device__ __forceinline__ void store8bf(u16* p, const float* v) {
    uint4 o;
    o.x = (u32)f2bf(v[0]) | ((u32)f2bf(v[1]) << 16);
    o.y = (u32)f2bf(v[2]) | ((u32)f2bf(v[3]) << 16);
    o.z = (u32)f2bf(v[4]) | ((u32)f2bf(v[5]) << 16);
    o.w = (u32)f2bf(v[6]) | ((u32)f2bf(v[7]) << 16);
    *(uint4*)p = o;
}
__device__ __forceinline__ uint4 cvt8_f32_bf16(const float* p) {
    float4 a = *(const float4*)p, b = *(const float4*)(p + 4);
    uint4 o;
    o.x = (u32)f2bf(a.x) | ((u32)f2bf(a.y) << 16);
    o.y = (u32)f2bf(a.z) | ((u32)f2bf(a.w) << 16);
    o.z = (u32)f2bf(b.x) | ((u32)f2bf(b.y) << 16);
    o.w = (u32)f2bf(b.z) | ((u32)f2bf(b.w) << 16);
    return o;
}
__device__ __forceinline__ void gload_lds16(const void* g, void* l) {
    __builtin_amdgcn_global_load_lds((const __attribute__((address_space(1))) u32*)g,
                                     (__attribute__((address_space(3))) u32*)l, 16, 0, 0);
}

// ---------------- weight f32 -> bf16 (8 elems/thread) ----------------
__global__ __launch_bounds__(256)
void cvt_w(const float* __restrict__ S, u16* __restrict__ D) {
    size_t i = ((size_t)blockIdx.x * 256 + threadIdx.x) * 8;
    *(uint4*)(D + i) = cvt8_f32_bf16(S + i);
}

// ---------------- RMSNorm (f32 in, bf16 out): one block per row of 2048 ----------------
__global__ __launch_bounds__(256)
void rmsnorm_k(const float* __restrict__ X, const float* __restrict__ W, u16* __restrict__ O) {
    const int row = blockIdx.x, tid = threadIdx.x;
    float v[8];
    load8f32(X + (size_t)row * DM + tid * 8, v);
    float ssq = 0.f;
#pragma unroll
    for (int i = 0; i < 8; ++i) ssq += v[i] * v[i];
#pragma unroll
    for (int d = 1; d < 64; d <<= 1) ssq += __shfl_xor(ssq, d);
    __shared__ float red[4];
    if ((tid & 63) == 0) red[tid >> 6] = ssq;
    __syncthreads();
    ssq = red[0] + red[1] + red[2] + red[3];
    const float inv = rsqrtf(ssq * (1.f / DM) + EPSF);
    float wv[8], o[8];
    load8f32(W + tid * 8, wv);
#pragma unroll
    for (int i = 0; i < 8; ++i) o[i] = v[i] * inv * wv[i];
    store8bf(O + (size_t)row * DM + tid * 8, o);
}

// ---------------- GEMM 128x128, 4-deep LDS ring, counted vmcnt, 2 blocks/CU ----------
// v6: ALL 8 fragment pre-reads (4 af + 4 bfr via bfr2 double-buffer) issued inside
// the MFMA cluster -> no exposed ds_read latency between steps. vmcnt(4) publishes
// stages t AND t+1 at the barrier so the pre-read is race-free.
// EPI: 0 = bf16 out, 1 = relu^2 bf16 out, 2 = + f32 Res -> f32 out
template<int EPI>
__global__ __launch_bounds__(256, 2)
void gemm_ring(const u16* __restrict__ A, const u16* __restrict__ Bw,
               const float* __restrict__ Res, void* __restrict__ Cp,
               int M, int N, int K, int ldb) {
    __shared__ alignas(16) u16 As[4][128 * 32];
    __shared__ alignas(16) u16 Bs[4][128 * 32];
    const int tid = threadIdx.x;
    const int lane = tid & 63, w = tid >> 6;
    const int quad = lane >> 4, col = lane & 15;
    const int n0 = blockIdx.x * 128, m0 = blockIdx.y * 128;
    const int wm = (w >> 1) * 64, wn = (w & 1) * 64;

    const int c0 = tid, c1 = tid + 256;
    const int ar0 = c0 >> 2, aq0 = (c0 & 3) ^ ((ar0 >> 1) & 3);
    const int ar1 = c1 >> 2, aq1 = (c1 & 3) ^ ((ar1 >> 1) & 3);
    const u16* agp0 = A  + (size_t)(m0 + ar0) * K + aq0 * 8;
    const u16* agp1 = A  + (size_t)(m0 + ar1) * K + aq1 * 8;
    const u16* bgp0 = Bw + (size_t)(n0 + ar0) * ldb + aq0 * 8;
    const u16* bgp1 = Bw + (size_t)(n0 + ar1) * ldb + aq1 * 8;
    const int l0 = c0 * 8, l1 = c1 * 8;

    int aoff[4], boff[4];
#pragma unroll
    for (int i = 0; i < 4; ++i) {
        int r = wm + i * 16 + col;
        aoff[i] = r * 32 + (quad ^ ((r >> 1) & 3)) * 8;
        r = wn + i * 16 + col;
        boff[i] = r * 32 + (quad ^ ((r >> 1) & 3)) * 8;
    }

    f32x4 acc[4][4];
#pragma unroll
    for (int i = 0; i < 4; ++i)
#pragma unroll
        for (int j = 0; j < 4; ++j) acc[i][j] = (f32x4){0.f, 0.f, 0.f, 0.f};

    const int KT = K >> 5;

#define GR_STAGE(s) { const int _b = (s) & 3; const size_t _ko = (size_t)(s) * 32; \
    gload_lds16(agp0 + _ko, &As[_b][l0]); \
    gload_lds16(agp1 + _ko, &As[_b][l1]); \
    gload_lds16(bgp0 + _ko, &Bs[_b][l0]); \
    gload_lds16(bgp1 + _ko, &Bs[_b][l1]); }

    GR_STAGE(0);
    GR_STAGE(1);
    GR_STAGE(2);

    // prologue: publish stage 0, read its fragments
    asm volatile("s_waitcnt vmcnt(8)" ::: "memory");
    __builtin_amdgcn_s_barrier();
    short8 af[4], bfr[4];
#pragma unroll
    for (int i = 0; i < 4; ++i) af[i]  = *(const short8*)(As[0] + aoff[i]);
#pragma unroll
    for (int i = 0; i < 4; ++i) bfr[i] = *(const short8*)(Bs[0] + boff[i]);

    for (int t = 0; t < KT; ++t) {
        // publish stages t and t+1 (pre-read of t+1 is then race-free)
        if (t <= KT - 3) asm volatile("s_waitcnt vmcnt(4)" ::: "memory");
        else             asm volatile("s_waitcnt vmcnt(0)" ::: "memory");
        __builtin_amdgcn_s_barrier();
        if (t + 3 < KT) GR_STAGE(t + 3);
        const u16* abn = As[(t + 1) & 3];
        const u16* bbn = Bs[(t + 1) & 3];
        short8 bfr2[4];
        __builtin_amdgcn_s_setprio(1);
#pragma unroll
        for (int mi = 0; mi < 4; ++mi) {
#pragma unroll
            for (int ni = 0; ni < 4; ++ni)
                acc[mi][ni] = __builtin_amdgcn_mfma_f32_16x16x32_bf16(af[mi], bfr[ni], acc[mi][ni], 0, 0, 0);
            bfr2[mi] = *(const short8*)(bbn + boff[mi]);  // frag(t+1), in MFMA shadow
            af[mi]   = *(const short8*)(abn + aoff[mi]);
        }
        __builtin_amdgcn_s_setprio(0);
#pragma unroll
        for (int ni = 0; ni < 4; ++ni) bfr[ni] = bfr2[ni];
        __builtin_amdgcn_sched_barrier(0);
    }
#undef GR_STAGE

#pragma unroll
    for (int mi = 0; mi < 4; ++mi)
#pragma unroll
        for (int ni = 0; ni < 4; ++ni) {
            const int rbase = m0 + wm + mi * 16 + quad * 4;
            const int cc = n0 + wn + ni * 16 + col;
#pragma unroll
            for (int rr = 0; rr < 4; ++rr) {
                float v = acc[mi][ni][rr];
                size_t idx = (size_t)(rbase + rr) * N + cc;
                if (EPI == 0) ((u16*)Cp)[idx] = f2bf(v);
                else if (EPI == 1) { float t2 = fmaxf(v, 0.f); ((u16*)Cp)[idx] = f2bf(t2 * t2); }
                else ((float*)Cp)[idx] = v + Res[idx];
            }
        }
}

// ---------------- GEMM 256x256, 8 waves, 4-deep LDS ring, counted vmcnt ----------------
// v6: all 12 fragment pre-reads (8 af + 4 bfr via bfr2) inside the MFMA cluster.
template<int EPI>
__global__ __launch_bounds__(512, 2)
void gemm_big(const u16* __restrict__ A, const u16* __restrict__ Bw,
              void* __restrict__ Cp, int M, int N, int K, int ldb) {
    __shared__ alignas(16) u16 As[4][256 * 32];
    __shared__ alignas(16) u16 Bs[4][256 * 32];
    const int tid = threadIdx.x;
    const int lane = tid & 63, w = tid >> 6;
    const int wr = w >> 2, wc = w & 3;              // 2M x 4N wave grid
    const int quad = lane >> 4, colL = lane & 15;

    const int nbx = N >> 8;
    const int nwg = gridDim.x;
    const int cpx = nwg >> 3;
    const int bid = blockIdx.x;
    const int swz = (bid & 7) * cpx + (bid >> 3);
    const int by = swz / nbx, bx = swz - by * nbx;
    const int m0 = by << 8, n0 = bx << 8;

    const int r0 = tid >> 2,       q0 = (tid & 3) ^ ((r0 >> 1) & 3);
    const int p1 = tid + 512;
    const int r1 = p1 >> 2,        q1 = (p1 & 3) ^ ((r1 >> 1) & 3);
    const u16* agp0 = A  + (size_t)(m0 + r0) * K   + q0 * 8;
    const u16* agp1 = A  + (size_t)(m0 + r1) * K   + q1 * 8;
    const u16* bgp0 = Bw + (size_t)(n0 + r0) * ldb + q0 * 8;
    const u16* bgp1 = Bw + (size_t)(n0 + r1) * ldb + q1 * 8;
    const int l0 = tid * 8, l1 = p1 * 8;

    int aoff[8], boff[4];
#pragma unroll
    for (int mi = 0; mi < 8; ++mi) {
        int r = wr * 128 + mi * 16 + colL;
        aoff[mi] = r * 32 + (quad ^ ((r >> 1) & 3)) * 8;
    }
#pragma unroll
    for (int ni = 0; ni < 4; ++ni) {
        int r = wc * 64 + ni * 16 + colL;
        boff[ni] = r * 32 + (quad ^ ((r >> 1) & 3)) * 8;
    }

    f32x4 acc[8][4];
#pragma unroll
    for (int i = 0; i < 8; ++i)
#pragma unroll
        for (int j = 0; j < 4; ++j) acc[i][j] = (f32x4){0.f, 0.f, 0.f, 0.f};

    const int KT = K >> 5;

#define GB_STAGE(s) { const int _b = (s) & 3; const size_t _ko = (size_t)(s) * 32; \
    gload_lds16(agp0 + _ko, &As[_b][l0]); \
    gload_lds16(agp1 + _ko, &As[_b][l1]); \
    gload_lds16(bgp0 + _ko, &Bs[_b][l0]); \
    gload_lds16(bgp1 + _ko, &Bs[_b][l1]); }

    GB_STAGE(0);
    GB_STAGE(1);
    GB_STAGE(2);

    asm volatile("s_waitcnt vmcnt(8)" ::: "memory");
    __builtin_amdgcn_s_barrier();
    short8 af[8], bfr[4];
#pragma unroll
    for (int i = 0; i < 8; ++i) af[i]  = *(const short8*)(As[0] + aoff[i]);
#pragma unroll
    for (int i = 0; i < 4; ++i) bfr[i] = *(const short8*)(Bs[0] + boff[i]);

    for (int t = 0; t < KT; ++t) {
        if (t <= KT - 3) asm volatile("s_waitcnt vmcnt(4)" ::: "memory");
        else             asm volatile("s_waitcnt vmcnt(0)" ::: "memory");
        __builtin_amdgcn_s_barrier();
        if (t + 3 < KT) GB_STAGE(t + 3);
        const u16* abn = As[(t + 1) & 3];
        const u16* bbn = Bs[(t + 1) & 3];
        short8 bfr2[4];
        __builtin_amdgcn_s_setprio(1);
#pragma unroll
        for (int mi = 0; mi < 8; ++mi) {
#pragma unroll
            for (int ni = 0; ni < 4; ++ni)
                acc[mi][ni] = __builtin_amdgcn_mfma_f32_16x16x32_bf16(af[mi], bfr[ni], acc[mi][ni], 0, 0, 0);
            if (mi < 4) bfr2[mi] = *(const short8*)(bbn + boff[mi]);  // frag(t+1)
            af[mi] = *(const short8*)(abn + aoff[mi]);                // in MFMA shadow
        }
        __builtin_amdgcn_s_setprio(0);
#pragma unroll
        for (int ni = 0; ni < 4; ++ni) bfr[ni] = bfr2[ni];
        __builtin_amdgcn_sched_barrier(0);
    }
#undef GB_STAGE

#pragma unroll
    for (int mi = 0; mi < 8; ++mi)
#pragma unroll
        for (int ni = 0; ni < 4; ++ni) {
            const int rbase = m0 + wr * 128 + mi * 16 + quad * 4;
            const int cc = n0 + wc * 64 + ni * 16 + colL;
#pragma unroll
            for (int rr = 0; rr < 4; ++rr) {
                float v = acc[mi][ni][rr];
                size_t idx = (size_t)(rbase + rr) * N + cc;
                if (EPI == 0) ((u16*)Cp)[idx] = f2bf(v);
                else { float tq = fmaxf(v, 0.f); ((u16*)Cp)[idx] = f2bf(tq * tq); }
            }
        }
}

// ---------------- RoPE + per-head RMSNorm on q,k; split v ----------------
__global__ __launch_bounds__(256)
void rope_split_k(const u16* __restrict__ QKV, const float* __restrict__ RC,
                  const float* __restrict__ QW, const float* __restrict__ KW,
                  u16* __restrict__ Qo, u16* __restrict__ Ko, u16* __restrict__ Vo) {
    const int row = blockIdx.x;                 // b*T + t
    const int t = row & (TT - 1), b = row >> 11;
    const int tid = threadIdx.x, h = tid >> 4, j = tid & 15;
    const size_t qb = (size_t)row * (3 * DM) + h * HD + j * 8;
    float q[8], k[8], cs[8], sn[8];
    load8f(QKV + qb, q);
    load8f(QKV + qb + DM, k);
    uint4 vv = *(const uint4*)(QKV + qb + 2 * DM);
    load8f32(RC + (size_t)t * HD + j * 8, cs);
    load8f32(RC + (size_t)(TT + t) * HD + j * 8, sn);
    float qr[8], kr[8];
#pragma unroll
    for (int p = 0; p < 4; ++p) {
        float c = cs[2 * p], s = sn[2 * p];
        qr[2*p]   = q[2*p]   * c - q[2*p+1] * s;
        qr[2*p+1] = q[2*p+1] * c + q[2*p]   * s;
        kr[2*p]   = k[2*p]   * c - k[2*p+1] * s;
        kr[2*p+1] = k[2*p+1] * c + k[2*p]   * s;
    }
    float sq = 0.f, sk = 0.f;
#pragma unroll
    for (int i = 0; i < 8; ++i) { sq += qr[i] * qr[i]; sk += kr[i] * kr[i]; }
#pragma unroll
    for (int d = 1; d < 16; d <<= 1) { sq += __shfl_xor(sq, d); sk += __shfl_xor(sk, d); }
    const float iq = rsqrtf(sq * (1.f / HD) + EPSF);
    const float ik = rsqrtf(sk * (1.f / HD) + EPSF);
    float qw[8], kw[8], oq[8], ok[8];
    load8f32(QW + j * 8, qw); load8f32(KW + j * 8, kw);
#pragma unroll
    for (int i = 0; i < 8; ++i) { oq[i] = qr[i] * iq * qw[i]; ok[i] = kr[i] * ik * kw[i]; }
    const size_t ob = ((size_t)(b * NH + h) * TT + t) * HD + j * 8;
    store8bf(Qo + ob, oq);
    store8bf(Ko + ob, ok);
    *(uint4*)(Vo + ob) = vv;
}

// ---------------- V transpose: [bh][T][128] -> [bh][128][T] ----------------
__global__ __launch_bounds__(256)
void transpose_v(const u16* __restrict__ V, u16* __restrict__ Vt) {
    __shared__ alignas(16) u16 tile[64][72];
    const int bh = blockIdx.z;
    const int t0 = blockIdx.x * 64, d0 = blockIdx.y * 64;
    const int tid = threadIdx.x;
#pragma unroll
    for (int i = 0; i < 2; ++i) {
        int c = i * 256 + tid;
        int r = c >> 3, cc = (c & 7) * 8;
        *(uint4*)(&tile[r][cc]) = *(const uint4*)(V + ((size_t)bh * TT + t0 + r) * HD + d0 + cc);
    }
    __syncthreads();
#pragma unroll
    for (int i = 0; i < 2; ++i) {
        int c = i * 256 + tid;
        int dc = c >> 3, rr = (c & 7) * 8;
        u16 tmp[8];
#pragma unroll
        for (int kk = 0; kk < 8; ++kk) tmp[kk] = tile[rr + kk][dc];
        uint4 o;
        o.x = (u32)tmp[0] | ((u32)tmp[1] << 16);
        o.y = (u32)tmp[2] | ((u32)tmp[3] << 16);
        o.z = (u32)tmp[4] | ((u32)tmp[5] << 16);
        o.w = (u32)tmp[6] | ((u32)tmp[7] << 16);
        *(uint4*)(Vt + ((size_t)bh * HD + d0 + dc) * TT + t0 + rr) = o;
    }
}

// ---------------- Causal flash attention, 128-query tile, 4 waves x 32 q/wave ----------
// v6: makespan-balanced grid + MFMA row-sum (P x ones on the matrix pipe).
__global__ __launch_bounds__(256, 2)
void attn_k(const u16* __restrict__ Q, const u16* __restrict__ Kg,
            const u16* __restrict__ Vt, u16* __restrict__ O) {
    __shared__ alignas(16) u16 k_lds[2][64 * 128];
    __shared__ alignas(16) u16 v_lds[2][128 * 64];
    __shared__ alignas(16) u16 p_lds[128 * 40];
    const int bh = blockIdx.x;                     // 0..31
    const int yy = blockIdx.y;                     // 0..15
    const int qt = (yy < 8) ? (15 - yy) : (yy - 8); // long blocks dispatched first
    const int tid = threadIdx.x, lane = tid & 63, w = tid >> 6;
    const int quad = lane >> 4, col = lane & 15;
    const int qbase = qt * 128;
    const int wq = qbase + w * 32;

    short8 qf[2][4];
#pragma unroll
    for (int sub = 0; sub < 2; ++sub) {
        const u16* qp = Q + ((size_t)bh * TT + wq + sub * 16 + col) * HD;
#pragma unroll
        for (int s = 0; s < 4; ++s) qf[sub][s] = *(const short8*)(qp + s * 32 + quad * 8);
    }
    short8 ones8;
#pragma unroll
    for (int j = 0; j < 8; ++j) ones8[j] = (short)0x3F80;   // bf16 1.0

    const u16* kp[4]; const u16* vp[4];
#pragma unroll
    for (int i = 0; i < 4; ++i) {
        int lin = i * 256 + tid;
        int r = lin >> 4, sl = lin & 15;
        int gq = sl ^ (r & 15);
        kp[i] = Kg + ((size_t)bh * TT + r) * HD + gq * 8;
    }
#pragma unroll
    for (int i = 0; i < 4; ++i) {
        int lin = i * 256 + tid;
        int r = lin >> 3, sl = lin & 7;
        int gq = sl ^ (r & 7);
        vp[i] = Vt + ((size_t)bh * HD + r) * TT + gq * 8;
    }

    f32x4 oacc[2][8];
#pragma unroll
    for (int s = 0; s < 2; ++s)
#pragma unroll
        for (int i = 0; i < 8; ++i) oacc[s][i] = (f32x4){0.f, 0.f, 0.f, 0.f};
    float mrow[2][4], lrow[2][4];
#pragma unroll
    for (int s = 0; s < 2; ++s)
#pragma unroll
        for (int r = 0; r < 4; ++r) { mrow[s][r] = NEGBIG; lrow[s][r] = 0.f; }
    const float scale = 0.08838834764831845f;   // 1/sqrt(128)

    u16* kcur = k_lds[0]; u16* knxt = k_lds[1];
    u16* vcur = v_lds[0]; u16* vnxt = v_lds[1];
#pragma unroll
    for (int i = 0; i < 4; ++i) gload_lds16(kp[i], kcur + (i * 256 + tid) * 8);
#pragma unroll
    for (int i = 0; i < 4; ++i) gload_lds16(vp[i], vcur + (i * 256 + tid) * 8);

    const int ktmax = 2 * qt + 1;
    for (int kt = 0; kt <= ktmax; ++kt) {
        const int kb = kt * 64;
        __syncthreads();   // drains vmcnt(0): buf[cur] staged, buf[nxt] reads done

        if (kt < ktmax) {  // prefetch next K/V tile into the other buffer (async)
            const int kb2 = kb + 64;
#pragma unroll
            for (int i = 0; i < 4; ++i) gload_lds16(kp[i] + (size_t)kb2 * HD, knxt + (i * 256 + tid) * 8);
#pragma unroll
            for (int i = 0; i < 4; ++i) gload_lds16(vp[i] + kb2, vnxt + (i * 256 + tid) * 8);
        }

        f32x4 sfr[2][4];
#pragma unroll
        for (int s = 0; s < 2; ++s)
#pragma unroll
            for (int ni = 0; ni < 4; ++ni) sfr[s][ni] = (f32x4){0.f, 0.f, 0.f, 0.f};
        __builtin_amdgcn_s_setprio(1);
#pragma unroll
        for (int ni = 0; ni < 4; ++ni) {
            const int r = ni * 16 + col;
#pragma unroll
            for (int s = 0; s < 4; ++s) {
                int sl = (s * 4 + quad) ^ (r & 15);
                short8 kf = *(const short8*)(kcur + r * 128 + sl * 8);
                sfr[0][ni] = __builtin_amdgcn_mfma_f32_16x16x32_bf16(qf[0][s], kf, sfr[0][ni], 0, 0, 0);
                sfr[1][ni] = __builtin_amdgcn_mfma_f32_16x16x32_bf16(qf[1][s], kf, sfr[1][ni], 0, 0, 0);
            }
        }
        __builtin_amdgcn_s_setprio(0);
#pragma unroll
        for (int sub = 0; sub < 2; ++sub)
#pragma unroll
            for (int ni = 0; ni < 4; ++ni) {
                const int key = kb + ni * 16 + col;
#pragma unroll
                for (int rr = 0; rr < 4; ++rr) {
                    float v = sfr[sub][ni][rr] * scale;
                    int qv = wq + sub * 16 + quad * 4 + rr;
                    if (key > qv) v = NEGBIG;
                    sfr[sub][ni][rr] = v;
                }
            }
        float mx[2][4];
#pragma unroll
        for (int sub = 0; sub < 2; ++sub)
#pragma unroll
            for (int rr = 0; rr < 4; ++rr)
                mx[sub][rr] = fmaxf(fmaxf(sfr[sub][0][rr], sfr[sub][1][rr]),
                                    fmaxf(sfr[sub][2][rr], sfr[sub][3][rr]));
#pragma unroll
        for (int d = 1; d < 16; d <<= 1)
#pragma unroll
            for (int sub = 0; sub < 2; ++sub)
#pragma unroll
                for (int rr = 0; rr < 4; ++rr) mx[sub][rr] = fmaxf(mx[sub][rr], __shfl_xor(mx[sub][rr], d));
        bool grew = false;
#pragma unroll
        for (int sub = 0; sub < 2; ++sub)
#pragma unroll
            for (int rr = 0; rr < 4; ++rr) grew = grew || (mx[sub][rr] > mrow[sub][rr]);
        if (__any(grew)) {
#pragma unroll
            for (int sub = 0; sub < 2; ++sub)
#pragma unroll
                for (int rr = 0; rr < 4; ++rr) {
                    float mn = fmaxf(mrow[sub][rr], mx[sub][rr]);
                    float a = __expf(mrow[sub][rr] - mn);
                    mrow[sub][rr] = mn;
                    lrow[sub][rr] *= a;
#pragma unroll
                    for (int i = 0; i < 8; ++i) oacc[sub][i][rr] *= a;
                }
        }
#pragma unroll
        for (int sub = 0; sub < 2; ++sub)
#pragma unroll
            for (int ni = 0; ni < 4; ++ni)
#pragma unroll
                for (int rr = 0; rr < 4; ++rr)
                    sfr[sub][ni][rr] = __expf(sfr[sub][ni][rr] - mrow[sub][rr]);
        // row-sum computed by MFMA (P x ones) inside PV below -- no shuffle reduce.
        f32x4 sacc[2];
        sacc[0] = (f32x4){0.f, 0.f, 0.f, 0.f};
        sacc[1] = (f32x4){0.f, 0.f, 0.f, 0.f};
#pragma unroll
        for (int ks = 0; ks < 2; ++ks) {
#pragma unroll
            for (int sub = 0; sub < 2; ++sub)
#pragma unroll
                for (int nio = 0; nio < 2; ++nio) {
                    const int ni = ks * 2 + nio;
#pragma unroll
                    for (int rr = 0; rr < 4; ++rr)
                        p_lds[(w * 32 + sub * 16 + quad * 4 + rr) * 40 + nio * 16 + col] = f2bf(sfr[sub][ni][rr]);
                }
            short8 pa0 = *(const short8*)(p_lds + (w * 32 + col) * 40 + quad * 8);
            short8 pa1 = *(const short8*)(p_lds + (w * 32 + 16 + col) * 40 + quad * 8);
            __builtin_amdgcn_s_setprio(1);
#pragma unroll
            for (int di = 0; di < 8; ++di) {
                int r = di * 16 + col;
                int sl = (ks * 4 + quad) ^ (r & 7);
                short8 vb = *(const short8*)(vcur + r * 64 + sl * 8);
                oacc[0][di] = __builtin_amdgcn_mfma_f32_16x16x32_bf16(pa0, vb, oacc[0][di], 0, 0, 0);
                oacc[1][di] = __builtin_amdgcn_mfma_f32_16x16x32_bf16(pa1, vb, oacc[1][di], 0, 0, 0);
            }
            sacc[0] = __builtin_amdgcn_mfma_f32_16x16x32_bf16(pa0, ones8, sacc[0], 0, 0, 0);
            sacc[1] = __builtin_amdgcn_mfma_f32_16x16x32_bf16(pa1, ones8, sacc[1], 0, 0, 0);
            __builtin_amdgcn_s_setprio(0);
        }
#pragma unroll
        for (int sub = 0; sub < 2; ++sub)
#pragma unroll
            for (int rr = 0; rr < 4; ++rr) lrow[sub][rr] += sacc[sub][rr];
        { u16* t = kcur; kcur = knxt; knxt = t; }
        { u16* t = vcur; vcur = vnxt; vnxt = t; }
    }
    const int b = bh >> 4, hh = bh & 15;
#pragma unroll
    for (int sub = 0; sub < 2; ++sub)
#pragma unroll
        for (int di = 0; di < 8; ++di)
#pragma unroll
            for (int rr = 0; rr < 4; ++rr) {
                int trow = wq + sub * 16 + quad * 4 + rr;
                float ov = oacc[sub][di][rr] / lrow[sub][rr];
                O[((size_t)(b * TT + trow)) * DM + hh * HD + di * 16 + col] = f2bf(ov);
            }
}

extern "C" void kernel_launch(void* const* d_in, const int* in_sizes, int n_in,
                              void* d_out, int out_size, void* d_ws, size_t ws_size,
                              hipStream_t stream) {
    const float* x    = (const float*)d_in[0];
    const float* rc   = (const float*)d_in[1];
    const float* anw  = (const float*)d_in[2];
    const float* qkvw = (const float*)d_in[3];
    const float* qnw  = (const float*)d_in[4];
    const float* knw  = (const float*)d_in[5];
    const float* opw  = (const float*)d_in[6];
    const float* mnw  = (const float*)d_in[7];
    const float* miw  = (const float*)d_in[8];
    const float* mow  = (const float*)d_in[9];

    char* ws = (char*)d_ws;
    // Workspace plan, 120 MiB peak (MiB offsets). Late-phase owners:
    //   hbuf[0,16) Wmi[16,48) Wmo[48,80) mbuf[80,112) Wo[112,120)
    // Early/mid aliases (dead before late owner is written):
    //   Wq[16,40)  qkv[48,96)  qh[96,112)  kh[112,128)  vh[0,16)  vt[16,32)  aout[32,48)
    // Residual x2 lives in d_out (f32), accumulated by the mlp_out halves.
    u16* hbuf = (u16*)(ws);
    u16* Wq   = (u16*)(ws + (16ll  << 20));
    u16* Wmi  = (u16*)(ws + (16ll  << 20));
    u16* vt   = (u16*)(ws + (16ll  << 20));
    u16* aout = (u16*)(ws + (32ll  << 20));
    u16* Wmo  = (u16*)(ws + (48ll  << 20));
    u16* qkv  = (u16*)(ws + (48ll  << 20));
    u16* mbuf = (u16*)(ws + (80ll  << 20));
    u16* qh   = (u16*)(ws + (96ll  << 20));
    u16* Wo   = (u16*)(ws + (112ll << 20));
    u16* kh   = (u16*)(ws + (112ll << 20));
    u16* vh   = (u16*)(ws);
    float* xo = (float*)d_out;

    rmsnorm_k<<<MR, 256, 0, stream>>>(x, anw, hbuf);
    cvt_w<<<6144, 256, 0, stream>>>(qkvw, Wq);                     // 3DM*DM
    // qkv on the 128^2 ring: 48x32 = 1536 blocks = 3 exactly-full rounds at 2/CU
    // (256^2 gave 384 blocks = 1.5 rounds -> 25% tail).
    gemm_ring<0><<<dim3(48, 32), 256, 0, stream>>>(hbuf, Wq, nullptr, qkv, MR, 3 * DM, DM, DM);
    rope_split_k<<<MR, 256, 0, stream>>>(qkv, rc, qnw, knw, qh, kh, vh);
    transpose_v<<<dim3(32, 2, 32), 256, 0, stream>>>(vh, vt);
    attn_k<<<dim3(32, 16), 256, 0, stream>>>(qh, kh, vt, aout);
    cvt_w<<<2048, 256, 0, stream>>>(opw, Wo);                      // DM*DM (kh dead)
    cvt_w<<<8192, 256, 0, stream>>>(mow, Wmo);                     // DM*FFN (qkv dead)
    gemm_ring<2><<<dim3(16, 32), 256, 0, stream>>>(aout, Wo, x, xo, MR, DM, DM, DM);
    rmsnorm_k<<<MR, 256, 0, stream>>>(xo, mnw, hbuf);
    cvt_w<<<8192, 256, 0, stream>>>(miw, Wmi);                     // FFN*DM (vt/aout dead)
    // MLP in two FFN halves; mbuf is 4096x4096 bf16, d_out accumulates in f32.
    gemm_big<1><<<256, 512, 0, stream>>>(hbuf, Wmi, mbuf, MR, FFN / 2, DM, DM);
    gemm_ring<2><<<dim3(16, 32), 256, 0, stream>>>(mbuf, Wmo, xo, xo, MR, DM, FFN / 2, FFN);
    gemm_big<1><<<256, 512, 0, stream>>>(hbuf, Wmi + (size_t)(FFN / 2) * DM, mbuf, MR, FFN / 2, DM, DM);
    gemm_ring<2><<<dim3(16, 32), 256, 0, stream>>>(mbuf, Wmo + FFN / 2, xo, xo, MR, DM, FFN / 2, FFN);
}